// Round 1
// baseline (3869.814 us; speedup 1.0000x reference)
//
#include <hip/hip_runtime.h>
#include <hip/hip_bf16.h>
#include <math.h>

#define N_BUILD 200000
#define N_COMM  10000
#define E_BUILD 1200000
#define E_COMM  160000

// ---------------- elementwise / utility kernels ----------------

__global__ __launch_bounds__(256) void fill_k(float* p, float v, int n) {
    int i = blockIdx.x * blockDim.x + threadIdx.x;
    if (i < n) p[i] = v;
}

__global__ __launch_bounds__(256) void deg_accum_k(float* deg, const int* __restrict__ dst, int e) {
    int i = blockIdx.x * blockDim.x + threadIdx.x;
    if (i < e) atomicAdd(&deg[dst[i]], 1.0f);
}

__global__ __launch_bounds__(256) void edge_w_k(const int* __restrict__ src, const int* __restrict__ dst,
                                                const float* __restrict__ deg, float* __restrict__ w, int e) {
    int i = blockIdx.x * blockDim.x + threadIdx.x;
    if (i < e) w[i] = rsqrtf(deg[src[i]] * deg[dst[i]]);
}

__global__ __launch_bounds__(256) void relu4_k(float4* p, int n4) {
    int i = blockIdx.x * blockDim.x + threadIdx.x;
    if (i < n4) {
        float4 v = p[i];
        v.x = fmaxf(v.x, 0.f); v.y = fmaxf(v.y, 0.f);
        v.z = fmaxf(v.z, 0.f); v.w = fmaxf(v.w, 0.f);
        p[i] = v;
    }
}

// ---------------- GEMM: H[M x N] = X[M x K] @ W[K x N] ----------------
// Block computes BM x BN tile. W tile and X tile staged in LDS.
// blockDim = 256 = (BM/TM) * (BN/TN).
template<int K, int N, int BN, int BM, int TM, int TN>
__global__ __launch_bounds__(256) void gemm_k(const float* __restrict__ X,
                                              const float* __restrict__ W,
                                              float* __restrict__ H, int M) {
    __shared__ float sW[K][BN];
    __shared__ float sX[BM][K + 1];   // +1 pad: breaks bank aliasing on column reads
    const int tid  = threadIdx.x;
    const int row0 = blockIdx.x * BM;
    const int col0 = blockIdx.y * BN;

    for (int idx = tid * 4; idx < K * BN; idx += 256 * 4) {
        int k = idx / BN, j = idx % BN;
        float4 v = *(const float4*)&W[(size_t)k * N + col0 + j];
        sW[k][j + 0] = v.x; sW[k][j + 1] = v.y; sW[k][j + 2] = v.z; sW[k][j + 3] = v.w;
    }
    for (int idx = tid * 4; idx < BM * K; idx += 256 * 4) {
        int r = idx / K, k = idx % K;
        float4 v = make_float4(0.f, 0.f, 0.f, 0.f);
        if (row0 + r < M) v = *(const float4*)&X[(size_t)(row0 + r) * K + k];
        sX[r][k + 0] = v.x; sX[r][k + 1] = v.y; sX[r][k + 2] = v.z; sX[r][k + 3] = v.w;
    }
    __syncthreads();

    const int NTC = BN / TN;
    const int tc = tid % NTC, tr = tid / NTC;
    float acc[TM][TN];
#pragma unroll
    for (int i = 0; i < TM; ++i)
#pragma unroll
        for (int j = 0; j < TN; ++j) acc[i][j] = 0.f;

#pragma unroll 4
    for (int k = 0; k < K; ++k) {
        float xv[TM], wv[TN];
#pragma unroll
        for (int i = 0; i < TM; ++i) xv[i] = sX[tr * TM + i][k];
#pragma unroll
        for (int j = 0; j < TN; ++j) wv[j] = sW[k][tc * TN + j];
#pragma unroll
        for (int i = 0; i < TM; ++i)
#pragma unroll
            for (int j = 0; j < TN; ++j) acc[i][j] = fmaf(xv[i], wv[j], acc[i][j]);
    }

#pragma unroll
    for (int i = 0; i < TM; ++i) {
        int r = row0 + tr * TM + i;
        if (r >= M) continue;
        float* o = &H[(size_t)r * N + col0 + tc * TN];
#pragma unroll
        for (int j = 0; j < TN; ++j) o[j] = acc[i][j];
    }
}

// GEMM for N=2 (final layer): one thread per row.
__global__ __launch_bounds__(256) void gemm_n2_k(const float* __restrict__ X,
                                                 const float* __restrict__ W, // [64 x 2]
                                                 float* __restrict__ H, int M) {
    __shared__ float sW[128];
    if (threadIdx.x < 128) sW[threadIdx.x] = W[threadIdx.x];
    __syncthreads();
    int i = blockIdx.x * blockDim.x + threadIdx.x;
    if (i >= M) return;
    const float* x = &X[(size_t)i * 64];
    float a = 0.f, b = 0.f;
#pragma unroll
    for (int c = 0; c < 16; ++c) {
        float4 v = *(const float4*)&x[c * 4];
        a = fmaf(v.x, sW[(c*4+0)*2+0], a); b = fmaf(v.x, sW[(c*4+0)*2+1], b);
        a = fmaf(v.y, sW[(c*4+1)*2+0], a); b = fmaf(v.y, sW[(c*4+1)*2+1], b);
        a = fmaf(v.z, sW[(c*4+2)*2+0], a); b = fmaf(v.z, sW[(c*4+2)*2+1], b);
        a = fmaf(v.w, sW[(c*4+3)*2+0], a); b = fmaf(v.w, sW[(c*4+3)*2+1], b);
    }
    H[2 * (size_t)i + 0] = a;
    H[2 * (size_t)i + 1] = b;
}

// ---------------- GCN self term: out = h/deg + bias ----------------
template<int F>
__global__ __launch_bounds__(256) void self_bias_k(const float* __restrict__ h,
                                                   const float* __restrict__ deg,
                                                   const float* __restrict__ b,
                                                   float* __restrict__ out, int n) {
    const int CH = F / 4;
    int gid = blockIdx.x * blockDim.x + threadIdx.x;
    if (gid >= n * CH) return;
    int i = gid / CH;
    int c = (gid % CH) * 4;
    float inv = 1.0f / deg[i];
    float4 v  = *(const float4*)&h[(size_t)i * F + c];
    float4 bb = *(const float4*)&b[c];
    float4 o;
    o.x = fmaf(v.x, inv, bb.x); o.y = fmaf(v.y, inv, bb.y);
    o.z = fmaf(v.z, inv, bb.z); o.w = fmaf(v.w, inv, bb.w);
    *(float4*)&out[(size_t)i * F + c] = o;
}

__global__ __launch_bounds__(256) void self_bias2_k(const float* __restrict__ h,
                                                    const float* __restrict__ deg,
                                                    const float* __restrict__ b,
                                                    float* __restrict__ out, int n) {
    int i = blockIdx.x * blockDim.x + threadIdx.x;
    if (i >= n) return;
    float inv = 1.0f / deg[i];
    out[2 * (size_t)i + 0] = fmaf(h[2 * (size_t)i + 0], inv, b[0]);
    out[2 * (size_t)i + 1] = fmaf(h[2 * (size_t)i + 1], inv, b[1]);
}

// ---------------- edge scatter: out[dst] += h[src] * w_e (atomics) ----------------
template<int F>
__global__ __launch_bounds__(256) void edge_scatter_k(const int* __restrict__ src,
                                                      const int* __restrict__ dst,
                                                      const float* __restrict__ w,
                                                      const float* __restrict__ h,
                                                      float* out, int e) {
    const int CH = F / 4;
    int gid = blockIdx.x * blockDim.x + threadIdx.x;
    if (gid >= e * CH) return;
    int ed = gid / CH;
    int c  = (gid % CH) * 4;
    int s = src[ed], d = dst[ed];
    float ww = w[ed];
    float4 v = *(const float4*)&h[(size_t)s * F + c];
    float* o = &out[(size_t)d * F + c];
    atomicAdd(o + 0, v.x * ww);
    atomicAdd(o + 1, v.y * ww);
    atomicAdd(o + 2, v.z * ww);
    atomicAdd(o + 3, v.w * ww);
}

__global__ __launch_bounds__(256) void edge_scatter2_k(const int* __restrict__ src,
                                                       const int* __restrict__ dst,
                                                       const float* __restrict__ w,
                                                       const float* __restrict__ h,
                                                       float* out, int e) {
    int ed = blockIdx.x * blockDim.x + threadIdx.x;
    if (ed >= e) return;
    int s = src[ed], d = dst[ed];
    float ww = w[ed];
    float2 v = *(const float2*)&h[2 * (size_t)s];
    atomicAdd(&out[2 * (size_t)d + 0], v.x * ww);
    atomicAdd(&out[2 * (size_t)d + 1], v.y * ww);
}

// ---------------- attention fuse ----------------
// fused[i] = [bf[g]*a0, comm_x[map[g]]*a1], a = softmax([bf,bc] @ W_att + b_att), g = l2g[i]
__global__ __launch_bounds__(256) void att_fuse_k(const float* __restrict__ bf,
                                                  const float* __restrict__ cx,
                                                  const int* __restrict__ map,
                                                  const int* __restrict__ l2g,
                                                  const float* __restrict__ Watt,  // [128 x 2]
                                                  const float* __restrict__ batt,  // [2]
                                                  float* __restrict__ fused, int n) {
    __shared__ float sW[256];
    sW[threadIdx.x] = Watt[threadIdx.x];
    __syncthreads();
    int i = blockIdx.x * blockDim.x + threadIdx.x;
    if (i >= n) return;
    int g = l2g[i];
    const float* f1 = &bf[(size_t)g * 64];
    const float* f2 = &cx[(size_t)map[g] * 64];
    float l0 = batt[0], l1 = batt[1];
    float r1[64], r2[64];
#pragma unroll
    for (int c = 0; c < 16; ++c) {
        float4 v = *(const float4*)&f1[c * 4];
        r1[c*4+0]=v.x; r1[c*4+1]=v.y; r1[c*4+2]=v.z; r1[c*4+3]=v.w;
    }
#pragma unroll
    for (int c = 0; c < 16; ++c) {
        float4 v = *(const float4*)&f2[c * 4];
        r2[c*4+0]=v.x; r2[c*4+1]=v.y; r2[c*4+2]=v.z; r2[c*4+3]=v.w;
    }
#pragma unroll
    for (int k = 0; k < 64; ++k) {
        l0 = fmaf(r1[k], sW[k * 2 + 0], l0);
        l1 = fmaf(r1[k], sW[k * 2 + 1], l1);
    }
#pragma unroll
    for (int k = 0; k < 64; ++k) {
        l0 = fmaf(r2[k], sW[(64 + k) * 2 + 0], l0);
        l1 = fmaf(r2[k], sW[(64 + k) * 2 + 1], l1);
    }
    float m  = fmaxf(l0, l1);
    float e0 = __expf(l0 - m), e1 = __expf(l1 - m);
    float inv = 1.0f / (e0 + e1);
    float a0 = e0 * inv, a1 = e1 * inv;
    float* fo = &fused[(size_t)i * 128];
#pragma unroll
    for (int c = 0; c < 16; ++c) {
        float4 o;
        o.x = r1[c*4+0]*a0; o.y = r1[c*4+1]*a0; o.z = r1[c*4+2]*a0; o.w = r1[c*4+3]*a0;
        *(float4*)&fo[c * 4] = o;
    }
#pragma unroll
    for (int c = 0; c < 16; ++c) {
        float4 o;
        o.x = r2[c*4+0]*a1; o.y = r2[c*4+1]*a1; o.z = r2[c*4+2]*a1; o.w = r2[c*4+3]*a1;
        *(float4*)&fo[64 + c * 4] = o;
    }
}

// ---------------- final log-softmax + scatter ----------------
__global__ __launch_bounds__(256) void logsm_k(const float* __restrict__ x,
                                               const int* __restrict__ l2g,
                                               float* __restrict__ out, int n) {
    int i = blockIdx.x * blockDim.x + threadIdx.x;
    if (i >= n) return;
    float a = x[2 * (size_t)i + 0], b = x[2 * (size_t)i + 1];
    float m = fmaxf(a, b);
    float ls = m + logf(__expf(a - m) + __expf(b - m));
    int g = l2g[i];
    out[2 * (size_t)g + 0] = a - ls;
    out[2 * (size_t)g + 1] = b - ls;
}

// ---------------- launch ----------------

static inline dim3 g1(long long n, int tpb = 256) { return dim3((unsigned)((n + tpb - 1) / tpb)); }

extern "C" void kernel_launch(void* const* d_in, const int* in_sizes, int n_in,
                              void* d_out, int out_size, void* d_ws, size_t ws_size,
                              hipStream_t stream) {
    const float* bF   = (const float*)d_in[0];
    const float* cF   = (const float*)d_in[1];
    const float* W_c1 = (const float*)d_in[2];
    const float* b_c1 = (const float*)d_in[3];
    const float* W_c2 = (const float*)d_in[4];
    const float* b_c2 = (const float*)d_in[5];
    const float* W_at = (const float*)d_in[6];
    const float* b_at = (const float*)d_in[7];
    const float* W_b1 = (const float*)d_in[8];
    const float* b_b1 = (const float*)d_in[9];
    const float* W_b2 = (const float*)d_in[10];
    const float* b_b2 = (const float*)d_in[11];
    const float* W_b3 = (const float*)d_in[12];
    const float* b_b3 = (const float*)d_in[13];
    const int* b_src = (const int*)d_in[14];
    const int* b_dst = (const int*)d_in[15];
    const int* c_src = (const int*)d_in[16];
    const int* c_dst = (const int*)d_in[17];
    const int* map   = (const int*)d_in[18];
    const int* l2g   = (const int*)d_in[19];
    float* out = (float*)d_out;

    float* p = (float*)d_ws;
    float* deg_c = p; p += N_COMM;
    float* deg_b = p; p += N_BUILD;
    float* w_c   = p; p += E_COMM;
    float* w_b   = p; p += E_BUILD;
    float* ch    = p; p += (size_t)N_COMM * 64;   // comm gemm output
    float* cx1   = p; p += (size_t)N_COMM * 64;   // comm layer1 out
    float* cx2   = p; p += (size_t)N_COMM * 64;   // comm layer2 out
    float* A     = p; p += (size_t)N_BUILD * 128; // fused / out1 / out2
    float* B     = p; p += (size_t)N_BUILD * 128; // h1 / h2
    float* Dh    = p; p += (size_t)N_BUILD * 2;   // h3
    float* Eo    = p; p += (size_t)N_BUILD * 2;   // out3

    // degrees (deg = 1 + in-degree) and per-edge symmetric norm weights
    fill_k<<<g1(N_COMM), 256, 0, stream>>>(deg_c, 1.0f, N_COMM);
    deg_accum_k<<<g1(E_COMM), 256, 0, stream>>>(deg_c, c_dst, E_COMM);
    fill_k<<<g1(N_BUILD), 256, 0, stream>>>(deg_b, 1.0f, N_BUILD);
    deg_accum_k<<<g1(E_BUILD), 256, 0, stream>>>(deg_b, b_dst, E_BUILD);
    edge_w_k<<<g1(E_COMM), 256, 0, stream>>>(c_src, c_dst, deg_c, w_c, E_COMM);
    edge_w_k<<<g1(E_BUILD), 256, 0, stream>>>(b_src, b_dst, deg_b, w_b, E_BUILD);

    // ---- community GCN layer 1 (32 -> 64) + relu ----
    gemm_k<32, 64, 64, 64, 4, 4><<<dim3((N_COMM + 63) / 64, 1), 256, 0, stream>>>(cF, W_c1, ch, N_COMM);
    self_bias_k<64><<<g1((long long)N_COMM * 16), 256, 0, stream>>>(ch, deg_c, b_c1, cx1, N_COMM);
    edge_scatter_k<64><<<g1((long long)E_COMM * 16), 256, 0, stream>>>(c_src, c_dst, w_c, ch, cx1, E_COMM);
    relu4_k<<<g1((long long)N_COMM * 16), 256, 0, stream>>>((float4*)cx1, N_COMM * 16);

    // ---- community GCN layer 2 (64 -> 64) + relu ----
    gemm_k<64, 64, 64, 64, 4, 4><<<dim3((N_COMM + 63) / 64, 1), 256, 0, stream>>>(cx1, W_c2, ch, N_COMM);
    self_bias_k<64><<<g1((long long)N_COMM * 16), 256, 0, stream>>>(ch, deg_c, b_c2, cx2, N_COMM);
    edge_scatter_k<64><<<g1((long long)E_COMM * 16), 256, 0, stream>>>(c_src, c_dst, w_c, ch, cx2, E_COMM);
    relu4_k<<<g1((long long)N_COMM * 16), 256, 0, stream>>>((float4*)cx2, N_COMM * 16);

    // ---- attention fuse -> local_x (A, 128-wide) ----
    att_fuse_k<<<g1(N_BUILD), 256, 0, stream>>>(bF, cx2, map, l2g, W_at, b_at, A, N_BUILD);

    // ---- building GCN layer 1 (128 -> 128) + relu ----
    gemm_k<128, 128, 64, 32, 2, 4><<<dim3((N_BUILD + 31) / 32, 2), 256, 0, stream>>>(A, W_b1, B, N_BUILD);
    self_bias_k<128><<<g1((long long)N_BUILD * 32), 256, 0, stream>>>(B, deg_b, b_b1, A, N_BUILD);
    edge_scatter_k<128><<<g1((long long)E_BUILD * 32), 256, 0, stream>>>(b_src, b_dst, w_b, B, A, E_BUILD);
    relu4_k<<<g1((long long)N_BUILD * 32), 256, 0, stream>>>((float4*)A, N_BUILD * 32);

    // ---- building GCN layer 2 (128 -> 64) + relu ----
    gemm_k<128, 64, 64, 32, 2, 4><<<dim3((N_BUILD + 31) / 32, 1), 256, 0, stream>>>(A, W_b2, B, N_BUILD);
    self_bias_k<64><<<g1((long long)N_BUILD * 16), 256, 0, stream>>>(B, deg_b, b_b2, A, N_BUILD);
    edge_scatter_k<64><<<g1((long long)E_BUILD * 16), 256, 0, stream>>>(b_src, b_dst, w_b, B, A, E_BUILD);
    relu4_k<<<g1((long long)N_BUILD * 16), 256, 0, stream>>>((float4*)A, N_BUILD * 16);

    // ---- building GCN layer 3 (64 -> 2), no relu ----
    gemm_n2_k<<<g1(N_BUILD), 256, 0, stream>>>(A, W_b3, Dh, N_BUILD);
    self_bias2_k<<<g1(N_BUILD), 256, 0, stream>>>(Dh, deg_b, b_b3, Eo, N_BUILD);
    edge_scatter2_k<<<g1(E_BUILD), 256, 0, stream>>>(b_src, b_dst, w_b, Dh, Eo, E_BUILD);

    // ---- scatter to global order + log_softmax ----
    fill_k<<<g1((long long)N_BUILD * 2), 256, 0, stream>>>(out, -0.69314718056f, N_BUILD * 2);
    logsm_k<<<g1(N_BUILD), 256, 0, stream>>>(Eo, l2g, out, N_BUILD);
}

// Round 2
// 822.416 us; speedup vs baseline: 4.7054x; 4.7054x over previous
//
#include <hip/hip_runtime.h>
#include <hip/hip_bf16.h>
#include <math.h>

#define N_BUILD 200000
#define N_COMM  10000
#define E_BUILD 1200000
#define E_COMM  160000

// ---------------- elementwise / utility kernels ----------------

__global__ __launch_bounds__(256) void fill_f_k(float* p, float v, int n) {
    int i = blockIdx.x * blockDim.x + threadIdx.x;
    if (i < n) p[i] = v;
}

__global__ __launch_bounds__(256) void fill_i_k(int* p, int v, int n) {
    int i = blockIdx.x * blockDim.x + threadIdx.x;
    if (i < n) p[i] = v;
}

__global__ __launch_bounds__(256) void hist_k(int* cnt, const int* __restrict__ dst, int e) {
    int i = blockIdx.x * blockDim.x + threadIdx.x;
    if (i < e) atomicAdd(&cnt[dst[i]], 1);
}

// ---------------- two-level exclusive scan (1024 elems / block) ----------------

__global__ __launch_bounds__(256) void scan1_k(const int* __restrict__ cnt, int* __restrict__ excl,
                                               int* __restrict__ bsum, int n) {
    __shared__ int sdata[256];
    const int tid = threadIdx.x;
    const int base = blockIdx.x * 1024 + tid * 4;
    int v[4]; int s = 0;
#pragma unroll
    for (int j = 0; j < 4; ++j) { v[j] = (base + j < n) ? cnt[base + j] : 0; s += v[j]; }
    sdata[tid] = s; __syncthreads();
    for (int off = 1; off < 256; off <<= 1) {
        int t = (tid >= off) ? sdata[tid - off] : 0;
        __syncthreads();
        sdata[tid] += t;
        __syncthreads();
    }
    if (tid == 255) bsum[blockIdx.x] = sdata[255];
    int run = sdata[tid] - s;   // exclusive prefix for this thread within block
#pragma unroll
    for (int j = 0; j < 4; ++j) { if (base + j < n) excl[base + j] = run; run += v[j]; }
}

__global__ __launch_bounds__(256) void scan2_k(int* bsum, int nb) {
    __shared__ int sdata[256];
    const int tid = threadIdx.x;
    int v = (tid < nb) ? bsum[tid] : 0;
    sdata[tid] = v; __syncthreads();
    for (int off = 1; off < 256; off <<= 1) {
        int t = (tid >= off) ? sdata[tid - off] : 0;
        __syncthreads();
        sdata[tid] += t;
        __syncthreads();
    }
    if (tid < nb) bsum[tid] = sdata[tid] - v;  // exclusive
}

// rowptr[i] = excl[i] + boff[block]; cursor = rowptr; dinv = 1/(cnt+1); rowptr[n] = e
__global__ __launch_bounds__(256) void finalize_k(const int* __restrict__ cnt, int* rowptr,
                                                  const int* __restrict__ boff, int* cursor,
                                                  float* dinv, int n, int e) {
    int i = blockIdx.x * blockDim.x + threadIdx.x;
    if (i < n) {
        int c = cnt[i];
        int r = rowptr[i] + boff[i >> 10];
        rowptr[i] = r;
        cursor[i] = r;
        dinv[i] = 1.0f / (float)(c + 1);
    }
    if (i == 0) rowptr[n] = e;
}

// csr_src[pos] = src, csr_w[pos] = rsqrt(deg_s*deg_d) = sqrt(dinv_s*dinv_d)
__global__ __launch_bounds__(256) void csr_scatter_k(const int* __restrict__ src, const int* __restrict__ dst,
                                                     int* cursor, const float* __restrict__ dinv,
                                                     int* __restrict__ csr_src, float* __restrict__ csr_w, int e) {
    int i = blockIdx.x * blockDim.x + threadIdx.x;
    if (i >= e) return;
    int s = src[i], d = dst[i];
    int pos = atomicAdd(&cursor[d], 1);
    csr_src[pos] = s;
    csr_w[pos] = sqrtf(dinv[s] * dinv[d]);
}

// ---------------- GEMM: H[M x N] = X[M x K] @ W[K x N] ----------------
template<int K, int N, int BN, int BM, int TM, int TN>
__global__ __launch_bounds__(256) void gemm_k(const float* __restrict__ X,
                                              const float* __restrict__ W,
                                              float* __restrict__ H, int M) {
    __shared__ float sW[K][BN];
    __shared__ float sX[BM][K + 1];
    const int tid  = threadIdx.x;
    const int row0 = blockIdx.x * BM;
    const int col0 = blockIdx.y * BN;

    for (int idx = tid * 4; idx < K * BN; idx += 256 * 4) {
        int k = idx / BN, j = idx % BN;
        float4 v = *(const float4*)&W[(size_t)k * N + col0 + j];
        sW[k][j + 0] = v.x; sW[k][j + 1] = v.y; sW[k][j + 2] = v.z; sW[k][j + 3] = v.w;
    }
    for (int idx = tid * 4; idx < BM * K; idx += 256 * 4) {
        int r = idx / K, k = idx % K;
        float4 v = make_float4(0.f, 0.f, 0.f, 0.f);
        if (row0 + r < M) v = *(const float4*)&X[(size_t)(row0 + r) * K + k];
        sX[r][k + 0] = v.x; sX[r][k + 1] = v.y; sX[r][k + 2] = v.z; sX[r][k + 3] = v.w;
    }
    __syncthreads();

    const int NTC = BN / TN;
    const int tc = tid % NTC, tr = tid / NTC;
    float acc[TM][TN];
#pragma unroll
    for (int i = 0; i < TM; ++i)
#pragma unroll
        for (int j = 0; j < TN; ++j) acc[i][j] = 0.f;

#pragma unroll 4
    for (int k = 0; k < K; ++k) {
        float xv[TM], wv[TN];
#pragma unroll
        for (int i = 0; i < TM; ++i) xv[i] = sX[tr * TM + i][k];
#pragma unroll
        for (int j = 0; j < TN; ++j) wv[j] = sW[k][tc * TN + j];
#pragma unroll
        for (int i = 0; i < TM; ++i)
#pragma unroll
            for (int j = 0; j < TN; ++j) acc[i][j] = fmaf(xv[i], wv[j], acc[i][j]);
    }

#pragma unroll
    for (int i = 0; i < TM; ++i) {
        int r = row0 + tr * TM + i;
        if (r >= M) continue;
        float* o = &H[(size_t)r * N + col0 + tc * TN];
#pragma unroll
        for (int j = 0; j < TN; ++j) o[j] = acc[i][j];
    }
}

// GEMM for N=2 (final layer): one thread per row.
__global__ __launch_bounds__(256) void gemm_n2_k(const float* __restrict__ X,
                                                 const float* __restrict__ W, // [64 x 2]
                                                 float* __restrict__ H, int M) {
    __shared__ float sW[128];
    if (threadIdx.x < 128) sW[threadIdx.x] = W[threadIdx.x];
    __syncthreads();
    int i = blockIdx.x * blockDim.x + threadIdx.x;
    if (i >= M) return;
    const float* x = &X[(size_t)i * 64];
    float a = 0.f, b = 0.f;
#pragma unroll
    for (int c = 0; c < 16; ++c) {
        float4 v = *(const float4*)&x[c * 4];
        a = fmaf(v.x, sW[(c*4+0)*2+0], a); b = fmaf(v.x, sW[(c*4+0)*2+1], b);
        a = fmaf(v.y, sW[(c*4+1)*2+0], a); b = fmaf(v.y, sW[(c*4+1)*2+1], b);
        a = fmaf(v.z, sW[(c*4+2)*2+0], a); b = fmaf(v.z, sW[(c*4+2)*2+1], b);
        a = fmaf(v.w, sW[(c*4+3)*2+0], a); b = fmaf(v.w, sW[(c*4+3)*2+1], b);
    }
    H[2 * (size_t)i + 0] = a;
    H[2 * (size_t)i + 1] = b;
}

// ---------------- fused GCN aggregation (gather, no atomics) ----------------
// out[i] = [relu]( sum_{e in row i} h[src_e]*w_e + h[i]*dinv[i] + bias )

template<bool RELU>
__global__ __launch_bounds__(256) void gather128_k(const int* __restrict__ rowptr,
                                                   const int* __restrict__ csrc,
                                                   const float* __restrict__ cw,
                                                   const float* __restrict__ h,
                                                   const float* __restrict__ dinv,
                                                   const float* __restrict__ bias,
                                                   float* __restrict__ out, int n) {
    int node = (blockIdx.x * blockDim.x + threadIdx.x) >> 6;   // one wave per node
    int lane = threadIdx.x & 63;
    if (node >= n) return;
    int beg = rowptr[node], end = rowptr[node + 1];
    int c = lane * 2;
    float2 acc = make_float2(0.f, 0.f);
    for (int e = beg; e < end; ++e) {
        int s = csrc[e];
        float w = cw[e];
        float2 v = *(const float2*)&h[(size_t)s * 128 + c];
        acc.x = fmaf(v.x, w, acc.x);
        acc.y = fmaf(v.y, w, acc.y);
    }
    float iv = dinv[node];
    float2 hv = *(const float2*)&h[(size_t)node * 128 + c];
    float2 bb = *(const float2*)&bias[c];
    float ox = fmaf(hv.x, iv, acc.x) + bb.x;
    float oy = fmaf(hv.y, iv, acc.y) + bb.y;
    if (RELU) { ox = fmaxf(ox, 0.f); oy = fmaxf(oy, 0.f); }
    *(float2*)&out[(size_t)node * 128 + c] = make_float2(ox, oy);
}

template<bool RELU>
__global__ __launch_bounds__(256) void gather64_k(const int* __restrict__ rowptr,
                                                  const int* __restrict__ csrc,
                                                  const float* __restrict__ cw,
                                                  const float* __restrict__ h,
                                                  const float* __restrict__ dinv,
                                                  const float* __restrict__ bias,
                                                  float* __restrict__ out, int n) {
    int node = (blockIdx.x * blockDim.x + threadIdx.x) >> 6;   // one wave per node
    int lane = threadIdx.x & 63;
    if (node >= n) return;
    int beg = rowptr[node], end = rowptr[node + 1];
    float acc = 0.f;
    for (int e = beg; e < end; ++e) {
        int s = csrc[e];
        float w = cw[e];
        acc = fmaf(h[(size_t)s * 64 + lane], w, acc);
    }
    float o = fmaf(h[(size_t)node * 64 + lane], dinv[node], acc) + bias[lane];
    if (RELU) o = fmaxf(o, 0.f);
    out[(size_t)node * 64 + lane] = o;
}

// final layer: gather (F=2) + bias + log-softmax + scatter to global order
__global__ __launch_bounds__(256) void gather2_logsm_k(const int* __restrict__ rowptr,
                                                       const int* __restrict__ csrc,
                                                       const float* __restrict__ cw,
                                                       const float* __restrict__ h2,
                                                       const float* __restrict__ dinv,
                                                       const float* __restrict__ bias,
                                                       const int* __restrict__ l2g,
                                                       float* __restrict__ out, int n) {
    int i = blockIdx.x * blockDim.x + threadIdx.x;
    if (i >= n) return;
    int beg = rowptr[i], end = rowptr[i + 1];
    float a = 0.f, b = 0.f;
    for (int e = beg; e < end; ++e) {
        int s = csrc[e];
        float w = cw[e];
        float2 v = *(const float2*)&h2[2 * (size_t)s];
        a = fmaf(v.x, w, a);
        b = fmaf(v.y, w, b);
    }
    float iv = dinv[i];
    float2 hv = *(const float2*)&h2[2 * (size_t)i];
    a = fmaf(hv.x, iv, a) + bias[0];
    b = fmaf(hv.y, iv, b) + bias[1];
    float m = fmaxf(a, b);
    float ls = m + logf(__expf(a - m) + __expf(b - m));
    int g = l2g[i];
    out[2 * (size_t)g + 0] = a - ls;
    out[2 * (size_t)g + 1] = b - ls;
}

// ---------------- attention fuse ----------------
__global__ __launch_bounds__(256) void att_fuse_k(const float* __restrict__ bf,
                                                  const float* __restrict__ cx,
                                                  const int* __restrict__ map,
                                                  const int* __restrict__ l2g,
                                                  const float* __restrict__ Watt,  // [128 x 2]
                                                  const float* __restrict__ batt,  // [2]
                                                  float* __restrict__ fused, int n) {
    __shared__ float sW[256];
    sW[threadIdx.x] = Watt[threadIdx.x];
    __syncthreads();
    int i = blockIdx.x * blockDim.x + threadIdx.x;
    if (i >= n) return;
    int g = l2g[i];
    const float* f1 = &bf[(size_t)g * 64];
    const float* f2 = &cx[(size_t)map[g] * 64];
    float l0 = batt[0], l1 = batt[1];
    float r1[64], r2[64];
#pragma unroll
    for (int c = 0; c < 16; ++c) {
        float4 v = *(const float4*)&f1[c * 4];
        r1[c*4+0]=v.x; r1[c*4+1]=v.y; r1[c*4+2]=v.z; r1[c*4+3]=v.w;
    }
#pragma unroll
    for (int c = 0; c < 16; ++c) {
        float4 v = *(const float4*)&f2[c * 4];
        r2[c*4+0]=v.x; r2[c*4+1]=v.y; r2[c*4+2]=v.z; r2[c*4+3]=v.w;
    }
#pragma unroll
    for (int k = 0; k < 64; ++k) {
        l0 = fmaf(r1[k], sW[k * 2 + 0], l0);
        l1 = fmaf(r1[k], sW[k * 2 + 1], l1);
    }
#pragma unroll
    for (int k = 0; k < 64; ++k) {
        l0 = fmaf(r2[k], sW[(64 + k) * 2 + 0], l0);
        l1 = fmaf(r2[k], sW[(64 + k) * 2 + 1], l1);
    }
    float m  = fmaxf(l0, l1);
    float e0 = __expf(l0 - m), e1 = __expf(l1 - m);
    float inv = 1.0f / (e0 + e1);
    float a0 = e0 * inv, a1 = e1 * inv;
    float* fo = &fused[(size_t)i * 128];
#pragma unroll
    for (int c = 0; c < 16; ++c) {
        float4 o;
        o.x = r1[c*4+0]*a0; o.y = r1[c*4+1]*a0; o.z = r1[c*4+2]*a0; o.w = r1[c*4+3]*a0;
        *(float4*)&fo[c * 4] = o;
    }
#pragma unroll
    for (int c = 0; c < 16; ++c) {
        float4 o;
        o.x = r2[c*4+0]*a1; o.y = r2[c*4+1]*a1; o.z = r2[c*4+2]*a1; o.w = r2[c*4+3]*a1;
        *(float4*)&fo[64 + c * 4] = o;
    }
}

// ---------------- launch ----------------

static inline dim3 g1(long long n, int tpb = 256) { return dim3((unsigned)((n + tpb - 1) / tpb)); }

extern "C" void kernel_launch(void* const* d_in, const int* in_sizes, int n_in,
                              void* d_out, int out_size, void* d_ws, size_t ws_size,
                              hipStream_t stream) {
    const float* bF   = (const float*)d_in[0];
    const float* cF   = (const float*)d_in[1];
    const float* W_c1 = (const float*)d_in[2];
    const float* b_c1 = (const float*)d_in[3];
    const float* W_c2 = (const float*)d_in[4];
    const float* b_c2 = (const float*)d_in[5];
    const float* W_at = (const float*)d_in[6];
    const float* b_at = (const float*)d_in[7];
    const float* W_b1 = (const float*)d_in[8];
    const float* b_b1 = (const float*)d_in[9];
    const float* W_b2 = (const float*)d_in[10];
    const float* b_b2 = (const float*)d_in[11];
    const float* W_b3 = (const float*)d_in[12];
    const float* b_b3 = (const float*)d_in[13];
    const int* b_src = (const int*)d_in[14];
    const int* b_dst = (const int*)d_in[15];
    const int* c_src = (const int*)d_in[16];
    const int* c_dst = (const int*)d_in[17];
    const int* map   = (const int*)d_in[18];
    const int* l2g   = (const int*)d_in[19];
    float* out = (float*)d_out;

    // workspace layout (all chunk sizes multiples of 4 elems -> 16B alignment)
    float* p = (float*)d_ws;
    int*   cnt_b    = (int*)p;  p += N_BUILD;        // also serves as histogram
    int*   rowptr_b = (int*)p;  p += N_BUILD + 4;
    int*   cursor_b = (int*)p;  p += N_BUILD;
    int*   bsum_b   = (int*)p;  p += 256;
    int*   cnt_c    = (int*)p;  p += N_COMM;
    int*   rowptr_c = (int*)p;  p += N_COMM + 4;
    int*   cursor_c = (int*)p;  p += N_COMM;
    int*   bsum_c   = (int*)p;  p += 256;
    int*   csrc_b   = (int*)p;  p += E_BUILD;
    float* cw_b     = p;        p += E_BUILD;
    int*   csrc_c   = (int*)p;  p += E_COMM;
    float* cw_c     = p;        p += E_COMM;
    float* dinv_b   = p;        p += N_BUILD;
    float* dinv_c   = p;        p += N_COMM;
    float* ch       = p;        p += (size_t)N_COMM * 64;
    float* cx1      = p;        p += (size_t)N_COMM * 64;
    float* cx2      = p;        p += (size_t)N_COMM * 64;
    float* A        = p;        p += (size_t)N_BUILD * 128;  // fused / out1 / out2
    float* B        = p;        p += (size_t)N_BUILD * 128;  // h1 / h2 / h3
    float* Dh       = B;                                      // h3 (B dead by then)

    const int nb_b = (N_BUILD + 1023) / 1024;   // 196
    const int nb_c = (N_COMM  + 1023) / 1024;   // 10

    // ---- build community CSR ----
    fill_i_k<<<g1(N_COMM), 256, 0, stream>>>(cnt_c, 0, N_COMM);
    hist_k<<<g1(E_COMM), 256, 0, stream>>>(cnt_c, c_dst, E_COMM);
    scan1_k<<<nb_c, 256, 0, stream>>>(cnt_c, rowptr_c, bsum_c, N_COMM);
    scan2_k<<<1, 256, 0, stream>>>(bsum_c, nb_c);
    finalize_k<<<g1(N_COMM), 256, 0, stream>>>(cnt_c, rowptr_c, bsum_c, cursor_c, dinv_c, N_COMM, E_COMM);
    csr_scatter_k<<<g1(E_COMM), 256, 0, stream>>>(c_src, c_dst, cursor_c, dinv_c, csrc_c, cw_c, E_COMM);

    // ---- build building CSR ----
    fill_i_k<<<g1(N_BUILD), 256, 0, stream>>>(cnt_b, 0, N_BUILD);
    hist_k<<<g1(E_BUILD), 256, 0, stream>>>(cnt_b, b_dst, E_BUILD);
    scan1_k<<<nb_b, 256, 0, stream>>>(cnt_b, rowptr_b, bsum_b, N_BUILD);
    scan2_k<<<1, 256, 0, stream>>>(bsum_b, nb_b);
    finalize_k<<<g1(N_BUILD), 256, 0, stream>>>(cnt_b, rowptr_b, bsum_b, cursor_b, dinv_b, N_BUILD, E_BUILD);
    csr_scatter_k<<<g1(E_BUILD), 256, 0, stream>>>(b_src, b_dst, cursor_b, dinv_b, csrc_b, cw_b, E_BUILD);

    // ---- community GCN layer 1 (32 -> 64) + relu ----
    gemm_k<32, 64, 64, 64, 4, 4><<<dim3((N_COMM + 63) / 64, 1), 256, 0, stream>>>(cF, W_c1, ch, N_COMM);
    gather64_k<true><<<g1((long long)N_COMM * 64), 256, 0, stream>>>(rowptr_c, csrc_c, cw_c, ch, dinv_c, b_c1, cx1, N_COMM);

    // ---- community GCN layer 2 (64 -> 64) + relu ----
    gemm_k<64, 64, 64, 64, 4, 4><<<dim3((N_COMM + 63) / 64, 1), 256, 0, stream>>>(cx1, W_c2, ch, N_COMM);
    gather64_k<true><<<g1((long long)N_COMM * 64), 256, 0, stream>>>(rowptr_c, csrc_c, cw_c, ch, dinv_c, b_c2, cx2, N_COMM);

    // ---- attention fuse -> local_x (A, 128-wide) ----
    att_fuse_k<<<g1(N_BUILD), 256, 0, stream>>>(bF, cx2, map, l2g, W_at, b_at, A, N_BUILD);

    // ---- building GCN layer 1 (128 -> 128) + relu ----
    gemm_k<128, 128, 64, 32, 2, 4><<<dim3((N_BUILD + 31) / 32, 2), 256, 0, stream>>>(A, W_b1, B, N_BUILD);
    gather128_k<true><<<g1((long long)N_BUILD * 64), 256, 0, stream>>>(rowptr_b, csrc_b, cw_b, B, dinv_b, b_b1, A, N_BUILD);

    // ---- building GCN layer 2 (128 -> 64) + relu ----
    gemm_k<128, 64, 64, 32, 2, 4><<<dim3((N_BUILD + 31) / 32, 1), 256, 0, stream>>>(A, W_b2, B, N_BUILD);
    gather64_k<true><<<g1((long long)N_BUILD * 64), 256, 0, stream>>>(rowptr_b, csrc_b, cw_b, B, dinv_b, b_b2, A, N_BUILD);

    // ---- building GCN layer 3 (64 -> 2) + log-softmax + scatter ----
    gemm_n2_k<<<g1(N_BUILD), 256, 0, stream>>>(A, W_b3, Dh, N_BUILD);
    fill_f_k<<<g1((long long)N_BUILD * 2), 256, 0, stream>>>(out, -0.69314718056f, N_BUILD * 2);
    gather2_logsm_k<<<g1(N_BUILD), 256, 0, stream>>>(rowptr_b, csrc_b, cw_b, Dh, dinv_b, b_b3, l2g, out, N_BUILD);
}

// Round 3
// 543.584 us; speedup vs baseline: 7.1191x; 1.5130x over previous
//
#include <hip/hip_runtime.h>
#include <hip/hip_bf16.h>
#include <math.h>

#define N_BUILD 200000
#define N_COMM  10000
#define E_BUILD 1200000
#define E_COMM  160000

typedef __bf16 bf16x8 __attribute__((ext_vector_type(8)));
typedef float  f32x4  __attribute__((ext_vector_type(4)));

// ---------------- bf16 helpers (RNE) ----------------
__device__ __forceinline__ unsigned short f2b(float f) {
    unsigned int u = __builtin_bit_cast(unsigned int, f);
    u += 0x7fffu + ((u >> 16) & 1u);
    return (unsigned short)(u >> 16);
}
__device__ __forceinline__ float b2f(unsigned short h) {
    unsigned int u = ((unsigned int)h) << 16;
    return __builtin_bit_cast(float, u);
}
__device__ __forceinline__ unsigned int pk2(float a, float b) {
    return (unsigned int)f2b(a) | ((unsigned int)f2b(b) << 16);
}
__device__ __forceinline__ void up8(uint4 v, float* r) {
    r[0] = b2f((unsigned short)v.x); r[1] = b2f((unsigned short)(v.x >> 16));
    r[2] = b2f((unsigned short)v.y); r[3] = b2f((unsigned short)(v.y >> 16));
    r[4] = b2f((unsigned short)v.z); r[5] = b2f((unsigned short)(v.z >> 16));
    r[6] = b2f((unsigned short)v.w); r[7] = b2f((unsigned short)(v.w >> 16));
}

// ---------------- elementwise / utility kernels ----------------

__global__ __launch_bounds__(256) void fill_f_k(float* p, float v, int n) {
    int i = blockIdx.x * blockDim.x + threadIdx.x;
    if (i < n) p[i] = v;
}

__global__ __launch_bounds__(256) void fill_i_k(int* p, int v, int n) {
    int i = blockIdx.x * blockDim.x + threadIdx.x;
    if (i < n) p[i] = v;
}

__global__ __launch_bounds__(256) void hist_k(int* cnt, const int* __restrict__ dst, int e) {
    int i = blockIdx.x * blockDim.x + threadIdx.x;
    if (i < e) atomicAdd(&cnt[dst[i]], 1);
}

// convert f32 -> bf16 flat
__global__ __launch_bounds__(256) void cvt_bf16_k(const float* __restrict__ in, unsigned short* __restrict__ out, int n) {
    int i = blockIdx.x * blockDim.x + threadIdx.x;
    if (i < n) out[i] = f2b(in[i]);
}

// W[K][N] f32 -> Wt[N][K] bf16
__global__ __launch_bounds__(256) void wt_bf16_k(const float* __restrict__ W, unsigned short* __restrict__ Wt, int K, int N) {
    int idx = blockIdx.x * blockDim.x + threadIdx.x;
    if (idx >= K * N) return;
    int k = idx / N, n = idx % N;
    Wt[n * K + k] = f2b(W[idx]);
}

// ---------------- two-level exclusive scan (1024 elems / block) ----------------

__global__ __launch_bounds__(256) void scan1_k(const int* __restrict__ cnt, int* __restrict__ excl,
                                               int* __restrict__ bsum, int n) {
    __shared__ int sdata[256];
    const int tid = threadIdx.x;
    const int base = blockIdx.x * 1024 + tid * 4;
    int v[4]; int s = 0;
#pragma unroll
    for (int j = 0; j < 4; ++j) { v[j] = (base + j < n) ? cnt[base + j] : 0; s += v[j]; }
    sdata[tid] = s; __syncthreads();
    for (int off = 1; off < 256; off <<= 1) {
        int t = (tid >= off) ? sdata[tid - off] : 0;
        __syncthreads();
        sdata[tid] += t;
        __syncthreads();
    }
    if (tid == 255) bsum[blockIdx.x] = sdata[255];
    int run = sdata[tid] - s;
#pragma unroll
    for (int j = 0; j < 4; ++j) { if (base + j < n) excl[base + j] = run; run += v[j]; }
}

__global__ __launch_bounds__(256) void scan2_k(int* bsum, int nb) {
    __shared__ int sdata[256];
    const int tid = threadIdx.x;
    int v = (tid < nb) ? bsum[tid] : 0;
    sdata[tid] = v; __syncthreads();
    for (int off = 1; off < 256; off <<= 1) {
        int t = (tid >= off) ? sdata[tid - off] : 0;
        __syncthreads();
        sdata[tid] += t;
        __syncthreads();
    }
    if (tid < nb) bsum[tid] = sdata[tid] - v;
}

__global__ __launch_bounds__(256) void finalize_k(const int* __restrict__ cnt, int* rowptr,
                                                  const int* __restrict__ boff, int* cursor,
                                                  float* dinv, int n, int e) {
    int i = blockIdx.x * blockDim.x + threadIdx.x;
    if (i < n) {
        int c = cnt[i];
        int r = rowptr[i] + boff[i >> 10];
        rowptr[i] = r;
        cursor[i] = r;
        dinv[i] = 1.0f / (float)(c + 1);
    }
    if (i == 0) rowptr[n] = e;
}

__global__ __launch_bounds__(256) void csr_scatter_k(const int* __restrict__ src, const int* __restrict__ dst,
                                                     int* cursor, const float* __restrict__ dinv,
                                                     int* __restrict__ csr_src, float* __restrict__ csr_w, int e) {
    int i = blockIdx.x * blockDim.x + threadIdx.x;
    if (i >= e) return;
    int s = src[i], d = dst[i];
    int pos = atomicAdd(&cursor[d], 1);
    csr_src[pos] = s;
    csr_w[pos] = sqrtf(dinv[s] * dinv[d]);
}

// ---------------- MFMA GEMM: H[M][N] (bf16) = X[M][K] (bf16) @ Wt[N][K]^T ----------------
// Block = 256 threads = 4 waves; each wave computes a 16-row x N slab.
// LDS XOR-granule swizzle (T2) to avoid 16-way bank conflicts on stride-K rows.
template<int K, int N, bool GUARD>
__global__ __launch_bounds__(256) void gemm_mfma_k(const unsigned short* __restrict__ X,
                                                   const unsigned short* __restrict__ Wt,
                                                   unsigned short* __restrict__ H, int M) {
    constexpr int GPR = K / 8;          // 16B granules per row
    __shared__ unsigned short sA[64 * K];
    __shared__ unsigned short sB[N * K];
    const int tid  = threadIdx.x;
    const int row0 = blockIdx.x * 64;

    for (int idx = tid; idx < 64 * GPR; idx += 256) {
        int r = idx / GPR, g = idx % GPR;
        uint4 v = make_uint4(0u, 0u, 0u, 0u);
        if (!GUARD || row0 + r < M)
            v = *(const uint4*)&X[(size_t)(row0 + r) * K + g * 8];
        int gs = g ^ (r & (GPR - 1));
        *(uint4*)&sA[r * K + gs * 8] = v;
    }
    for (int idx = tid; idx < N * GPR; idx += 256) {
        int r = idx / GPR, g = idx % GPR;
        uint4 v = *(const uint4*)&Wt[(size_t)r * K + g * 8];
        int gs = g ^ (r & (GPR - 1));
        *(uint4*)&sB[r * K + gs * 8] = v;
    }
    __syncthreads();

    const int wave = tid >> 6, lane = tid & 63;
    const int rA = wave * 16 + (lane & 15);   // A row (M) within block tile
    const int kg = lane >> 4;                 // granule within 32-wide K-step

    f32x4 zero = {0.f, 0.f, 0.f, 0.f};
    f32x4 acc[N / 16];
#pragma unroll
    for (int t = 0; t < N / 16; ++t) acc[t] = zero;

#pragma unroll
    for (int ks = 0; ks < K / 32; ++ks) {
        int gA = (ks * 4 + kg) ^ (rA & (GPR - 1));
        bf16x8 a = *(const bf16x8*)&sA[rA * K + gA * 8];
#pragma unroll
        for (int t = 0; t < N / 16; ++t) {
            int rB = t * 16 + (lane & 15);
            int gB = (ks * 4 + kg) ^ (rB & (GPR - 1));
            bf16x8 b = *(const bf16x8*)&sB[rB * K + gB * 8];
            acc[t] = __builtin_amdgcn_mfma_f32_16x16x32_bf16(a, b, acc[t], 0, 0, 0);
        }
    }

    // C/D: col = lane&15, row = (lane>>4)*4 + j   [m89 verified mapping]
    const int crow = wave * 16 + (lane >> 4) * 4;
    const int ccol = lane & 15;
#pragma unroll
    for (int t = 0; t < N / 16; ++t) {
#pragma unroll
        for (int j = 0; j < 4; ++j) {
            int r = row0 + crow + j;
            if (!GUARD || r < M)
                H[(size_t)r * N + t * 16 + ccol] = f2b(acc[t][j]);
        }
    }
}

// GEMM N=2 (final layer), bf16 input, f32 out
__global__ __launch_bounds__(256) void gemm_n2b_k(const unsigned short* __restrict__ X,
                                                  const float* __restrict__ W, // [64 x 2]
                                                  float* __restrict__ H, int M) {
    __shared__ float sW[128];
    if (threadIdx.x < 128) sW[threadIdx.x] = W[threadIdx.x];
    __syncthreads();
    int i = blockIdx.x * blockDim.x + threadIdx.x;
    if (i >= M) return;
    const unsigned short* x = &X[(size_t)i * 64];
    float a = 0.f, b = 0.f;
#pragma unroll
    for (int c = 0; c < 8; ++c) {
        uint4 v = *(const uint4*)&x[c * 8];
        float r[8]; up8(v, r);
#pragma unroll
        for (int j = 0; j < 8; ++j) {
            a = fmaf(r[j], sW[(c * 8 + j) * 2 + 0], a);
            b = fmaf(r[j], sW[(c * 8 + j) * 2 + 1], b);
        }
    }
    H[2 * (size_t)i + 0] = a;
    H[2 * (size_t)i + 1] = b;
}

// ---------------- fused GCN aggregation (gather, bf16 features) ----------------
// out[i] = [relu]( sum_e h[src_e]*w_e + h[i]*dinv[i] + bias )

template<bool RELU>
__global__ __launch_bounds__(256) void gather128b_k(const int* __restrict__ rowptr,
                                                    const int* __restrict__ csrc,
                                                    const float* __restrict__ cw,
                                                    const unsigned short* __restrict__ h,
                                                    const float* __restrict__ dinv,
                                                    const float* __restrict__ bias,
                                                    unsigned short* __restrict__ out, int n) {
    int node = (blockIdx.x * blockDim.x + threadIdx.x) >> 6;   // one wave per node
    int lane = threadIdx.x & 63;
    if (node >= n) return;
    int beg = rowptr[node], end = rowptr[node + 1];
    int c = lane * 2;
    float ax = 0.f, ay = 0.f;
    for (int e = beg; e < end; ++e) {
        int s = csrc[e];
        float w = cw[e];
        unsigned int v = *(const unsigned int*)&h[(size_t)s * 128 + c];
        ax = fmaf(b2f((unsigned short)v), w, ax);
        ay = fmaf(b2f((unsigned short)(v >> 16)), w, ay);
    }
    float iv = dinv[node];
    unsigned int hv = *(const unsigned int*)&h[(size_t)node * 128 + c];
    float ox = fmaf(b2f((unsigned short)hv), iv, ax) + bias[c];
    float oy = fmaf(b2f((unsigned short)(hv >> 16)), iv, ay) + bias[c + 1];
    if (RELU) { ox = fmaxf(ox, 0.f); oy = fmaxf(oy, 0.f); }
    *(unsigned int*)&out[(size_t)node * 128 + c] = pk2(ox, oy);
}

template<bool RELU>
__global__ __launch_bounds__(256) void gather64b_k(const int* __restrict__ rowptr,
                                                   const int* __restrict__ csrc,
                                                   const float* __restrict__ cw,
                                                   const unsigned short* __restrict__ h,
                                                   const float* __restrict__ dinv,
                                                   const float* __restrict__ bias,
                                                   unsigned short* __restrict__ out, int n) {
    int gid = blockIdx.x * blockDim.x + threadIdx.x;
    int node = gid >> 5;                                        // half-wave per node
    int sl = gid & 31;
    if (node >= n) return;
    int beg = rowptr[node], end = rowptr[node + 1];
    int c = sl * 2;
    float ax = 0.f, ay = 0.f;
    for (int e = beg; e < end; ++e) {
        int s = csrc[e];
        float w = cw[e];
        unsigned int v = *(const unsigned int*)&h[(size_t)s * 64 + c];
        ax = fmaf(b2f((unsigned short)v), w, ax);
        ay = fmaf(b2f((unsigned short)(v >> 16)), w, ay);
    }
    float iv = dinv[node];
    unsigned int hv = *(const unsigned int*)&h[(size_t)node * 64 + c];
    float ox = fmaf(b2f((unsigned short)hv), iv, ax) + bias[c];
    float oy = fmaf(b2f((unsigned short)(hv >> 16)), iv, ay) + bias[c + 1];
    if (RELU) { ox = fmaxf(ox, 0.f); oy = fmaxf(oy, 0.f); }
    *(unsigned int*)&out[(size_t)node * 64 + c] = pk2(ox, oy);
}

// final layer: gather (F=2, f32) + bias + log-softmax + scatter to global order
__global__ __launch_bounds__(256) void gather2_logsm_k(const int* __restrict__ rowptr,
                                                       const int* __restrict__ csrc,
                                                       const float* __restrict__ cw,
                                                       const float* __restrict__ h2,
                                                       const float* __restrict__ dinv,
                                                       const float* __restrict__ bias,
                                                       const int* __restrict__ l2g,
                                                       float* __restrict__ out, int n) {
    int i = blockIdx.x * blockDim.x + threadIdx.x;
    if (i >= n) return;
    int beg = rowptr[i], end = rowptr[i + 1];
    float a = 0.f, b = 0.f;
    for (int e = beg; e < end; ++e) {
        int s = csrc[e];
        float w = cw[e];
        float2 v = *(const float2*)&h2[2 * (size_t)s];
        a = fmaf(v.x, w, a);
        b = fmaf(v.y, w, b);
    }
    float iv = dinv[i];
    float2 hv = *(const float2*)&h2[2 * (size_t)i];
    a = fmaf(hv.x, iv, a) + bias[0];
    b = fmaf(hv.y, iv, b) + bias[1];
    float m = fmaxf(a, b);
    float ls = m + logf(__expf(a - m) + __expf(b - m));
    int g = l2g[i];
    out[2 * (size_t)g + 0] = a - ls;
    out[2 * (size_t)g + 1] = b - ls;
}

// ---------------- attention fuse (f32 bF, bf16 comm emb -> bf16 fused) ----------------
__global__ __launch_bounds__(256) void att_fuse_k(const float* __restrict__ bf,
                                                  const unsigned short* __restrict__ cx,
                                                  const int* __restrict__ map,
                                                  const int* __restrict__ l2g,
                                                  const float* __restrict__ Watt,  // [128 x 2]
                                                  const float* __restrict__ batt,  // [2]
                                                  unsigned short* __restrict__ fused, int n) {
    __shared__ float sW[256];
    sW[threadIdx.x] = Watt[threadIdx.x];
    __syncthreads();
    int i = blockIdx.x * blockDim.x + threadIdx.x;
    if (i >= n) return;
    int g = l2g[i];
    const float* f1 = &bf[(size_t)g * 64];
    const unsigned short* f2 = &cx[(size_t)map[g] * 64];
    float r1[64], r2[64];
#pragma unroll
    for (int c = 0; c < 16; ++c) {
        float4 v = *(const float4*)&f1[c * 4];
        r1[c*4+0]=v.x; r1[c*4+1]=v.y; r1[c*4+2]=v.z; r1[c*4+3]=v.w;
    }
#pragma unroll
    for (int c = 0; c < 8; ++c) {
        uint4 v = *(const uint4*)&f2[c * 8];
        up8(v, &r2[c * 8]);
    }
    float l0 = batt[0], l1 = batt[1];
#pragma unroll
    for (int k = 0; k < 64; ++k) {
        l0 = fmaf(r1[k], sW[k * 2 + 0], l0);
        l1 = fmaf(r1[k], sW[k * 2 + 1], l1);
    }
#pragma unroll
    for (int k = 0; k < 64; ++k) {
        l0 = fmaf(r2[k], sW[(64 + k) * 2 + 0], l0);
        l1 = fmaf(r2[k], sW[(64 + k) * 2 + 1], l1);
    }
    float m  = fmaxf(l0, l1);
    float e0 = __expf(l0 - m), e1 = __expf(l1 - m);
    float inv = 1.0f / (e0 + e1);
    float a0 = e0 * inv, a1 = e1 * inv;
    unsigned short* fo = &fused[(size_t)i * 128];
#pragma unroll
    for (int c = 0; c < 8; ++c) {
        uint4 o;
        o.x = pk2(r1[c*8+0]*a0, r1[c*8+1]*a0);
        o.y = pk2(r1[c*8+2]*a0, r1[c*8+3]*a0);
        o.z = pk2(r1[c*8+4]*a0, r1[c*8+5]*a0);
        o.w = pk2(r1[c*8+6]*a0, r1[c*8+7]*a0);
        *(uint4*)&fo[c * 8] = o;
    }
#pragma unroll
    for (int c = 0; c < 8; ++c) {
        uint4 o;
        o.x = pk2(r2[c*8+0]*a1, r2[c*8+1]*a1);
        o.y = pk2(r2[c*8+2]*a1, r2[c*8+3]*a1);
        o.z = pk2(r2[c*8+4]*a1, r2[c*8+5]*a1);
        o.w = pk2(r2[c*8+6]*a1, r2[c*8+7]*a1);
        *(uint4*)&fo[64 + c * 8] = o;
    }
}

// ---------------- launch ----------------

static inline dim3 g1(long long n, int tpb = 256) { return dim3((unsigned)((n + tpb - 1) / tpb)); }

extern "C" void kernel_launch(void* const* d_in, const int* in_sizes, int n_in,
                              void* d_out, int out_size, void* d_ws, size_t ws_size,
                              hipStream_t stream) {
    const float* bF   = (const float*)d_in[0];
    const float* cF   = (const float*)d_in[1];
    const float* W_c1 = (const float*)d_in[2];
    const float* b_c1 = (const float*)d_in[3];
    const float* W_c2 = (const float*)d_in[4];
    const float* b_c2 = (const float*)d_in[5];
    const float* W_at = (const float*)d_in[6];
    const float* b_at = (const float*)d_in[7];
    const float* W_b1 = (const float*)d_in[8];
    const float* b_b1 = (const float*)d_in[9];
    const float* W_b2 = (const float*)d_in[10];
    const float* b_b2 = (const float*)d_in[11];
    const float* W_b3 = (const float*)d_in[12];
    const float* b_b3 = (const float*)d_in[13];
    const int* b_src = (const int*)d_in[14];
    const int* b_dst = (const int*)d_in[15];
    const int* c_src = (const int*)d_in[16];
    const int* c_dst = (const int*)d_in[17];
    const int* map   = (const int*)d_in[18];
    const int* l2g   = (const int*)d_in[19];
    float* out = (float*)d_out;

    // workspace layout (all chunks multiples of 16 B)
    char* p = (char*)d_ws;
    auto alloc = [&](size_t bytes) { char* q = p; p += (bytes + 15) & ~(size_t)15; return q; };
    int*   cnt_b    = (int*)  alloc(N_BUILD * 4);
    int*   rowptr_b = (int*)  alloc((N_BUILD + 4) * 4);
    int*   cursor_b = (int*)  alloc(N_BUILD * 4);
    int*   bsum_b   = (int*)  alloc(256 * 4);
    int*   cnt_c    = (int*)  alloc(N_COMM * 4);
    int*   rowptr_c = (int*)  alloc((N_COMM + 4) * 4);
    int*   cursor_c = (int*)  alloc(N_COMM * 4);
    int*   bsum_c   = (int*)  alloc(256 * 4);
    int*   csrc_b   = (int*)  alloc((size_t)E_BUILD * 4);
    float* cw_b     = (float*)alloc((size_t)E_BUILD * 4);
    int*   csrc_c   = (int*)  alloc(E_COMM * 4);
    float* cw_c     = (float*)alloc(E_COMM * 4);
    float* dinv_b   = (float*)alloc(N_BUILD * 4);
    float* dinv_c   = (float*)alloc(N_COMM * 4);
    unsigned short* cFb    = (unsigned short*)alloc((size_t)N_COMM * 32 * 2);
    unsigned short* Wt_c1  = (unsigned short*)alloc(64 * 32 * 2);
    unsigned short* Wt_c2  = (unsigned short*)alloc(64 * 64 * 2);
    unsigned short* Wt_b1  = (unsigned short*)alloc(128 * 128 * 2);
    unsigned short* Wt_b2  = (unsigned short*)alloc(64 * 128 * 2);
    unsigned short* ch_bf  = (unsigned short*)alloc((size_t)N_COMM * 64 * 2);
    unsigned short* cx1_bf = (unsigned short*)alloc((size_t)N_COMM * 64 * 2);
    unsigned short* cx2_bf = (unsigned short*)alloc((size_t)N_COMM * 64 * 2);
    unsigned short* A_bf   = (unsigned short*)alloc((size_t)N_BUILD * 128 * 2); // fused / o1 / o2
    unsigned short* B_bf   = (unsigned short*)alloc((size_t)N_BUILD * 128 * 2); // h1 / h2
    float* Dh = (float*)alloc((size_t)N_BUILD * 2 * 4);

    const int nb_b = (N_BUILD + 1023) / 1024;
    const int nb_c = (N_COMM  + 1023) / 1024;

    // ---- weight / input conversions ----
    cvt_bf16_k<<<g1((long long)N_COMM * 32), 256, 0, stream>>>(cF, cFb, N_COMM * 32);
    wt_bf16_k<<<g1(32 * 64), 256, 0, stream>>>(W_c1, Wt_c1, 32, 64);
    wt_bf16_k<<<g1(64 * 64), 256, 0, stream>>>(W_c2, Wt_c2, 64, 64);
    wt_bf16_k<<<g1(128 * 128), 256, 0, stream>>>(W_b1, Wt_b1, 128, 128);
    wt_bf16_k<<<g1(128 * 64), 256, 0, stream>>>(W_b2, Wt_b2, 128, 64);

    // ---- build community CSR ----
    fill_i_k<<<g1(N_COMM), 256, 0, stream>>>(cnt_c, 0, N_COMM);
    hist_k<<<g1(E_COMM), 256, 0, stream>>>(cnt_c, c_dst, E_COMM);
    scan1_k<<<nb_c, 256, 0, stream>>>(cnt_c, rowptr_c, bsum_c, N_COMM);
    scan2_k<<<1, 256, 0, stream>>>(bsum_c, nb_c);
    finalize_k<<<g1(N_COMM), 256, 0, stream>>>(cnt_c, rowptr_c, bsum_c, cursor_c, dinv_c, N_COMM, E_COMM);
    csr_scatter_k<<<g1(E_COMM), 256, 0, stream>>>(c_src, c_dst, cursor_c, dinv_c, csrc_c, cw_c, E_COMM);

    // ---- build building CSR ----
    fill_i_k<<<g1(N_BUILD), 256, 0, stream>>>(cnt_b, 0, N_BUILD);
    hist_k<<<g1(E_BUILD), 256, 0, stream>>>(cnt_b, b_dst, E_BUILD);
    scan1_k<<<nb_b, 256, 0, stream>>>(cnt_b, rowptr_b, bsum_b, N_BUILD);
    scan2_k<<<1, 256, 0, stream>>>(bsum_b, nb_b);
    finalize_k<<<g1(N_BUILD), 256, 0, stream>>>(cnt_b, rowptr_b, bsum_b, cursor_b, dinv_b, N_BUILD, E_BUILD);
    csr_scatter_k<<<g1(E_BUILD), 256, 0, stream>>>(b_src, b_dst, cursor_b, dinv_b, csrc_b, cw_b, E_BUILD);

    // ---- community GCN layer 1 (32 -> 64) + relu ----
    gemm_mfma_k<32, 64, true><<<dim3((N_COMM + 63) / 64), 256, 0, stream>>>(cFb, Wt_c1, ch_bf, N_COMM);
    gather64b_k<true><<<g1((long long)N_COMM * 32), 256, 0, stream>>>(rowptr_c, csrc_c, cw_c, ch_bf, dinv_c, b_c1, cx1_bf, N_COMM);

    // ---- community GCN layer 2 (64 -> 64) + relu ----
    gemm_mfma_k<64, 64, true><<<dim3((N_COMM + 63) / 64), 256, 0, stream>>>(cx1_bf, Wt_c2, ch_bf, N_COMM);
    gather64b_k<true><<<g1((long long)N_COMM * 32), 256, 0, stream>>>(rowptr_c, csrc_c, cw_c, ch_bf, dinv_c, b_c2, cx2_bf, N_COMM);

    // ---- attention fuse -> fused (A_bf, 128-wide bf16) ----
    att_fuse_k<<<g1(N_BUILD), 256, 0, stream>>>(bF, cx2_bf, map, l2g, W_at, b_at, A_bf, N_BUILD);

    // ---- building GCN layer 1 (128 -> 128) + relu ----
    gemm_mfma_k<128, 128, false><<<dim3(N_BUILD / 64), 256, 0, stream>>>(A_bf, Wt_b1, B_bf, N_BUILD);
    gather128b_k<true><<<g1((long long)N_BUILD * 64), 256, 0, stream>>>(rowptr_b, csrc_b, cw_b, B_bf, dinv_b, b_b1, A_bf, N_BUILD);

    // ---- building GCN layer 2 (128 -> 64) + relu ----
    gemm_mfma_k<128, 64, false><<<dim3(N_BUILD / 64), 256, 0, stream>>>(A_bf, Wt_b2, B_bf, N_BUILD);
    gather64b_k<true><<<g1((long long)N_BUILD * 32), 256, 0, stream>>>(rowptr_b, csrc_b, cw_b, B_bf, dinv_b, b_b2, A_bf, N_BUILD);

    // ---- building GCN layer 3 (64 -> 2) + log-softmax + scatter ----
    gemm_n2b_k<<<g1(N_BUILD), 256, 0, stream>>>(A_bf, W_b3, Dh, N_BUILD);
    fill_f_k<<<g1((long long)N_BUILD * 2), 256, 0, stream>>>(out, -0.69314718056f, N_BUILD * 2);
    gather2_logsm_k<<<g1(N_BUILD), 256, 0, stream>>>(rowptr_b, csrc_b, cw_b, Dh, dinv_b, b_b3, l2g, out, N_BUILD);
}

// Round 4
// 407.678 us; speedup vs baseline: 9.4923x; 1.3334x over previous
//
#include <hip/hip_runtime.h>
#include <hip/hip_bf16.h>
#include <math.h>

#define N_BUILD 200000
#define N_COMM  10000
#define E_BUILD 1200000
#define E_COMM  160000

typedef __bf16 bf16x8 __attribute__((ext_vector_type(8)));
typedef float  f32x4  __attribute__((ext_vector_type(4)));

// ---------------- bf16 helpers (RNE) ----------------
__device__ __forceinline__ unsigned short f2b(float f) {
    unsigned int u = __builtin_bit_cast(unsigned int, f);
    u += 0x7fffu + ((u >> 16) & 1u);
    return (unsigned short)(u >> 16);
}
__device__ __forceinline__ float b2f(unsigned short h) {
    unsigned int u = ((unsigned int)h) << 16;
    return __builtin_bit_cast(float, u);
}
__device__ __forceinline__ unsigned int pk2(float a, float b) {
    return (unsigned int)f2b(a) | ((unsigned int)f2b(b) << 16);
}
__device__ __forceinline__ void up8(uint4 v, float* r) {
    r[0] = b2f((unsigned short)v.x); r[1] = b2f((unsigned short)(v.x >> 16));
    r[2] = b2f((unsigned short)v.y); r[3] = b2f((unsigned short)(v.y >> 16));
    r[4] = b2f((unsigned short)v.z); r[5] = b2f((unsigned short)(v.z >> 16));
    r[6] = b2f((unsigned short)v.w); r[7] = b2f((unsigned short)(v.w >> 16));
}

// ---------------- elementwise / utility kernels ----------------

__global__ __launch_bounds__(256) void fill_f_k(float* p, float v, int n) {
    int i = blockIdx.x * blockDim.x + threadIdx.x;
    if (i < n) p[i] = v;
}

__global__ __launch_bounds__(256) void fill_i_k(int* p, int v, int n) {
    int i = blockIdx.x * blockDim.x + threadIdx.x;
    if (i < n) p[i] = v;
}

__global__ __launch_bounds__(256) void hist_k(int* cnt, const int* __restrict__ dst, int e) {
    int i = blockIdx.x * blockDim.x + threadIdx.x;
    if (i < e) atomicAdd(&cnt[dst[i]], 1);
}

__global__ __launch_bounds__(256) void cvt_bf16_k(const float* __restrict__ in, unsigned short* __restrict__ out, int n) {
    int i = blockIdx.x * blockDim.x + threadIdx.x;
    if (i < n) out[i] = f2b(in[i]);
}

// W[K][N] f32 -> Wt[N][K] bf16
__global__ __launch_bounds__(256) void wt_bf16_k(const float* __restrict__ W, unsigned short* __restrict__ Wt, int K, int N) {
    int idx = blockIdx.x * blockDim.x + threadIdx.x;
    if (idx >= K * N) return;
    int k = idx / N, n = idx % N;
    Wt[n * K + k] = f2b(W[idx]);
}

// ---------------- two-level exclusive scan (1024 elems / block) ----------------

__global__ __launch_bounds__(256) void scan1_k(const int* __restrict__ cnt, int* __restrict__ excl,
                                               int* __restrict__ bsum, int n) {
    __shared__ int sdata[256];
    const int tid = threadIdx.x;
    const int base = blockIdx.x * 1024 + tid * 4;
    int v[4]; int s = 0;
#pragma unroll
    for (int j = 0; j < 4; ++j) { v[j] = (base + j < n) ? cnt[base + j] : 0; s += v[j]; }
    sdata[tid] = s; __syncthreads();
    for (int off = 1; off < 256; off <<= 1) {
        int t = (tid >= off) ? sdata[tid - off] : 0;
        __syncthreads();
        sdata[tid] += t;
        __syncthreads();
    }
    if (tid == 255) bsum[blockIdx.x] = sdata[255];
    int run = sdata[tid] - s;
#pragma unroll
    for (int j = 0; j < 4; ++j) { if (base + j < n) excl[base + j] = run; run += v[j]; }
}

__global__ __launch_bounds__(256) void scan2_k(int* bsum, int nb) {
    __shared__ int sdata[256];
    const int tid = threadIdx.x;
    int v = (tid < nb) ? bsum[tid] : 0;
    sdata[tid] = v; __syncthreads();
    for (int off = 1; off < 256; off <<= 1) {
        int t = (tid >= off) ? sdata[tid - off] : 0;
        __syncthreads();
        sdata[tid] += t;
        __syncthreads();
    }
    if (tid < nb) bsum[tid] = sdata[tid] - v;
}

__global__ __launch_bounds__(256) void finalize_k(const int* __restrict__ cnt, int* rowptr,
                                                  const int* __restrict__ boff, int* cursor,
                                                  float* dinv, int n, int e) {
    int i = blockIdx.x * blockDim.x + threadIdx.x;
    if (i < n) {
        int c = cnt[i];
        int r = rowptr[i] + boff[i >> 10];
        rowptr[i] = r;
        cursor[i] = r;
        dinv[i] = 1.0f / (float)(c + 1);
    }
    if (i == 0) rowptr[n] = e;
}

// cse[pos] = (src, bitcast(rsqrt(deg_s*deg_d)))
__global__ __launch_bounds__(256) void csr_scatter_k(const int* __restrict__ src, const int* __restrict__ dst,
                                                     int* cursor, const float* __restrict__ dinv,
                                                     int2* __restrict__ cse, int e) {
    int i = blockIdx.x * blockDim.x + threadIdx.x;
    if (i >= e) return;
    int s = src[i], d = dst[i];
    int pos = atomicAdd(&cursor[d], 1);
    cse[pos] = make_int2(s, __float_as_int(sqrtf(dinv[s] * dinv[d])));
}

// ---------------- MFMA GEMM: H[M][N] (bf16) = X[M][K] (bf16) @ Wt[N][K]^T ----------------
template<int K, int N, bool GUARD>
__global__ __launch_bounds__(256) void gemm_mfma_k(const unsigned short* __restrict__ X,
                                                   const unsigned short* __restrict__ Wt,
                                                   unsigned short* __restrict__ H, int M) {
    constexpr int GPR = K / 8;
    __shared__ unsigned short sA[64 * K];
    __shared__ unsigned short sB[N * K];
    const int tid  = threadIdx.x;
    const int row0 = blockIdx.x * 64;

    for (int idx = tid; idx < 64 * GPR; idx += 256) {
        int r = idx / GPR, g = idx % GPR;
        uint4 v = make_uint4(0u, 0u, 0u, 0u);
        if (!GUARD || row0 + r < M)
            v = *(const uint4*)&X[(size_t)(row0 + r) * K + g * 8];
        int gs = g ^ (r & (GPR - 1));
        *(uint4*)&sA[r * K + gs * 8] = v;
    }
    for (int idx = tid; idx < N * GPR; idx += 256) {
        int r = idx / GPR, g = idx % GPR;
        uint4 v = *(const uint4*)&Wt[(size_t)r * K + g * 8];
        int gs = g ^ (r & (GPR - 1));
        *(uint4*)&sB[r * K + gs * 8] = v;
    }
    __syncthreads();

    const int wave = tid >> 6, lane = tid & 63;
    const int rA = wave * 16 + (lane & 15);
    const int kg = lane >> 4;

    f32x4 zero = {0.f, 0.f, 0.f, 0.f};
    f32x4 acc[N / 16];
#pragma unroll
    for (int t = 0; t < N / 16; ++t) acc[t] = zero;

#pragma unroll
    for (int ks = 0; ks < K / 32; ++ks) {
        int gA = (ks * 4 + kg) ^ (rA & (GPR - 1));
        bf16x8 a = *(const bf16x8*)&sA[rA * K + gA * 8];
#pragma unroll
        for (int t = 0; t < N / 16; ++t) {
            int rB = t * 16 + (lane & 15);
            int gB = (ks * 4 + kg) ^ (rB & (GPR - 1));
            bf16x8 b = *(const bf16x8*)&sB[rB * K + gB * 8];
            acc[t] = __builtin_amdgcn_mfma_f32_16x16x32_bf16(a, b, acc[t], 0, 0, 0);
        }
    }

    const int crow = wave * 16 + (lane >> 4) * 4;
    const int ccol = lane & 15;
#pragma unroll
    for (int t = 0; t < N / 16; ++t) {
#pragma unroll
        for (int j = 0; j < 4; ++j) {
            int r = row0 + crow + j;
            if (!GUARD || r < M)
                H[(size_t)r * N + t * 16 + ccol] = f2b(acc[t][j]);
        }
    }
}

// ---------------- fused GCN aggregation (gather, 8-deep pipelined) ----------------
// out[i] = [relu]( sum_e h[src_e]*w_e + h[i]*dinv[i] + bias )

template<bool RELU>
__global__ __launch_bounds__(256) void gather128b_k(const int* __restrict__ rowptr,
                                                    const int2* __restrict__ cse,
                                                    const unsigned short* __restrict__ h,
                                                    const float* __restrict__ dinv,
                                                    const float* __restrict__ bias,
                                                    unsigned short* __restrict__ out, int n) {
    int node = (blockIdx.x * blockDim.x + threadIdx.x) >> 6;   // one wave per node
    int lane = threadIdx.x & 63;
    if (node >= n) return;
    int beg = rowptr[node], end = rowptr[node + 1];
    int c = lane * 2;
    float ax = 0.f, ay = 0.f;
    for (int e0 = beg; e0 < end; e0 += 8) {
        int2 q[8]; unsigned int v[8];
#pragma unroll
        for (int t = 0; t < 8; ++t) {
            int e = e0 + t;
            q[t] = cse[e < end ? e : end - 1];
        }
#pragma unroll
        for (int t = 0; t < 8; ++t)
            v[t] = *(const unsigned int*)&h[(size_t)q[t].x * 128 + c];
#pragma unroll
        for (int t = 0; t < 8; ++t) {
            float w = (e0 + t < end) ? __int_as_float(q[t].y) : 0.f;
            ax = fmaf(b2f((unsigned short)v[t]), w, ax);
            ay = fmaf(b2f((unsigned short)(v[t] >> 16)), w, ay);
        }
    }
    float iv = dinv[node];
    unsigned int hv = *(const unsigned int*)&h[(size_t)node * 128 + c];
    float2 bb = *(const float2*)&bias[c];
    float ox = fmaf(b2f((unsigned short)hv), iv, ax) + bb.x;
    float oy = fmaf(b2f((unsigned short)(hv >> 16)), iv, ay) + bb.y;
    if (RELU) { ox = fmaxf(ox, 0.f); oy = fmaxf(oy, 0.f); }
    *(unsigned int*)&out[(size_t)node * 128 + c] = pk2(ox, oy);
}

template<bool RELU>
__global__ __launch_bounds__(256) void gather64b_k(const int* __restrict__ rowptr,
                                                   const int2* __restrict__ cse,
                                                   const unsigned short* __restrict__ h,
                                                   const float* __restrict__ dinv,
                                                   const float* __restrict__ bias,
                                                   unsigned short* __restrict__ out, int n) {
    int gid = blockIdx.x * blockDim.x + threadIdx.x;
    int node = gid >> 5;                                        // half-wave per node
    int sl = gid & 31;
    if (node >= n) return;
    int beg = rowptr[node], end = rowptr[node + 1];
    int c = sl * 2;
    float ax = 0.f, ay = 0.f;
    for (int e0 = beg; e0 < end; e0 += 8) {
        int2 q[8]; unsigned int v[8];
#pragma unroll
        for (int t = 0; t < 8; ++t) {
            int e = e0 + t;
            q[t] = cse[e < end ? e : end - 1];
        }
#pragma unroll
        for (int t = 0; t < 8; ++t)
            v[t] = *(const unsigned int*)&h[(size_t)q[t].x * 64 + c];
#pragma unroll
        for (int t = 0; t < 8; ++t) {
            float w = (e0 + t < end) ? __int_as_float(q[t].y) : 0.f;
            ax = fmaf(b2f((unsigned short)v[t]), w, ax);
            ay = fmaf(b2f((unsigned short)(v[t] >> 16)), w, ay);
        }
    }
    float iv = dinv[node];
    unsigned int hv = *(const unsigned int*)&h[(size_t)node * 64 + c];
    float2 bb = *(const float2*)&bias[c];
    float ox = fmaf(b2f((unsigned short)hv), iv, ax) + bb.x;
    float oy = fmaf(b2f((unsigned short)(hv >> 16)), iv, ay) + bb.y;
    if (RELU) { ox = fmaxf(ox, 0.f); oy = fmaxf(oy, 0.f); }
    *(unsigned int*)&out[(size_t)node * 64 + c] = pk2(ox, oy);
}

// building layer-2 gather fused with layer-3 XW (64 -> 2): writes Dh[node][2] f32
__global__ __launch_bounds__(256) void gather64_dot_k(const int* __restrict__ rowptr,
                                                      const int2* __restrict__ cse,
                                                      const unsigned short* __restrict__ h,
                                                      const float* __restrict__ dinv,
                                                      const float* __restrict__ bias,
                                                      const float* __restrict__ W3,  // [64 x 2]
                                                      float* __restrict__ Dh, int n) {
    int gid = blockIdx.x * blockDim.x + threadIdx.x;
    int node = gid >> 5;
    int sl = gid & 31;
    if (node >= n) return;
    int beg = rowptr[node], end = rowptr[node + 1];
    int c = sl * 2;
    float ax = 0.f, ay = 0.f;
    for (int e0 = beg; e0 < end; e0 += 8) {
        int2 q[8]; unsigned int v[8];
#pragma unroll
        for (int t = 0; t < 8; ++t) {
            int e = e0 + t;
            q[t] = cse[e < end ? e : end - 1];
        }
#pragma unroll
        for (int t = 0; t < 8; ++t)
            v[t] = *(const unsigned int*)&h[(size_t)q[t].x * 64 + c];
#pragma unroll
        for (int t = 0; t < 8; ++t) {
            float w = (e0 + t < end) ? __int_as_float(q[t].y) : 0.f;
            ax = fmaf(b2f((unsigned short)v[t]), w, ax);
            ay = fmaf(b2f((unsigned short)(v[t] >> 16)), w, ay);
        }
    }
    float iv = dinv[node];
    unsigned int hv = *(const unsigned int*)&h[(size_t)node * 64 + c];
    float2 bb = *(const float2*)&bias[c];
    float ox = fmaf(b2f((unsigned short)hv), iv, ax) + bb.x;
    float oy = fmaf(b2f((unsigned short)(hv >> 16)), iv, ay) + bb.y;
    ox = fmaxf(ox, 0.f); oy = fmaxf(oy, 0.f);
    // dot with W3 columns
    float4 w4 = *(const float4*)&W3[c * 2];   // W3[c][0], W3[c][1], W3[c+1][0], W3[c+1][1]
    float d0 = fmaf(ox, w4.x, oy * w4.z);
    float d1 = fmaf(ox, w4.y, oy * w4.w);
#pragma unroll
    for (int m = 1; m < 32; m <<= 1) {
        d0 += __shfl_xor(d0, m, 32);
        d1 += __shfl_xor(d1, m, 32);
    }
    if (sl == 0) {
        Dh[2 * (size_t)node + 0] = d0;
        Dh[2 * (size_t)node + 1] = d1;
    }
}

// final layer: gather (F=2, f32) + bias + log-softmax + scatter to global order
__global__ __launch_bounds__(256) void gather2_logsm_k(const int* __restrict__ rowptr,
                                                       const int2* __restrict__ cse,
                                                       const float* __restrict__ h2,
                                                       const float* __restrict__ dinv,
                                                       const float* __restrict__ bias,
                                                       const int* __restrict__ l2g,
                                                       float* __restrict__ out, int n) {
    int i = blockIdx.x * blockDim.x + threadIdx.x;
    if (i >= n) return;
    int beg = rowptr[i], end = rowptr[i + 1];
    float a = 0.f, b = 0.f;
    for (int e0 = beg; e0 < end; e0 += 4) {
        int2 q[4]; float2 v[4];
#pragma unroll
        for (int t = 0; t < 4; ++t) {
            int e = e0 + t;
            q[t] = cse[e < end ? e : end - 1];
        }
#pragma unroll
        for (int t = 0; t < 4; ++t)
            v[t] = *(const float2*)&h2[2 * (size_t)q[t].x];
#pragma unroll
        for (int t = 0; t < 4; ++t) {
            float w = (e0 + t < end) ? __int_as_float(q[t].y) : 0.f;
            a = fmaf(v[t].x, w, a);
            b = fmaf(v[t].y, w, b);
        }
    }
    float iv = dinv[i];
    float2 hv = *(const float2*)&h2[2 * (size_t)i];
    a = fmaf(hv.x, iv, a) + bias[0];
    b = fmaf(hv.y, iv, b) + bias[1];
    float m = fmaxf(a, b);
    float ls = m + logf(__expf(a - m) + __expf(b - m));
    int g = l2g[i];
    out[2 * (size_t)g + 0] = a - ls;
    out[2 * (size_t)g + 1] = b - ls;
}

// ---------------- attention fuse: 8 lanes per node (coalesced) ----------------
__global__ __launch_bounds__(256) void att_fuse_k(const float* __restrict__ bf,
                                                  const unsigned short* __restrict__ cx,
                                                  const int* __restrict__ map,
                                                  const int* __restrict__ l2g,
                                                  const float* __restrict__ Watt,  // [128 x 2]
                                                  const float* __restrict__ batt,  // [2]
                                                  unsigned short* __restrict__ fused, int n) {
    __shared__ float sW0[128], sW1[128];
    if (threadIdx.x < 128) {
        sW0[threadIdx.x] = Watt[threadIdx.x * 2 + 0];
        sW1[threadIdx.x] = Watt[threadIdx.x * 2 + 1];
    }
    __syncthreads();
    int gid = blockIdx.x * blockDim.x + threadIdx.x;
    int i = gid >> 3;          // node
    int j = gid & 7;           // 8-lane group slot: channels j*8 .. j*8+7
    if (i >= n) return;
    int g = l2g[i];
    const float* f1 = &bf[(size_t)g * 64 + j * 8];
    const unsigned short* f2 = &cx[(size_t)map[g] * 64 + j * 8];
    float r1[8], r2[8];
    {
        float4 v0 = *(const float4*)&f1[0];
        float4 v1 = *(const float4*)&f1[4];
        r1[0]=v0.x; r1[1]=v0.y; r1[2]=v0.z; r1[3]=v0.w;
        r1[4]=v1.x; r1[5]=v1.y; r1[6]=v1.z; r1[7]=v1.w;
        uint4 u = *(const uint4*)&f2[0];
        up8(u, r2);
    }
    float l0 = 0.f, l1 = 0.f;
#pragma unroll
    for (int k = 0; k < 8; ++k) {
        l0 = fmaf(r1[k], sW0[j * 8 + k], l0);
        l1 = fmaf(r1[k], sW1[j * 8 + k], l1);
        l0 = fmaf(r2[k], sW0[64 + j * 8 + k], l0);
        l1 = fmaf(r2[k], sW1[64 + j * 8 + k], l1);
    }
#pragma unroll
    for (int m = 1; m < 8; m <<= 1) {
        l0 += __shfl_xor(l0, m, 8);
        l1 += __shfl_xor(l1, m, 8);
    }
    l0 += batt[0]; l1 += batt[1];
    float m  = fmaxf(l0, l1);
    float e0 = __expf(l0 - m), e1 = __expf(l1 - m);
    float inv = 1.0f / (e0 + e1);
    float a0 = e0 * inv, a1 = e1 * inv;
    unsigned short* fo = &fused[(size_t)i * 128];
    uint4 o1, o2;
    o1.x = pk2(r1[0]*a0, r1[1]*a0); o1.y = pk2(r1[2]*a0, r1[3]*a0);
    o1.z = pk2(r1[4]*a0, r1[5]*a0); o1.w = pk2(r1[6]*a0, r1[7]*a0);
    o2.x = pk2(r2[0]*a1, r2[1]*a1); o2.y = pk2(r2[2]*a1, r2[3]*a1);
    o2.z = pk2(r2[4]*a1, r2[5]*a1); o2.w = pk2(r2[6]*a1, r2[7]*a1);
    *(uint4*)&fo[j * 8] = o1;
    *(uint4*)&fo[64 + j * 8] = o2;
}

// ---------------- launch ----------------

static inline dim3 g1(long long n, int tpb = 256) { return dim3((unsigned)((n + tpb - 1) / tpb)); }

extern "C" void kernel_launch(void* const* d_in, const int* in_sizes, int n_in,
                              void* d_out, int out_size, void* d_ws, size_t ws_size,
                              hipStream_t stream) {
    const float* bF   = (const float*)d_in[0];
    const float* cF   = (const float*)d_in[1];
    const float* W_c1 = (const float*)d_in[2];
    const float* b_c1 = (const float*)d_in[3];
    const float* W_c2 = (const float*)d_in[4];
    const float* b_c2 = (const float*)d_in[5];
    const float* W_at = (const float*)d_in[6];
    const float* b_at = (const float*)d_in[7];
    const float* W_b1 = (const float*)d_in[8];
    const float* b_b1 = (const float*)d_in[9];
    const float* W_b2 = (const float*)d_in[10];
    const float* b_b2 = (const float*)d_in[11];
    const float* W_b3 = (const float*)d_in[12];
    const float* b_b3 = (const float*)d_in[13];
    const int* b_src = (const int*)d_in[14];
    const int* b_dst = (const int*)d_in[15];
    const int* c_src = (const int*)d_in[16];
    const int* c_dst = (const int*)d_in[17];
    const int* map   = (const int*)d_in[18];
    const int* l2g   = (const int*)d_in[19];
    float* out = (float*)d_out;

    char* p = (char*)d_ws;
    auto alloc = [&](size_t bytes) { char* q = p; p += (bytes + 15) & ~(size_t)15; return q; };
    int*   cnt_b    = (int*)  alloc(N_BUILD * 4);
    int*   rowptr_b = (int*)  alloc((N_BUILD + 4) * 4);
    int*   cursor_b = (int*)  alloc(N_BUILD * 4);
    int*   bsum_b   = (int*)  alloc(256 * 4);
    int*   cnt_c    = (int*)  alloc(N_COMM * 4);
    int*   rowptr_c = (int*)  alloc((N_COMM + 4) * 4);
    int*   cursor_c = (int*)  alloc(N_COMM * 4);
    int*   bsum_c   = (int*)  alloc(256 * 4);
    int2*  cse_b    = (int2*) alloc((size_t)E_BUILD * 8);
    int2*  cse_c    = (int2*) alloc((size_t)E_COMM * 8);
    float* dinv_b   = (float*)alloc(N_BUILD * 4);
    float* dinv_c   = (float*)alloc(N_COMM * 4);
    unsigned short* cFb    = (unsigned short*)alloc((size_t)N_COMM * 32 * 2);
    unsigned short* Wt_c1  = (unsigned short*)alloc(64 * 32 * 2);
    unsigned short* Wt_c2  = (unsigned short*)alloc(64 * 64 * 2);
    unsigned short* Wt_b1  = (unsigned short*)alloc(128 * 128 * 2);
    unsigned short* Wt_b2  = (unsigned short*)alloc(64 * 128 * 2);
    unsigned short* ch_bf  = (unsigned short*)alloc((size_t)N_COMM * 64 * 2);
    unsigned short* cx1_bf = (unsigned short*)alloc((size_t)N_COMM * 64 * 2);
    unsigned short* cx2_bf = (unsigned short*)alloc((size_t)N_COMM * 64 * 2);
    unsigned short* A_bf   = (unsigned short*)alloc((size_t)N_BUILD * 128 * 2); // fused / o1
    unsigned short* B_bf   = (unsigned short*)alloc((size_t)N_BUILD * 128 * 2); // h1 / h2
    float* Dh = (float*)alloc((size_t)N_BUILD * 2 * 4);

    const int nb_b = (N_BUILD + 1023) / 1024;
    const int nb_c = (N_COMM  + 1023) / 1024;

    // ---- weight / input conversions ----
    cvt_bf16_k<<<g1((long long)N_COMM * 32), 256, 0, stream>>>(cF, cFb, N_COMM * 32);
    wt_bf16_k<<<g1(32 * 64), 256, 0, stream>>>(W_c1, Wt_c1, 32, 64);
    wt_bf16_k<<<g1(64 * 64), 256, 0, stream>>>(W_c2, Wt_c2, 64, 64);
    wt_bf16_k<<<g1(128 * 128), 256, 0, stream>>>(W_b1, Wt_b1, 128, 128);
    wt_bf16_k<<<g1(128 * 64), 256, 0, stream>>>(W_b2, Wt_b2, 128, 64);

    // ---- build community CSR ----
    fill_i_k<<<g1(N_COMM), 256, 0, stream>>>(cnt_c, 0, N_COMM);
    hist_k<<<g1(E_COMM), 256, 0, stream>>>(cnt_c, c_dst, E_COMM);
    scan1_k<<<nb_c, 256, 0, stream>>>(cnt_c, rowptr_c, bsum_c, N_COMM);
    scan2_k<<<1, 256, 0, stream>>>(bsum_c, nb_c);
    finalize_k<<<g1(N_COMM), 256, 0, stream>>>(cnt_c, rowptr_c, bsum_c, cursor_c, dinv_c, N_COMM, E_COMM);
    csr_scatter_k<<<g1(E_COMM), 256, 0, stream>>>(c_src, c_dst, cursor_c, dinv_c, cse_c, E_COMM);

    // ---- build building CSR ----
    fill_i_k<<<g1(N_BUILD), 256, 0, stream>>>(cnt_b, 0, N_BUILD);
    hist_k<<<g1(E_BUILD), 256, 0, stream>>>(cnt_b, b_dst, E_BUILD);
    scan1_k<<<nb_b, 256, 0, stream>>>(cnt_b, rowptr_b, bsum_b, N_BUILD);
    scan2_k<<<1, 256, 0, stream>>>(bsum_b, nb_b);
    finalize_k<<<g1(N_BUILD), 256, 0, stream>>>(cnt_b, rowptr_b, bsum_b, cursor_b, dinv_b, N_BUILD, E_BUILD);
    csr_scatter_k<<<g1(E_BUILD), 256, 0, stream>>>(b_src, b_dst, cursor_b, dinv_b, cse_b, E_BUILD);

    // ---- community GCN layer 1 (32 -> 64) + relu ----
    gemm_mfma_k<32, 64, true><<<dim3((N_COMM + 63) / 64), 256, 0, stream>>>(cFb, Wt_c1, ch_bf, N_COMM);
    gather64b_k<true><<<g1((long long)N_COMM * 32), 256, 0, stream>>>(rowptr_c, cse_c, ch_bf, dinv_c, b_c1, cx1_bf, N_COMM);

    // ---- community GCN layer 2 (64 -> 64) + relu ----
    gemm_mfma_k<64, 64, true><<<dim3((N_COMM + 63) / 64), 256, 0, stream>>>(cx1_bf, Wt_c2, ch_bf, N_COMM);
    gather64b_k<true><<<g1((long long)N_COMM * 32), 256, 0, stream>>>(rowptr_c, cse_c, ch_bf, dinv_c, b_c2, cx2_bf, N_COMM);

    // ---- attention fuse -> fused (A_bf, 128-wide bf16) ----
    att_fuse_k<<<g1((long long)N_BUILD * 8), 256, 0, stream>>>(bF, cx2_bf, map, l2g, W_at, b_at, A_bf, N_BUILD);

    // ---- building GCN layer 1 (128 -> 128) + relu ----
    gemm_mfma_k<128, 128, false><<<dim3(N_BUILD / 64), 256, 0, stream>>>(A_bf, Wt_b1, B_bf, N_BUILD);
    gather128b_k<true><<<g1((long long)N_BUILD * 64), 256, 0, stream>>>(rowptr_b, cse_b, B_bf, dinv_b, b_b1, A_bf, N_BUILD);

    // ---- building GCN layer 2 (128 -> 64) + relu, fused with layer-3 XW ----
    gemm_mfma_k<128, 64, false><<<dim3(N_BUILD / 64), 256, 0, stream>>>(A_bf, Wt_b2, B_bf, N_BUILD);
    gather64_dot_k<<<g1((long long)N_BUILD * 32), 256, 0, stream>>>(rowptr_b, cse_b, B_bf, dinv_b, b_b2, W_b3, Dh, N_BUILD);

    // ---- building GCN layer 3 aggregation + log-softmax + scatter ----
    fill_f_k<<<g1((long long)N_BUILD * 2), 256, 0, stream>>>(out, -0.69314718056f, N_BUILD * 2);
    gather2_logsm_k<<<g1(N_BUILD), 256, 0, stream>>>(rowptr_b, cse_b, Dh, dinv_b, b_b3, l2g, out, N_BUILD);
}

// Round 5
// 380.374 us; speedup vs baseline: 10.1737x; 1.0718x over previous
//
#include <hip/hip_runtime.h>
#include <hip/hip_bf16.h>
#include <math.h>

#define N_BUILD 200000
#define N_COMM  10000
#define E_BUILD 1200000
#define E_COMM  160000
#define NB_B 196   // scan blocks for building (200000/1024 rounded up)
#define NB_C 10

typedef __bf16 bf16x8 __attribute__((ext_vector_type(8)));
typedef float  f32x4  __attribute__((ext_vector_type(4)));

// ---------------- bf16 helpers (RNE) ----------------
__device__ __forceinline__ unsigned short f2b(float f) {
    unsigned int u = __builtin_bit_cast(unsigned int, f);
    u += 0x7fffu + ((u >> 16) & 1u);
    return (unsigned short)(u >> 16);
}
__device__ __forceinline__ float b2f(unsigned short h) {
    unsigned int u = ((unsigned int)h) << 16;
    return __builtin_bit_cast(float, u);
}
__device__ __forceinline__ unsigned int pk2(float a, float b) {
    return (unsigned int)f2b(a) | ((unsigned int)f2b(b) << 16);
}
__device__ __forceinline__ void up8(uint4 v, float* r) {
    r[0] = b2f((unsigned short)v.x); r[1] = b2f((unsigned short)(v.x >> 16));
    r[2] = b2f((unsigned short)v.y); r[3] = b2f((unsigned short)(v.y >> 16));
    r[4] = b2f((unsigned short)v.z); r[5] = b2f((unsigned short)(v.z >> 16));
    r[6] = b2f((unsigned short)v.w); r[7] = b2f((unsigned short)(v.w >> 16));
}

// ---------------- merged prep: cF cvt + all weight transposes ----------------
__global__ __launch_bounds__(256) void prep_k(const float* __restrict__ cF, unsigned short* __restrict__ cFb,
                                              const float* __restrict__ W_c1, unsigned short* __restrict__ Wt_c1,
                                              const float* __restrict__ W_c2, unsigned short* __restrict__ Wt_c2,
                                              const float* __restrict__ W_b1, unsigned short* __restrict__ Wt_b1,
                                              const float* __restrict__ W_b2, unsigned short* __restrict__ Wt_b2) {
    int idx = blockIdx.x * blockDim.x + threadIdx.x;
    if (idx < N_COMM * 32) { cFb[idx] = f2b(cF[idx]); return; }
    idx -= N_COMM * 32;
    if (idx < 2048) { int k = idx / 64, n = idx % 64; Wt_c1[n * 32 + k] = f2b(W_c1[idx]); return; }
    idx -= 2048;
    if (idx < 4096) { int k = idx / 64, n = idx % 64; Wt_c2[n * 64 + k] = f2b(W_c2[idx]); return; }
    idx -= 4096;
    if (idx < 16384) { int k = idx / 128, n = idx % 128; Wt_b1[n * 128 + k] = f2b(W_b1[idx]); return; }
    idx -= 16384;
    if (idx < 8192) { int k = idx / 64, n = idx % 64; Wt_b2[n * 128 + k] = f2b(W_b2[idx]); }
}

// ---------------- merged CSR build kernels (both graphs per launch) ----------------

__global__ __launch_bounds__(256) void fill2_k(int* cnt_b, int* cnt_c, float* out) {
    int i = blockIdx.x * blockDim.x + threadIdx.x;
    if (i < N_BUILD) cnt_b[i] = 0;
    else if (i < N_BUILD + N_COMM) cnt_c[i - N_BUILD] = 0;
    else if (i < N_BUILD + N_COMM + 2 * N_BUILD) out[i - N_BUILD - N_COMM] = -0.69314718056f;
}

__global__ __launch_bounds__(256) void hist2_k(int* cnt_b, const int* __restrict__ b_dst,
                                               int* cnt_c, const int* __restrict__ c_dst) {
    int i = blockIdx.x * blockDim.x + threadIdx.x;
    if (i < E_BUILD) atomicAdd(&cnt_b[b_dst[i]], 1);
    else if (i < E_BUILD + E_COMM) atomicAdd(&cnt_c[c_dst[i - E_BUILD]], 1);
}

__global__ __launch_bounds__(256) void scan1m_k(const int* __restrict__ cnt_b, int* __restrict__ ex_b, int* __restrict__ bs_b,
                                                const int* __restrict__ cnt_c, int* __restrict__ ex_c, int* __restrict__ bs_c) {
    __shared__ int sdata[256];
    const int tid = threadIdx.x;
    const int* cnt; int* ex; int* bs; int n, blk;
    if ((int)blockIdx.x < NB_B) { cnt = cnt_b; ex = ex_b; bs = bs_b; n = N_BUILD; blk = blockIdx.x; }
    else                        { cnt = cnt_c; ex = ex_c; bs = bs_c; n = N_COMM;  blk = blockIdx.x - NB_B; }
    const int base = blk * 1024 + tid * 4;
    int v[4]; int s = 0;
#pragma unroll
    for (int j = 0; j < 4; ++j) { v[j] = (base + j < n) ? cnt[base + j] : 0; s += v[j]; }
    sdata[tid] = s; __syncthreads();
    for (int off = 1; off < 256; off <<= 1) {
        int t = (tid >= off) ? sdata[tid - off] : 0;
        __syncthreads();
        sdata[tid] += t;
        __syncthreads();
    }
    if (tid == 255) bs[blk] = sdata[255];
    int run = sdata[tid] - s;
#pragma unroll
    for (int j = 0; j < 4; ++j) { if (base + j < n) ex[base + j] = run; run += v[j]; }
}

__global__ __launch_bounds__(256) void scan2m_k(int* bs_b, int* bs_c) {
    __shared__ int sdata[256];
    int* bs = (blockIdx.x == 0) ? bs_b : bs_c;
    int nb  = (blockIdx.x == 0) ? NB_B : NB_C;
    const int tid = threadIdx.x;
    int v = (tid < nb) ? bs[tid] : 0;
    sdata[tid] = v; __syncthreads();
    for (int off = 1; off < 256; off <<= 1) {
        int t = (tid >= off) ? sdata[tid - off] : 0;
        __syncthreads();
        sdata[tid] += t;
        __syncthreads();
    }
    if (tid < nb) bs[tid] = sdata[tid] - v;
}

__global__ __launch_bounds__(256) void finalizem_k(const int* __restrict__ cnt_b, int* rp_b, const int* __restrict__ bo_b,
                                                   int* cur_b, float* di_b,
                                                   const int* __restrict__ cnt_c, int* rp_c, const int* __restrict__ bo_c,
                                                   int* cur_c, float* di_c) {
    int i = blockIdx.x * blockDim.x + threadIdx.x;
    if (i < N_BUILD) {
        int cc = cnt_b[i];
        int r = rp_b[i] + bo_b[i >> 10];
        rp_b[i] = r; cur_b[i] = r; di_b[i] = 1.0f / (float)(cc + 1);
        if (i == 0) { rp_b[N_BUILD] = E_BUILD; rp_c[N_COMM] = E_COMM; }
    } else if (i < N_BUILD + N_COMM) {
        int ic = i - N_BUILD;
        int cc = cnt_c[ic];
        int r = rp_c[ic] + bo_c[ic >> 10];
        rp_c[ic] = r; cur_c[ic] = r; di_c[ic] = 1.0f / (float)(cc + 1);
    }
}

__global__ __launch_bounds__(256) void csr_scatterm_k(const int* __restrict__ b_src, const int* __restrict__ b_dst,
                                                      int* cur_b, const float* __restrict__ di_b, int2* __restrict__ cse_b,
                                                      const int* __restrict__ c_src, const int* __restrict__ c_dst,
                                                      int* cur_c, const float* __restrict__ di_c, int2* __restrict__ cse_c) {
    int i = blockIdx.x * blockDim.x + threadIdx.x;
    if (i < E_BUILD) {
        int s = b_src[i], d = b_dst[i];
        int pos = atomicAdd(&cur_b[d], 1);
        cse_b[pos] = make_int2(s, __float_as_int(sqrtf(di_b[s] * di_b[d])));
    } else if (i < E_BUILD + E_COMM) {
        int ie = i - E_BUILD;
        int s = c_src[ie], d = c_dst[ie];
        int pos = atomicAdd(&cur_c[d], 1);
        cse_c[pos] = make_int2(s, __float_as_int(sqrtf(di_c[s] * di_c[d])));
    }
}

// ---------------- MFMA GEMM: H[M][N] (bf16) = X[M][K] (bf16) @ Wt[N][K]^T ----------------
template<int K, int N, bool GUARD>
__global__ __launch_bounds__(256) void gemm_mfma_k(const unsigned short* __restrict__ X,
                                                   const unsigned short* __restrict__ Wt,
                                                   unsigned short* __restrict__ H, int M) {
    constexpr int GPR = K / 8;
    __shared__ unsigned short sA[64 * K];
    __shared__ unsigned short sB[N * K];
    const int tid  = threadIdx.x;
    const int row0 = blockIdx.x * 64;

    for (int idx = tid; idx < 64 * GPR; idx += 256) {
        int r = idx / GPR, g = idx % GPR;
        uint4 v = make_uint4(0u, 0u, 0u, 0u);
        if (!GUARD || row0 + r < M)
            v = *(const uint4*)&X[(size_t)(row0 + r) * K + g * 8];
        int gs = g ^ (r & (GPR - 1));
        *(uint4*)&sA[r * K + gs * 8] = v;
    }
    for (int idx = tid; idx < N * GPR; idx += 256) {
        int r = idx / GPR, g = idx % GPR;
        uint4 v = *(const uint4*)&Wt[(size_t)r * K + g * 8];
        int gs = g ^ (r & (GPR - 1));
        *(uint4*)&sB[r * K + gs * 8] = v;
    }
    __syncthreads();

    const int wave = tid >> 6, lane = tid & 63;
    const int rA = wave * 16 + (lane & 15);
    const int kg = lane >> 4;

    f32x4 zero = {0.f, 0.f, 0.f, 0.f};
    f32x4 acc[N / 16];
#pragma unroll
    for (int t = 0; t < N / 16; ++t) acc[t] = zero;

#pragma unroll
    for (int ks = 0; ks < K / 32; ++ks) {
        int gA = (ks * 4 + kg) ^ (rA & (GPR - 1));
        bf16x8 a = *(const bf16x8*)&sA[rA * K + gA * 8];
#pragma unroll
        for (int t = 0; t < N / 16; ++t) {
            int rB = t * 16 + (lane & 15);
            int gB = (ks * 4 + kg) ^ (rB & (GPR - 1));
            bf16x8 b = *(const bf16x8*)&sB[rB * K + gB * 8];
            acc[t] = __builtin_amdgcn_mfma_f32_16x16x32_bf16(a, b, acc[t], 0, 0, 0);
        }
    }

    const int crow = wave * 16 + (lane >> 4) * 4;
    const int ccol = lane & 15;
#pragma unroll
    for (int t = 0; t < N / 16; ++t) {
#pragma unroll
        for (int j = 0; j < 4; ++j) {
            int r = row0 + crow + j;
            if (!GUARD || r < M)
                H[(size_t)r * N + t * 16 + ccol] = f2b(acc[t][j]);
        }
    }
}

// ---------------- fused attention + building GEMM layer 1 (K=N=128) ----------------
// A-tile rows are computed on the fly: fused[i] = [bF[g]*a0, cx[map[g]]*a1],
// a = softmax([bF,cx] @ Watt + batt). 4 threads per row, shfl-reduce width 4.
__global__ __launch_bounds__(256) void gemm_att_k(const float* __restrict__ bF,
                                                  const unsigned short* __restrict__ cx,
                                                  const int* __restrict__ map,
                                                  const int* __restrict__ l2g,
                                                  const float* __restrict__ Watt,  // [128][2]
                                                  const float* __restrict__ batt,  // [2]
                                                  const unsigned short* __restrict__ Wt,  // [128][128]
                                                  unsigned short* __restrict__ H) {
    constexpr int K = 128, N = 128, GPR = 16;
    __shared__ unsigned short sA[64 * K];
    __shared__ unsigned short sB[N * K];
    __shared__ float sWt[256];
    const int tid = threadIdx.x;
    const int row0 = blockIdx.x * 64;
    sWt[tid] = Watt[tid];
    for (int idx = tid; idx < N * GPR; idx += 256) {
        int r = idx / GPR, g = idx % GPR;
        uint4 v = *(const uint4*)&Wt[(size_t)r * K + g * 8];
        int gs = g ^ (r & (GPR - 1));
        *(uint4*)&sB[r * K + gs * 8] = v;
    }
    __syncthreads();
    {
        const int r = tid >> 2, j = tid & 3;   // N_BUILD % 64 == 0 -> no guard
        const int g = l2g[row0 + r];
        float vals[32];
        if (j < 2) {
            const float* f1 = &bF[(size_t)g * 64 + j * 32];
#pragma unroll
            for (int t = 0; t < 8; ++t) {
                float4 v = *(const float4*)&f1[t * 4];
                vals[t*4+0]=v.x; vals[t*4+1]=v.y; vals[t*4+2]=v.z; vals[t*4+3]=v.w;
            }
        } else {
            const unsigned short* f2 = &cx[(size_t)map[g] * 64 + (j & 1) * 32];
#pragma unroll
            for (int t = 0; t < 4; ++t) {
                uint4 u = *(const uint4*)&f2[t * 8];
                up8(u, &vals[t * 8]);
            }
        }
        float l0 = 0.f, l1 = 0.f;
        const int ch0 = j * 32;
#pragma unroll
        for (int t = 0; t < 32; ++t) {
            l0 = fmaf(vals[t], sWt[(ch0 + t) * 2 + 0], l0);
            l1 = fmaf(vals[t], sWt[(ch0 + t) * 2 + 1], l1);
        }
        l0 += __shfl_xor(l0, 1, 4); l0 += __shfl_xor(l0, 2, 4);
        l1 += __shfl_xor(l1, 1, 4); l1 += __shfl_xor(l1, 2, 4);
        l0 += batt[0]; l1 += batt[1];
        float mm = fmaxf(l0, l1);
        float e0 = __expf(l0 - mm), e1 = __expf(l1 - mm);
        float a = ((j < 2) ? e0 : e1) / (e0 + e1);
#pragma unroll
        for (int t = 0; t < 4; ++t) {
            uint4 o;
            o.x = pk2(vals[t*8+0]*a, vals[t*8+1]*a);
            o.y = pk2(vals[t*8+2]*a, vals[t*8+3]*a);
            o.z = pk2(vals[t*8+4]*a, vals[t*8+5]*a);
            o.w = pk2(vals[t*8+6]*a, vals[t*8+7]*a);
            int gi = j * 4 + t;
            int gs = gi ^ (r & (GPR - 1));
            *(uint4*)&sA[r * K + gs * 8] = o;
        }
    }
    __syncthreads();
    const int wave = tid >> 6, lane = tid & 63;
    const int rA = wave * 16 + (lane & 15);
    const int kg = lane >> 4;
    f32x4 zero = {0.f, 0.f, 0.f, 0.f};
    f32x4 acc[8];
#pragma unroll
    for (int t = 0; t < 8; ++t) acc[t] = zero;
#pragma unroll
    for (int ks = 0; ks < 4; ++ks) {
        int gA = (ks * 4 + kg) ^ (rA & 15);
        bf16x8 a = *(const bf16x8*)&sA[rA * K + gA * 8];
#pragma unroll
        for (int t = 0; t < 8; ++t) {
            int rB = t * 16 + (lane & 15);
            int gB = (ks * 4 + kg) ^ (rB & 15);
            bf16x8 b = *(const bf16x8*)&sB[rB * K + gB * 8];
            acc[t] = __builtin_amdgcn_mfma_f32_16x16x32_bf16(a, b, acc[t], 0, 0, 0);
        }
    }
    const int crow = wave * 16 + (lane >> 4) * 4;
    const int ccol = lane & 15;
#pragma unroll
    for (int t = 0; t < 8; ++t)
#pragma unroll
        for (int jj = 0; jj < 4; ++jj)
            H[(size_t)(row0 + crow + jj) * N + t * 16 + ccol] = f2b(acc[t][jj]);
}

// ---------------- gathers: latency-chain optimized ----------------
// gather128: one wave handles TWO nodes (dual accumulators; uniform cse indices).
template<bool RELU>
__global__ __launch_bounds__(256) void gather128b_k(const int* __restrict__ rowptr,
                                                    const int2* __restrict__ cse,
                                                    const unsigned short* __restrict__ h,
                                                    const float* __restrict__ dinv,
                                                    const float* __restrict__ bias,
                                                    unsigned short* __restrict__ out, int nPair) {
    int wid = (blockIdx.x * blockDim.x + threadIdx.x) >> 6;
    int lane = threadIdx.x & 63;
    if (wid >= nPair) return;
    int n0 = wid * 2;
    int c = lane * 2;
    int b0 = rowptr[n0], m0 = rowptr[n0 + 1], m1 = rowptr[n0 + 2];
    unsigned int hv0 = *(const unsigned int*)&h[(size_t)n0 * 128 + c];
    unsigned int hv1 = *(const unsigned int*)&h[((size_t)n0 + 1) * 128 + c];
    float iv0 = dinv[n0], iv1 = dinv[n0 + 1];
    float2 bb = *(const float2*)&bias[c];
    float ax0 = 0.f, ay0 = 0.f, ax1 = 0.f, ay1 = 0.f;
    int p0 = b0, p1 = m0;
    while (p0 < m0 || p1 < m1) {
        int2 q0[8], q1[8];
        unsigned int v0[8], v1[8];
#pragma unroll
        for (int t = 0; t < 8; ++t) {
            int i0 = p0 + t, i1 = p1 + t;
            q0[t] = cse[i0 < m0 ? i0 : 0];
            q1[t] = cse[i1 < m1 ? i1 : 0];
        }
#pragma unroll
        for (int t = 0; t < 8; ++t) v0[t] = *(const unsigned int*)&h[(size_t)q0[t].x * 128 + c];
#pragma unroll
        for (int t = 0; t < 8; ++t) v1[t] = *(const unsigned int*)&h[(size_t)q1[t].x * 128 + c];
#pragma unroll
        for (int t = 0; t < 8; ++t) {
            float w0 = (p0 + t < m0) ? __int_as_float(q0[t].y) : 0.f;
            float w1 = (p1 + t < m1) ? __int_as_float(q1[t].y) : 0.f;
            ax0 = fmaf(b2f((unsigned short)v0[t]), w0, ax0);
            ay0 = fmaf(b2f((unsigned short)(v0[t] >> 16)), w0, ay0);
            ax1 = fmaf(b2f((unsigned short)v1[t]), w1, ax1);
            ay1 = fmaf(b2f((unsigned short)(v1[t] >> 16)), w1, ay1);
        }
        p0 += 8; p1 += 8;
    }
    float ox0 = fmaf(b2f((unsigned short)hv0), iv0, ax0) + bb.x;
    float oy0 = fmaf(b2f((unsigned short)(hv0 >> 16)), iv0, ay0) + bb.y;
    float ox1 = fmaf(b2f((unsigned short)hv1), iv1, ax1) + bb.x;
    float oy1 = fmaf(b2f((unsigned short)(hv1 >> 16)), iv1, ay1) + bb.y;
    if (RELU) {
        ox0 = fmaxf(ox0, 0.f); oy0 = fmaxf(oy0, 0.f);
        ox1 = fmaxf(ox1, 0.f); oy1 = fmaxf(oy1, 0.f);
    }
    *(unsigned int*)&out[(size_t)n0 * 128 + c] = pk2(ox0, oy0);
    *(unsigned int*)&out[((size_t)n0 + 1) * 128 + c] = pk2(ox1, oy1);
}

// gather64: lane-split — lanes 0-31 node0, lanes 32-63 node1 (divergent trip counts OK).
template<bool RELU>
__global__ __launch_bounds__(256) void gather64b_k(const int* __restrict__ rowptr,
                                                   const int2* __restrict__ cse,
                                                   const unsigned short* __restrict__ h,
                                                   const float* __restrict__ dinv,
                                                   const float* __restrict__ bias,
                                                   unsigned short* __restrict__ out, int nPair) {
    int wid = (blockIdx.x * blockDim.x + threadIdx.x) >> 6;
    int lane = threadIdx.x & 63;
    if (wid >= nPair) return;
    int node = wid * 2 + (lane >> 5);
    int sl = lane & 31, c = sl * 2;
    int beg = rowptr[node], end = rowptr[node + 1];
    unsigned int hv = *(const unsigned int*)&h[(size_t)node * 64 + c];
    float iv = dinv[node];
    float2 bb = *(const float2*)&bias[c];
    float ax = 0.f, ay = 0.f;
    for (int p = beg; p < end; p += 8) {
        int2 q[8]; unsigned int v[8];
#pragma unroll
        for (int t = 0; t < 8; ++t) { int e = p + t; q[t] = cse[e < end ? e : 0]; }
#pragma unroll
        for (int t = 0; t < 8; ++t) v[t] = *(const unsigned int*)&h[(size_t)q[t].x * 64 + c];
#pragma unroll
        for (int t = 0; t < 8; ++t) {
            float w = (p + t < end) ? __int_as_float(q[t].y) : 0.f;
            ax = fmaf(b2f((unsigned short)v[t]), w, ax);
            ay = fmaf(b2f((unsigned short)(v[t] >> 16)), w, ay);
        }
    }
    float ox = fmaf(b2f((unsigned short)hv), iv, ax) + bb.x;
    float oy = fmaf(b2f((unsigned short)(hv >> 16)), iv, ay) + bb.y;
    if (RELU) { ox = fmaxf(ox, 0.f); oy = fmaxf(oy, 0.f); }
    *(unsigned int*)&out[(size_t)node * 64 + c] = pk2(ox, oy);
}

// building layer-2 gather fused with layer-3 XW (64 -> 2), lane-split 2 nodes/wave.
__global__ __launch_bounds__(256) void gather64_dot_k(const int* __restrict__ rowptr,
                                                      const int2* __restrict__ cse,
                                                      const unsigned short* __restrict__ h,
                                                      const float* __restrict__ dinv,
                                                      const float* __restrict__ bias,
                                                      const float* __restrict__ W3,  // [64][2]
                                                      float* __restrict__ Dh, int nPair) {
    int wid = (blockIdx.x * blockDim.x + threadIdx.x) >> 6;
    int lane = threadIdx.x & 63;
    if (wid >= nPair) return;
    int node = wid * 2 + (lane >> 5);
    int sl = lane & 31, c = sl * 2;
    int beg = rowptr[node], end = rowptr[node + 1];
    unsigned int hv = *(const unsigned int*)&h[(size_t)node * 64 + c];
    float iv = dinv[node];
    float2 bb = *(const float2*)&bias[c];
    float4 w4 = *(const float4*)&W3[c * 2];
    float ax = 0.f, ay = 0.f;
    for (int p = beg; p < end; p += 8) {
        int2 q[8]; unsigned int v[8];
#pragma unroll
        for (int t = 0; t < 8; ++t) { int e = p + t; q[t] = cse[e < end ? e : 0]; }
#pragma unroll
        for (int t = 0; t < 8; ++t) v[t] = *(const unsigned int*)&h[(size_t)q[t].x * 64 + c];
#pragma unroll
        for (int t = 0; t < 8; ++t) {
            float w = (p + t < end) ? __int_as_float(q[t].y) : 0.f;
            ax = fmaf(b2f((unsigned short)v[t]), w, ax);
            ay = fmaf(b2f((unsigned short)(v[t] >> 16)), w, ay);
        }
    }
    float ox = fmaf(b2f((unsigned short)hv), iv, ax) + bb.x;
    float oy = fmaf(b2f((unsigned short)(hv >> 16)), iv, ay) + bb.y;
    ox = fmaxf(ox, 0.f); oy = fmaxf(oy, 0.f);
    float d0 = fmaf(ox, w4.x, oy * w4.z);
    float d1 = fmaf(ox, w4.y, oy * w4.w);
#pragma unroll
    for (int m = 1; m < 32; m <<= 1) {
        d0 += __shfl_xor(d0, m, 32);
        d1 += __shfl_xor(d1, m, 32);
    }
    if (sl == 0) {
        Dh[2 * (size_t)node + 0] = d0;
        Dh[2 * (size_t)node + 1] = d1;
    }
}

// final layer: gather (F=2, f32) + bias + log-softmax + scatter to global order
__global__ __launch_bounds__(256) void gather2_logsm_k(const int* __restrict__ rowptr,
                                                       const int2* __restrict__ cse,
                                                       const float* __restrict__ h2,
                                                       const float* __restrict__ dinv,
                                                       const float* __restrict__ bias,
                                                       const int* __restrict__ l2g,
                                                       float* __restrict__ out, int n) {
    int i = blockIdx.x * blockDim.x + threadIdx.x;
    if (i >= n) return;
    int beg = rowptr[i], end = rowptr[i + 1];
    float2 hv = *(const float2*)&h2[2 * (size_t)i];
    float iv = dinv[i];
    float a = 0.f, b = 0.f;
    for (int p = beg; p < end; p += 8) {
        int2 q[8]; float2 v[8];
#pragma unroll
        for (int t = 0; t < 8; ++t) { int e = p + t; q[t] = cse[e < end ? e : 0]; }
#pragma unroll
        for (int t = 0; t < 8; ++t) v[t] = *(const float2*)&h2[2 * (size_t)q[t].x];
#pragma unroll
        for (int t = 0; t < 8; ++t) {
            float w = (p + t < end) ? __int_as_float(q[t].y) : 0.f;
            a = fmaf(v[t].x, w, a);
            b = fmaf(v[t].y, w, b);
        }
    }
    a = fmaf(hv.x, iv, a) + bias[0];
    b = fmaf(hv.y, iv, b) + bias[1];
    float m = fmaxf(a, b);
    float ls = m + logf(__expf(a - m) + __expf(b - m));
    int g = l2g[i];
    out[2 * (size_t)g + 0] = a - ls;
    out[2 * (size_t)g + 1] = b - ls;
}

// ---------------- launch ----------------

static inline dim3 g1(long long n, int tpb = 256) { return dim3((unsigned)((n + tpb - 1) / tpb)); }

extern "C" void kernel_launch(void* const* d_in, const int* in_sizes, int n_in,
                              void* d_out, int out_size, void* d_ws, size_t ws_size,
                              hipStream_t stream) {
    const float* bF   = (const float*)d_in[0];
    const float* cF   = (const float*)d_in[1];
    const float* W_c1 = (const float*)d_in[2];
    const float* b_c1 = (const float*)d_in[3];
    const float* W_c2 = (const float*)d_in[4];
    const float* b_c2 = (const float*)d_in[5];
    const float* W_at = (const float*)d_in[6];
    const float* b_at = (const float*)d_in[7];
    const float* W_b1 = (const float*)d_in[8];
    const float* b_b1 = (const float*)d_in[9];
    const float* W_b2 = (const float*)d_in[10];
    const float* b_b2 = (const float*)d_in[11];
    const float* W_b3 = (const float*)d_in[12];
    const float* b_b3 = (const float*)d_in[13];
    const int* b_src = (const int*)d_in[14];
    const int* b_dst = (const int*)d_in[15];
    const int* c_src = (const int*)d_in[16];
    const int* c_dst = (const int*)d_in[17];
    const int* map   = (const int*)d_in[18];
    const int* l2g   = (const int*)d_in[19];
    float* out = (float*)d_out;

    char* p = (char*)d_ws;
    auto alloc = [&](size_t bytes) { char* q = p; p += (bytes + 15) & ~(size_t)15; return q; };
    int*   cnt_b    = (int*)  alloc(N_BUILD * 4);
    int*   rowptr_b = (int*)  alloc((N_BUILD + 4) * 4);
    int*   cursor_b = (int*)  alloc(N_BUILD * 4);
    int*   bsum_b   = (int*)  alloc(256 * 4);
    int*   cnt_c    = (int*)  alloc(N_COMM * 4);
    int*   rowptr_c = (int*)  alloc((N_COMM + 4) * 4);
    int*   cursor_c = (int*)  alloc(N_COMM * 4);
    int*   bsum_c   = (int*)  alloc(256 * 4);
    int2*  cse_b    = (int2*) alloc((size_t)E_BUILD * 8);
    int2*  cse_c    = (int2*) alloc((size_t)E_COMM * 8);
    float* dinv_b   = (float*)alloc(N_BUILD * 4);
    float* dinv_c   = (float*)alloc(N_COMM * 4);
    unsigned short* cFb    = (unsigned short*)alloc((size_t)N_COMM * 32 * 2);
    unsigned short* Wt_c1  = (unsigned short*)alloc(64 * 32 * 2);
    unsigned short* Wt_c2  = (unsigned short*)alloc(64 * 64 * 2);
    unsigned short* Wt_b1  = (unsigned short*)alloc(128 * 128 * 2);
    unsigned short* Wt_b2  = (unsigned short*)alloc(64 * 128 * 2);
    unsigned short* ch_bf  = (unsigned short*)alloc((size_t)N_COMM * 64 * 2);
    unsigned short* cx1_bf = (unsigned short*)alloc((size_t)N_COMM * 64 * 2);
    unsigned short* cx2_bf = (unsigned short*)alloc((size_t)N_COMM * 64 * 2);
    unsigned short* A_bf   = (unsigned short*)alloc((size_t)N_BUILD * 128 * 2); // o1
    unsigned short* B_bf   = (unsigned short*)alloc((size_t)N_BUILD * 128 * 2); // h1 / h2
    float* Dh = (float*)alloc((size_t)N_BUILD * 2 * 4);

    // ---- CSR build (both graphs), out pre-fill, weight prep ----
    fill2_k<<<g1(N_BUILD + N_COMM + 2 * N_BUILD), 256, 0, stream>>>(cnt_b, cnt_c, out);
    hist2_k<<<g1(E_BUILD + E_COMM), 256, 0, stream>>>(cnt_b, b_dst, cnt_c, c_dst);
    scan1m_k<<<NB_B + NB_C, 256, 0, stream>>>(cnt_b, rowptr_b, bsum_b, cnt_c, rowptr_c, bsum_c);
    scan2m_k<<<2, 256, 0, stream>>>(bsum_b, bsum_c);
    finalizem_k<<<g1(N_BUILD + N_COMM), 256, 0, stream>>>(cnt_b, rowptr_b, bsum_b, cursor_b, dinv_b,
                                                          cnt_c, rowptr_c, bsum_c, cursor_c, dinv_c);
    csr_scatterm_k<<<g1(E_BUILD + E_COMM), 256, 0, stream>>>(b_src, b_dst, cursor_b, dinv_b, cse_b,
                                                             c_src, c_dst, cursor_c, dinv_c, cse_c);
    prep_k<<<g1(N_COMM * 32 + 2048 + 4096 + 16384 + 8192), 256, 0, stream>>>(
        cF, cFb, W_c1, Wt_c1, W_c2, Wt_c2, W_b1, Wt_b1, W_b2, Wt_b2);

    // ---- community GCN layer 1 (32 -> 64) + relu ----
    gemm_mfma_k<32, 64, true><<<dim3((N_COMM + 63) / 64), 256, 0, stream>>>(cFb, Wt_c1, ch_bf, N_COMM);
    gather64b_k<true><<<g1((long long)(N_COMM / 2) * 64), 256, 0, stream>>>(rowptr_c, cse_c, ch_bf, dinv_c, b_c1, cx1_bf, N_COMM / 2);

    // ---- community GCN layer 2 (64 -> 64) + relu ----
    gemm_mfma_k<64, 64, true><<<dim3((N_COMM + 63) / 64), 256, 0, stream>>>(cx1_bf, Wt_c2, ch_bf, N_COMM);
    gather64b_k<true><<<g1((long long)(N_COMM / 2) * 64), 256, 0, stream>>>(rowptr_c, cse_c, ch_bf, dinv_c, b_c2, cx2_bf, N_COMM / 2);

    // ---- building layer 1: fused attention + GEMM (128 -> 128), then gather + relu ----
    gemm_att_k<<<dim3(N_BUILD / 64), 256, 0, stream>>>(bF, cx2_bf, map, l2g, W_at, b_at, Wt_b1, B_bf);
    gather128b_k<true><<<g1((long long)(N_BUILD / 2) * 64), 256, 0, stream>>>(rowptr_b, cse_b, B_bf, dinv_b, b_b1, A_bf, N_BUILD / 2);

    // ---- building layer 2 (128 -> 64) + relu, fused with layer-3 XW ----
    gemm_mfma_k<128, 64, false><<<dim3(N_BUILD / 64), 256, 0, stream>>>(A_bf, Wt_b2, B_bf, N_BUILD);
    gather64_dot_k<<<g1((long long)(N_BUILD / 2) * 64), 256, 0, stream>>>(rowptr_b, cse_b, B_bf, dinv_b, b_b2, W_b3, Dh, N_BUILD / 2);

    // ---- building layer 3 aggregation + log-softmax + scatter ----
    gather2_logsm_k<<<g1(N_BUILD), 256, 0, stream>>>(rowptr_b, cse_b, Dh, dinv_b, b_b3, l2g, out, N_BUILD);
}

// Round 6
// 358.671 us; speedup vs baseline: 10.7893x; 1.0605x over previous
//
#include <hip/hip_runtime.h>
#include <hip/hip_bf16.h>
#include <math.h>

#define N_BUILD 200000
#define N_COMM  10000
#define E_BUILD 1200000
#define E_COMM  160000
#define NB_B 196   // scan blocks for building (200000/1024 rounded up)
#define NB_C 10

typedef __bf16 bf16x8 __attribute__((ext_vector_type(8)));
typedef float  f32x4  __attribute__((ext_vector_type(4)));

// ---------------- bf16 helpers (RNE) ----------------
__device__ __forceinline__ unsigned short f2b(float f) {
    unsigned int u = __builtin_bit_cast(unsigned int, f);
    u += 0x7fffu + ((u >> 16) & 1u);
    return (unsigned short)(u >> 16);
}
__device__ __forceinline__ float b2f(unsigned short h) {
    unsigned int u = ((unsigned int)h) << 16;
    return __builtin_bit_cast(float, u);
}
__device__ __forceinline__ unsigned int pk2(float a, float b) {
    return (unsigned int)f2b(a) | ((unsigned int)f2b(b) << 16);
}
__device__ __forceinline__ void up8(uint4 v, float* r) {
    r[0] = b2f((unsigned short)v.x); r[1] = b2f((unsigned short)(v.x >> 16));
    r[2] = b2f((unsigned short)v.y); r[3] = b2f((unsigned short)(v.y >> 16));
    r[4] = b2f((unsigned short)v.z); r[5] = b2f((unsigned short)(v.z >> 16));
    r[6] = b2f((unsigned short)v.w); r[7] = b2f((unsigned short)(v.w >> 16));
}

// ---------------- merged init: zero counts + out prefill + all weight prep ----------------
// task index cascade; one launch covers everything with no intra-kernel deps.
#define INIT_TOT (N_BUILD + N_COMM + 2 * N_BUILD + N_COMM * 32 + 2048 + 4096 + 16384 + 8192)
__global__ __launch_bounds__(256) void init_k(int* cnt_b, int* cnt_c, float* out,
                                              const float* __restrict__ cF, unsigned short* __restrict__ cFb,
                                              const float* __restrict__ W_c1, unsigned short* __restrict__ Wt_c1,
                                              const float* __restrict__ W_c2, unsigned short* __restrict__ Wt_c2,
                                              const float* __restrict__ W_b1, unsigned short* __restrict__ Wt_b1,
                                              const float* __restrict__ W_b2, unsigned short* __restrict__ Wt_b2) {
    int i = blockIdx.x * blockDim.x + threadIdx.x;
    if (i < N_BUILD) { cnt_b[i] = 0; return; }
    i -= N_BUILD;
    if (i < N_COMM) { cnt_c[i] = 0; return; }
    i -= N_COMM;
    if (i < 2 * N_BUILD) { out[i] = -0.69314718056f; return; }
    i -= 2 * N_BUILD;
    if (i < N_COMM * 32) { cFb[i] = f2b(cF[i]); return; }
    i -= N_COMM * 32;
    if (i < 2048) { Wt_c1[(i % 64) * 32 + i / 64] = f2b(W_c1[i]); return; }
    i -= 2048;
    if (i < 4096) { Wt_c2[(i % 64) * 64 + i / 64] = f2b(W_c2[i]); return; }
    i -= 4096;
    if (i < 16384) { Wt_b1[(i % 128) * 128 + i / 128] = f2b(W_b1[i]); return; }
    i -= 16384;
    if (i < 8192) { Wt_b2[(i % 64) * 128 + i / 64] = f2b(W_b2[i]); }
}

// ---------------- merged CSR build kernels (both graphs per launch) ----------------

__global__ __launch_bounds__(256) void hist2_k(int* cnt_b, const int* __restrict__ b_dst,
                                               int* cnt_c, const int* __restrict__ c_dst) {
    int i = blockIdx.x * blockDim.x + threadIdx.x;
    if (i < E_BUILD) atomicAdd(&cnt_b[b_dst[i]], 1);
    else if (i < E_BUILD + E_COMM) atomicAdd(&cnt_c[c_dst[i - E_BUILD]], 1);
}

__global__ __launch_bounds__(256) void scan1m_k(const int* __restrict__ cnt_b, int* __restrict__ ex_b, int* __restrict__ bs_b,
                                                const int* __restrict__ cnt_c, int* __restrict__ ex_c, int* __restrict__ bs_c) {
    __shared__ int sdata[256];
    const int tid = threadIdx.x;
    const int* cnt; int* ex; int* bs; int n, blk;
    if ((int)blockIdx.x < NB_B) { cnt = cnt_b; ex = ex_b; bs = bs_b; n = N_BUILD; blk = blockIdx.x; }
    else                        { cnt = cnt_c; ex = ex_c; bs = bs_c; n = N_COMM;  blk = blockIdx.x - NB_B; }
    const int base = blk * 1024 + tid * 4;
    int v[4]; int s = 0;
#pragma unroll
    for (int j = 0; j < 4; ++j) { v[j] = (base + j < n) ? cnt[base + j] : 0; s += v[j]; }
    sdata[tid] = s; __syncthreads();
    for (int off = 1; off < 256; off <<= 1) {
        int t = (tid >= off) ? sdata[tid - off] : 0;
        __syncthreads();
        sdata[tid] += t;
        __syncthreads();
    }
    if (tid == 255) bs[blk] = sdata[255];
    int run = sdata[tid] - s;
#pragma unroll
    for (int j = 0; j < 4; ++j) { if (base + j < n) ex[base + j] = run; run += v[j]; }
}

__global__ __launch_bounds__(256) void scan2m_k(int* bs_b, int* bs_c) {
    __shared__ int sdata[256];
    int* bs = (blockIdx.x == 0) ? bs_b : bs_c;
    int nb  = (blockIdx.x == 0) ? NB_B : NB_C;
    const int tid = threadIdx.x;
    int v = (tid < nb) ? bs[tid] : 0;
    sdata[tid] = v; __syncthreads();
    for (int off = 1; off < 256; off <<= 1) {
        int t = (tid >= off) ? sdata[tid - off] : 0;
        __syncthreads();
        sdata[tid] += t;
        __syncthreads();
    }
    if (tid < nb) bs[tid] = sdata[tid] - v;
}

__global__ __launch_bounds__(256) void finalizem_k(const int* __restrict__ cnt_b, int* rp_b, const int* __restrict__ bo_b,
                                                   int* cur_b, float* di_b,
                                                   const int* __restrict__ cnt_c, int* rp_c, const int* __restrict__ bo_c,
                                                   int* cur_c, float* di_c) {
    int i = blockIdx.x * blockDim.x + threadIdx.x;
    if (i < N_BUILD) {
        int cc = cnt_b[i];
        int r = rp_b[i] + bo_b[i >> 10];
        rp_b[i] = r; cur_b[i] = r; di_b[i] = 1.0f / (float)(cc + 1);
        if (i == 0) { rp_b[N_BUILD] = E_BUILD; rp_c[N_COMM] = E_COMM; }
    } else if (i < N_BUILD + N_COMM) {
        int ic = i - N_BUILD;
        int cc = cnt_c[ic];
        int r = rp_c[ic] + bo_c[ic >> 10];
        rp_c[ic] = r; cur_c[ic] = r; di_c[ic] = 1.0f / (float)(cc + 1);
    }
}

__global__ __launch_bounds__(256) void csr_scatterm_k(const int* __restrict__ b_src, const int* __restrict__ b_dst,
                                                      int* cur_b, const float* __restrict__ di_b, int2* __restrict__ cse_b,
                                                      const int* __restrict__ c_src, const int* __restrict__ c_dst,
                                                      int* cur_c, const float* __restrict__ di_c, int2* __restrict__ cse_c) {
    int i = blockIdx.x * blockDim.x + threadIdx.x;
    if (i < E_BUILD) {
        int s = b_src[i], d = b_dst[i];
        int pos = atomicAdd(&cur_b[d], 1);
        cse_b[pos] = make_int2(s, __float_as_int(sqrtf(di_b[s] * di_b[d])));
    } else if (i < E_BUILD + E_COMM) {
        int ie = i - E_BUILD;
        int s = c_src[ie], d = c_dst[ie];
        int pos = atomicAdd(&cur_c[d], 1);
        cse_c[pos] = make_int2(s, __float_as_int(sqrtf(di_c[s] * di_c[d])));
    }
}

// ---------------- MFMA GEMM: H[M][N] (bf16) = X[M][K] (bf16) @ Wt[N][K]^T ----------------
template<int K, int N, bool GUARD>
__global__ __launch_bounds__(256) void gemm_mfma_k(const unsigned short* __restrict__ X,
                                                   const unsigned short* __restrict__ Wt,
                                                   unsigned short* __restrict__ H, int M) {
    constexpr int GPR = K / 8;
    __shared__ unsigned short sA[64 * K];
    __shared__ unsigned short sB[N * K];
    const int tid  = threadIdx.x;
    const int row0 = blockIdx.x * 64;

    for (int idx = tid; idx < 64 * GPR; idx += 256) {
        int r = idx / GPR, g = idx % GPR;
        uint4 v = make_uint4(0u, 0u, 0u, 0u);
        if (!GUARD || row0 + r < M)
            v = *(const uint4*)&X[(size_t)(row0 + r) * K + g * 8];
        int gs = g ^ (r & (GPR - 1));
        *(uint4*)&sA[r * K + gs * 8] = v;
    }
    for (int idx = tid; idx < N * GPR; idx += 256) {
        int r = idx / GPR, g = idx % GPR;
        uint4 v = *(const uint4*)&Wt[(size_t)r * K + g * 8];
        int gs = g ^ (r & (GPR - 1));
        *(uint4*)&sB[r * K + gs * 8] = v;
    }
    __syncthreads();

    const int wave = tid >> 6, lane = tid & 63;
    const int rA = wave * 16 + (lane & 15);
    const int kg = lane >> 4;

    f32x4 zero = {0.f, 0.f, 0.f, 0.f};
    f32x4 acc[N / 16];
#pragma unroll
    for (int t = 0; t < N / 16; ++t) acc[t] = zero;

#pragma unroll
    for (int ks = 0; ks < K / 32; ++ks) {
        int gA = (ks * 4 + kg) ^ (rA & (GPR - 1));
        bf16x8 a = *(const bf16x8*)&sA[rA * K + gA * 8];
#pragma unroll
        for (int t = 0; t < N / 16; ++t) {
            int rB = t * 16 + (lane & 15);
            int gB = (ks * 4 + kg) ^ (rB & (GPR - 1));
            bf16x8 b = *(const bf16x8*)&sB[rB * K + gB * 8];
            acc[t] = __builtin_amdgcn_mfma_f32_16x16x32_bf16(a, b, acc[t], 0, 0, 0);
        }
    }

    const int crow = wave * 16 + (lane >> 4) * 4;
    const int ccol = lane & 15;
#pragma unroll
    for (int t = 0; t < N / 16; ++t) {
#pragma unroll
        for (int j = 0; j < 4; ++j) {
            int r = row0 + crow + j;
            if (!GUARD || r < M)
                H[(size_t)r * N + t * 16 + ccol] = f2b(acc[t][j]);
        }
    }
}

// ---------------- fused attention + building GEMM layer 1 (K=N=128) ----------------
__global__ __launch_bounds__(256) void gemm_att_k(const float* __restrict__ bF,
                                                  const unsigned short* __restrict__ cx,
                                                  const int* __restrict__ map,
                                                  const int* __restrict__ l2g,
                                                  const float* __restrict__ Watt,  // [128][2]
                                                  const float* __restrict__ batt,  // [2]
                                                  const unsigned short* __restrict__ Wt,  // [128][128]
                                                  unsigned short* __restrict__ H) {
    constexpr int K = 128, N = 128, GPR = 16;
    __shared__ unsigned short sA[64 * K];
    __shared__ unsigned short sB[N * K];
    __shared__ float sWt[256];
    const int tid = threadIdx.x;
    const int row0 = blockIdx.x * 64;
    sWt[tid] = Watt[tid];
    for (int idx = tid; idx < N * GPR; idx += 256) {
        int r = idx / GPR, g = idx % GPR;
        uint4 v = *(const uint4*)&Wt[(size_t)r * K + g * 8];
        int gs = g ^ (r & (GPR - 1));
        *(uint4*)&sB[r * K + gs * 8] = v;
    }
    __syncthreads();
    {
        const int r = tid >> 2, j = tid & 3;   // N_BUILD % 64 == 0 -> no guard
        const int g = l2g[row0 + r];
        float vals[32];
        if (j < 2) {
            const float* f1 = &bF[(size_t)g * 64 + j * 32];
#pragma unroll
            for (int t = 0; t < 8; ++t) {
                float4 v = *(const float4*)&f1[t * 4];
                vals[t*4+0]=v.x; vals[t*4+1]=v.y; vals[t*4+2]=v.z; vals[t*4+3]=v.w;
            }
        } else {
            const unsigned short* f2 = &cx[(size_t)map[g] * 64 + (j & 1) * 32];
#pragma unroll
            for (int t = 0; t < 4; ++t) {
                uint4 u = *(const uint4*)&f2[t * 8];
                up8(u, &vals[t * 8]);
            }
        }
        float l0 = 0.f, l1 = 0.f;
        const int ch0 = j * 32;
#pragma unroll
        for (int t = 0; t < 32; ++t) {
            l0 = fmaf(vals[t], sWt[(ch0 + t) * 2 + 0], l0);
            l1 = fmaf(vals[t], sWt[(ch0 + t) * 2 + 1], l1);
        }
        l0 += __shfl_xor(l0, 1, 4); l0 += __shfl_xor(l0, 2, 4);
        l1 += __shfl_xor(l1, 1, 4); l1 += __shfl_xor(l1, 2, 4);
        l0 += batt[0]; l1 += batt[1];
        float mm = fmaxf(l0, l1);
        float e0 = __expf(l0 - mm), e1 = __expf(l1 - mm);
        float a = ((j < 2) ? e0 : e1) / (e0 + e1);
#pragma unroll
        for (int t = 0; t < 4; ++t) {
            uint4 o;
            o.x = pk2(vals[t*8+0]*a, vals[t*8+1]*a);
            o.y = pk2(vals[t*8+2]*a, vals[t*8+3]*a);
            o.z = pk2(vals[t*8+4]*a, vals[t*8+5]*a);
            o.w = pk2(vals[t*8+6]*a, vals[t*8+7]*a);
            int gi = j * 4 + t;
            int gs = gi ^ (r & (GPR - 1));
            *(uint4*)&sA[r * K + gs * 8] = o;
        }
    }
    __syncthreads();
    const int wave = tid >> 6, lane = tid & 63;
    const int rA = wave * 16 + (lane & 15);
    const int kg = lane >> 4;
    f32x4 zero = {0.f, 0.f, 0.f, 0.f};
    f32x4 acc[8];
#pragma unroll
    for (int t = 0; t < 8; ++t) acc[t] = zero;
#pragma unroll
    for (int ks = 0; ks < 4; ++ks) {
        int gA = (ks * 4 + kg) ^ (rA & 15);
        bf16x8 a = *(const bf16x8*)&sA[rA * K + gA * 8];
#pragma unroll
        for (int t = 0; t < 8; ++t) {
            int rB = t * 16 + (lane & 15);
            int gB = (ks * 4 + kg) ^ (rB & 15);
            bf16x8 b = *(const bf16x8*)&sB[rB * K + gB * 8];
            acc[t] = __builtin_amdgcn_mfma_f32_16x16x32_bf16(a, b, acc[t], 0, 0, 0);
        }
    }
    const int crow = wave * 16 + (lane >> 4) * 4;
    const int ccol = lane & 15;
#pragma unroll
    for (int t = 0; t < 8; ++t)
#pragma unroll
        for (int jj = 0; jj < 4; ++jj)
            H[(size_t)(row0 + crow + jj) * N + t * 16 + ccol] = f2b(acc[t][jj]);
}

// ---------------- gathers: lane-split node packing ----------------
// gather128: 2 nodes/wave — lanes 0-31 node0, lanes 32-63 node1, 4 ch/lane (uint2).
// Both nodes' edge loads share the SAME load instructions (different addrs per half),
// so per-node dependency chains halve at constant wave residency.
template<bool RELU>
__global__ __launch_bounds__(256) void gather128b_k(const int* __restrict__ rowptr,
                                                    const int2* __restrict__ cse,
                                                    const unsigned short* __restrict__ h,
                                                    const float* __restrict__ dinv,
                                                    const float* __restrict__ bias,
                                                    unsigned short* __restrict__ out, int nPair) {
    int wid = (blockIdx.x * blockDim.x + threadIdx.x) >> 6;
    int lane = threadIdx.x & 63;
    if (wid >= nPair) return;
    int node = wid * 2 + (lane >> 5);
    int sl = lane & 31, c = sl * 4;
    int beg = rowptr[node], end = rowptr[node + 1];
    uint2 hv = *(const uint2*)&h[(size_t)node * 128 + c];
    float iv = dinv[node];
    float4 bb = *(const float4*)&bias[c];
    float a0 = 0.f, a1 = 0.f, a2 = 0.f, a3 = 0.f;
    for (int p = beg; p < end; p += 8) {
        int2 q[8]; uint2 v[8];
#pragma unroll
        for (int t = 0; t < 8; ++t) { int e = p + t; q[t] = cse[e < end ? e : 0]; }
#pragma unroll
        for (int t = 0; t < 8; ++t) v[t] = *(const uint2*)&h[(size_t)q[t].x * 128 + c];
#pragma unroll
        for (int t = 0; t < 8; ++t) {
            float w = (p + t < end) ? __int_as_float(q[t].y) : 0.f;
            a0 = fmaf(b2f((unsigned short)v[t].x), w, a0);
            a1 = fmaf(b2f((unsigned short)(v[t].x >> 16)), w, a1);
            a2 = fmaf(b2f((unsigned short)v[t].y), w, a2);
            a3 = fmaf(b2f((unsigned short)(v[t].y >> 16)), w, a3);
        }
    }
    float o0 = fmaf(b2f((unsigned short)hv.x), iv, a0) + bb.x;
    float o1 = fmaf(b2f((unsigned short)(hv.x >> 16)), iv, a1) + bb.y;
    float o2 = fmaf(b2f((unsigned short)hv.y), iv, a2) + bb.z;
    float o3 = fmaf(b2f((unsigned short)(hv.y >> 16)), iv, a3) + bb.w;
    if (RELU) {
        o0 = fmaxf(o0, 0.f); o1 = fmaxf(o1, 0.f);
        o2 = fmaxf(o2, 0.f); o3 = fmaxf(o3, 0.f);
    }
    uint2 ov; ov.x = pk2(o0, o1); ov.y = pk2(o2, o3);
    *(uint2*)&out[(size_t)node * 128 + c] = ov;
}

// gather64: 4 nodes/wave — 16 lanes/node, 4 ch/lane (uint2).
template<bool RELU>
__global__ __launch_bounds__(256) void gather64x4_k(const int* __restrict__ rowptr,
                                                    const int2* __restrict__ cse,
                                                    const unsigned short* __restrict__ h,
                                                    const float* __restrict__ dinv,
                                                    const float* __restrict__ bias,
                                                    unsigned short* __restrict__ out, int nQuad) {
    int wid = (blockIdx.x * blockDim.x + threadIdx.x) >> 6;
    int lane = threadIdx.x & 63;
    if (wid >= nQuad) return;
    int node = wid * 4 + (lane >> 4);
    int sl = lane & 15, c = sl * 4;
    int beg = rowptr[node], end = rowptr[node + 1];
    uint2 hv = *(const uint2*)&h[(size_t)node * 64 + c];
    float iv = dinv[node];
    float4 bb = *(const float4*)&bias[c];
    float a0 = 0.f, a1 = 0.f, a2 = 0.f, a3 = 0.f;
    for (int p = beg; p < end; p += 8) {
        int2 q[8]; uint2 v[8];
#pragma unroll
        for (int t = 0; t < 8; ++t) { int e = p + t; q[t] = cse[e < end ? e : 0]; }
#pragma unroll
        for (int t = 0; t < 8; ++t) v[t] = *(const uint2*)&h[(size_t)q[t].x * 64 + c];
#pragma unroll
        for (int t = 0; t < 8; ++t) {
            float w = (p + t < end) ? __int_as_float(q[t].y) : 0.f;
            a0 = fmaf(b2f((unsigned short)v[t].x), w, a0);
            a1 = fmaf(b2f((unsigned short)(v[t].x >> 16)), w, a1);
            a2 = fmaf(b2f((unsigned short)v[t].y), w, a2);
            a3 = fmaf(b2f((unsigned short)(v[t].y >> 16)), w, a3);
        }
    }
    float o0 = fmaf(b2f((unsigned short)hv.x), iv, a0) + bb.x;
    float o1 = fmaf(b2f((unsigned short)(hv.x >> 16)), iv, a1) + bb.y;
    float o2 = fmaf(b2f((unsigned short)hv.y), iv, a2) + bb.z;
    float o3 = fmaf(b2f((unsigned short)(hv.y >> 16)), iv, a3) + bb.w;
    if (RELU) {
        o0 = fmaxf(o0, 0.f); o1 = fmaxf(o1, 0.f);
        o2 = fmaxf(o2, 0.f); o3 = fmaxf(o3, 0.f);
    }
    uint2 ov; ov.x = pk2(o0, o1); ov.y = pk2(o2, o3);
    *(uint2*)&out[(size_t)node * 64 + c] = ov;
}

// building layer-2 gather fused with layer-3 XW (64 -> 2): 4 nodes/wave, 16 lanes/node.
__global__ __launch_bounds__(256) void gather64_dot_k(const int* __restrict__ rowptr,
                                                      const int2* __restrict__ cse,
                                                      const unsigned short* __restrict__ h,
                                                      const float* __restrict__ dinv,
                                                      const float* __restrict__ bias,
                                                      const float* __restrict__ W3,  // [64][2]
                                                      float* __restrict__ Dh, int nQuad) {
    int wid = (blockIdx.x * blockDim.x + threadIdx.x) >> 6;
    int lane = threadIdx.x & 63;
    if (wid >= nQuad) return;
    int node = wid * 4 + (lane >> 4);
    int sl = lane & 15, c = sl * 4;
    int beg = rowptr[node], end = rowptr[node + 1];
    uint2 hv = *(const uint2*)&h[(size_t)node * 64 + c];
    float iv = dinv[node];
    float4 bb = *(const float4*)&bias[c];
    float4 w01 = *(const float4*)&W3[c * 2];       // W3[c][0..1], W3[c+1][0..1]
    float4 w23 = *(const float4*)&W3[c * 2 + 4];   // W3[c+2][0..1], W3[c+3][0..1]
    float a0 = 0.f, a1 = 0.f, a2 = 0.f, a3 = 0.f;
    for (int p = beg; p < end; p += 8) {
        int2 q[8]; uint2 v[8];
#pragma unroll
        for (int t = 0; t < 8; ++t) { int e = p + t; q[t] = cse[e < end ? e : 0]; }
#pragma unroll
        for (int t = 0; t < 8; ++t) v[t] = *(const uint2*)&h[(size_t)q[t].x * 64 + c];
#pragma unroll
        for (int t = 0; t < 8; ++t) {
            float w = (p + t < end) ? __int_as_float(q[t].y) : 0.f;
            a0 = fmaf(b2f((unsigned short)v[t].x), w, a0);
            a1 = fmaf(b2f((unsigned short)(v[t].x >> 16)), w, a1);
            a2 = fmaf(b2f((unsigned short)v[t].y), w, a2);
            a3 = fmaf(b2f((unsigned short)(v[t].y >> 16)), w, a3);
        }
    }
    float o0 = fmaxf(fmaf(b2f((unsigned short)hv.x), iv, a0) + bb.x, 0.f);
    float o1 = fmaxf(fmaf(b2f((unsigned short)(hv.x >> 16)), iv, a1) + bb.y, 0.f);
    float o2 = fmaxf(fmaf(b2f((unsigned short)hv.y), iv, a2) + bb.z, 0.f);
    float o3 = fmaxf(fmaf(b2f((unsigned short)(hv.y >> 16)), iv, a3) + bb.w, 0.f);
    float d0 = o0 * w01.x + o1 * w01.z + o2 * w23.x + o3 * w23.z;
    float d1 = o0 * w01.y + o1 * w01.w + o2 * w23.y + o3 * w23.w;
#pragma unroll
    for (int m = 1; m < 16; m <<= 1) {
        d0 += __shfl_xor(d0, m, 16);
        d1 += __shfl_xor(d1, m, 16);
    }
    if (sl == 0) {
        Dh[2 * (size_t)node + 0] = d0;
        Dh[2 * (size_t)node + 1] = d1;
    }
}

// final layer: gather (F=2, f32) + bias + log-softmax + scatter to global order
__global__ __launch_bounds__(256) void gather2_logsm_k(const int* __restrict__ rowptr,
                                                       const int2* __restrict__ cse,
                                                       const float* __restrict__ h2,
                                                       const float* __restrict__ dinv,
                                                       const float* __restrict__ bias,
                                                       const int* __restrict__ l2g,
                                                       float* __restrict__ out, int n) {
    int i = blockIdx.x * blockDim.x + threadIdx.x;
    if (i >= n) return;
    int beg = rowptr[i], end = rowptr[i + 1];
    float2 hv = *(const float2*)&h2[2 * (size_t)i];
    float iv = dinv[i];
    float a = 0.f, b = 0.f;
    for (int p = beg; p < end; p += 8) {
        int2 q[8]; float2 v[8];
#pragma unroll
        for (int t = 0; t < 8; ++t) { int e = p + t; q[t] = cse[e < end ? e : 0]; }
#pragma unroll
        for (int t = 0; t < 8; ++t) v[t] = *(const float2*)&h2[2 * (size_t)q[t].x];
#pragma unroll
        for (int t = 0; t < 8; ++t) {
            float w = (p + t < end) ? __int_as_float(q[t].y) : 0.f;
            a = fmaf(v[t].x, w, a);
            b = fmaf(v[t].y, w, b);
        }
    }
    a = fmaf(hv.x, iv, a) + bias[0];
    b = fmaf(hv.y, iv, b) + bias[1];
    float m = fmaxf(a, b);
    float ls = m + logf(__expf(a - m) + __expf(b - m));
    int g = l2g[i];
    out[2 * (size_t)g + 0] = a - ls;
    out[2 * (size_t)g + 1] = b - ls;
}

// ---------------- launch ----------------

static inline dim3 g1(long long n, int tpb = 256) { return dim3((unsigned)((n + tpb - 1) / tpb)); }

extern "C" void kernel_launch(void* const* d_in, const int* in_sizes, int n_in,
                              void* d_out, int out_size, void* d_ws, size_t ws_size,
                              hipStream_t stream) {
    const float* bF   = (const float*)d_in[0];
    const float* cF   = (const float*)d_in[1];
    const float* W_c1 = (const float*)d_in[2];
    const float* b_c1 = (const float*)d_in[3];
    const float* W_c2 = (const float*)d_in[4];
    const float* b_c2 = (const float*)d_in[5];
    const float* W_at = (const float*)d_in[6];
    const float* b_at = (const float*)d_in[7];
    const float* W_b1 = (const float*)d_in[8];
    const float* b_b1 = (const float*)d_in[9];
    const float* W_b2 = (const float*)d_in[10];
    const float* b_b2 = (const float*)d_in[11];
    const float* W_b3 = (const float*)d_in[12];
    const float* b_b3 = (const float*)d_in[13];
    const int* b_src = (const int*)d_in[14];
    const int* b_dst = (const int*)d_in[15];
    const int* c_src = (const int*)d_in[16];
    const int* c_dst = (const int*)d_in[17];
    const int* map   = (const int*)d_in[18];
    const int* l2g   = (const int*)d_in[19];
    float* out = (float*)d_out;

    char* p = (char*)d_ws;
    auto alloc = [&](size_t bytes) { char* q = p; p += (bytes + 15) & ~(size_t)15; return q; };
    int*   cnt_b    = (int*)  alloc(N_BUILD * 4);
    int*   rowptr_b = (int*)  alloc((N_BUILD + 4) * 4);
    int*   cursor_b = (int*)  alloc(N_BUILD * 4);
    int*   bsum_b   = (int*)  alloc(256 * 4);
    int*   cnt_c    = (int*)  alloc(N_COMM * 4);
    int*   rowptr_c = (int*)  alloc((N_COMM + 4) * 4);
    int*   cursor_c = (int*)  alloc(N_COMM * 4);
    int*   bsum_c   = (int*)  alloc(256 * 4);
    int2*  cse_b    = (int2*) alloc((size_t)E_BUILD * 8);
    int2*  cse_c    = (int2*) alloc((size_t)E_COMM * 8);
    float* dinv_b   = (float*)alloc(N_BUILD * 4);
    float* dinv_c   = (float*)alloc(N_COMM * 4);
    unsigned short* cFb    = (unsigned short*)alloc((size_t)N_COMM * 32 * 2);
    unsigned short* Wt_c1  = (unsigned short*)alloc(64 * 32 * 2);
    unsigned short* Wt_c2  = (unsigned short*)alloc(64 * 64 * 2);
    unsigned short* Wt_b1  = (unsigned short*)alloc(128 * 128 * 2);
    unsigned short* Wt_b2  = (unsigned short*)alloc(64 * 128 * 2);
    unsigned short* ch_bf  = (unsigned short*)alloc((size_t)N_COMM * 64 * 2);
    unsigned short* cx1_bf = (unsigned short*)alloc((size_t)N_COMM * 64 * 2);
    unsigned short* cx2_bf = (unsigned short*)alloc((size_t)N_COMM * 64 * 2);
    unsigned short* A_bf   = (unsigned short*)alloc((size_t)N_BUILD * 128 * 2); // o1
    unsigned short* B_bf   = (unsigned short*)alloc((size_t)N_BUILD * 128 * 2); // h1 / h2
    float* Dh = (float*)alloc((size_t)N_BUILD * 2 * 4);

    // ---- init (counts zero + out prefill + weight prep), then CSR build both graphs ----
    init_k<<<g1(INIT_TOT), 256, 0, stream>>>(cnt_b, cnt_c, out,
                                             cF, cFb, W_c1, Wt_c1, W_c2, Wt_c2, W_b1, Wt_b1, W_b2, Wt_b2);
    hist2_k<<<g1(E_BUILD + E_COMM), 256, 0, stream>>>(cnt_b, b_dst, cnt_c, c_dst);
    scan1m_k<<<NB_B + NB_C, 256, 0, stream>>>(cnt_b, rowptr_b, bsum_b, cnt_c, rowptr_c, bsum_c);
    scan2m_k<<<2, 256, 0, stream>>>(bsum_b, bsum_c);
    finalizem_k<<<g1(N_BUILD + N_COMM), 256, 0, stream>>>(cnt_b, rowptr_b, bsum_b, cursor_b, dinv_b,
                                                          cnt_c, rowptr_c, bsum_c, cursor_c, dinv_c);
    csr_scatterm_k<<<g1(E_BUILD + E_COMM), 256, 0, stream>>>(b_src, b_dst, cursor_b, dinv_b, cse_b,
                                                             c_src, c_dst, cursor_c, dinv_c, cse_c);

    // ---- community GCN layer 1 (32 -> 64) + relu ----
    gemm_mfma_k<32, 64, true><<<dim3((N_COMM + 63) / 64), 256, 0, stream>>>(cFb, Wt_c1, ch_bf, N_COMM);
    gather64x4_k<true><<<g1((long long)(N_COMM / 4) * 64), 256, 0, stream>>>(rowptr_c, cse_c, ch_bf, dinv_c, b_c1, cx1_bf, N_COMM / 4);

    // ---- community GCN layer 2 (64 -> 64) + relu ----
    gemm_mfma_k<64, 64, true><<<dim3((N_COMM + 63) / 64), 256, 0, stream>>>(cx1_bf, Wt_c2, ch_bf, N_COMM);
    gather64x4_k<true><<<g1((long long)(N_COMM / 4) * 64), 256, 0, stream>>>(rowptr_c, cse_c, ch_bf, dinv_c, b_c2, cx2_bf, N_COMM / 4);

    // ---- building layer 1: fused attention + GEMM (128 -> 128), then gather + relu ----
    gemm_att_k<<<dim3(N_BUILD / 64), 256, 0, stream>>>(bF, cx2_bf, map, l2g, W_at, b_at, Wt_b1, B_bf);
    gather128b_k<true><<<g1((long long)(N_BUILD / 2) * 64), 256, 0, stream>>>(rowptr_b, cse_b, B_bf, dinv_b, b_b1, A_bf, N_BUILD / 2);

    // ---- building layer 2 (128 -> 64) + relu, fused with layer-3 XW ----
    gemm_mfma_k<128, 64, false><<<dim3(N_BUILD / 64), 256, 0, stream>>>(A_bf, Wt_b2, B_bf, N_BUILD);
    gather64_dot_k<<<g1((long long)(N_BUILD / 4) * 64), 256, 0, stream>>>(rowptr_b, cse_b, B_bf, dinv_b, b_b2, W_b3, Dh, N_BUILD / 4);

    // ---- building layer 3 aggregation + log-softmax + scatter ----
    gather2_logsm_k<<<g1(N_BUILD), 256, 0, stream>>>(rowptr_b, cse_b, Dh, dinv_b, b_b3, l2g, out, N_BUILD);
}

// Round 7
// 338.861 us; speedup vs baseline: 11.4201x; 1.0585x over previous
//
#include <hip/hip_runtime.h>
#include <hip/hip_bf16.h>
#include <math.h>

#define N_BUILD 200000
#define N_COMM  10000
#define E_BUILD 1200000
#define E_COMM  160000
#define NB_B 196   // scan blocks for building (200000/1024 rounded up)
#define NB_C 10
#define CHUNK 2048
#define CB_B ((E_BUILD + CHUNK - 1) / CHUNK)   // 586
#define CB_C ((E_COMM  + CHUNK - 1) / CHUNK)   // 79

typedef __bf16 bf16x8 __attribute__((ext_vector_type(8)));
typedef float  f32x4  __attribute__((ext_vector_type(4)));

// ---------------- bf16 helpers (RNE) ----------------
__device__ __forceinline__ unsigned short f2b(float f) {
    unsigned int u = __builtin_bit_cast(unsigned int, f);
    u += 0x7fffu + ((u >> 16) & 1u);
    return (unsigned short)(u >> 16);
}
__device__ __forceinline__ float b2f(unsigned short h) {
    unsigned int u = ((unsigned int)h) << 16;
    return __builtin_bit_cast(float, u);
}
__device__ __forceinline__ unsigned int pk2(float a, float b) {
    return (unsigned int)f2b(a) | ((unsigned int)f2b(b) << 16);
}
__device__ __forceinline__ void up8(uint4 v, float* r) {
    r[0] = b2f((unsigned short)v.x); r[1] = b2f((unsigned short)(v.x >> 16));
    r[2] = b2f((unsigned short)v.y); r[3] = b2f((unsigned short)(v.y >> 16));
    r[4] = b2f((unsigned short)v.z); r[5] = b2f((unsigned short)(v.z >> 16));
    r[6] = b2f((unsigned short)v.w); r[7] = b2f((unsigned short)(v.w >> 16));
}

// ---------------- merged init: zero counts + out prefill + all weight prep ----------------
#define INIT_TOT (N_BUILD + N_COMM + 2 * N_BUILD + N_COMM * 32 + 2048 + 4096 + 16384 + 8192)
__global__ __launch_bounds__(256) void init_k(int* cnt_b, int* cnt_c, float* out,
                                              const float* __restrict__ cF, unsigned short* __restrict__ cFb,
                                              const float* __restrict__ W_c1, unsigned short* __restrict__ Wt_c1,
                                              const float* __restrict__ W_c2, unsigned short* __restrict__ Wt_c2,
                                              const float* __restrict__ W_b1, unsigned short* __restrict__ Wt_b1,
                                              const float* __restrict__ W_b2, unsigned short* __restrict__ Wt_b2) {
    int i = blockIdx.x * blockDim.x + threadIdx.x;
    if (i < N_BUILD) { cnt_b[i] = 0; return; }
    i -= N_BUILD;
    if (i < N_COMM) { cnt_c[i] = 0; return; }
    i -= N_COMM;
    if (i < 2 * N_BUILD) { out[i] = -0.69314718056f; return; }
    i -= 2 * N_BUILD;
    if (i < N_COMM * 32) { cFb[i] = f2b(cF[i]); return; }
    i -= N_COMM * 32;
    if (i < 2048) { Wt_c1[(i % 64) * 32 + i / 64] = f2b(W_c1[i]); return; }
    i -= 2048;
    if (i < 4096) { Wt_c2[(i % 64) * 64 + i / 64] = f2b(W_c2[i]); return; }
    i -= 4096;
    if (i < 16384) { Wt_b1[(i % 128) * 128 + i / 128] = f2b(W_b1[i]); return; }
    i -= 16384;
    if (i < 8192) { Wt_b2[(i % 64) * 128 + i / 64] = f2b(W_b2[i]); }
}

// ---------------- merged CSR build kernels ----------------

__global__ __launch_bounds__(256) void hist2_k(int* cnt_b, const int* __restrict__ b_dst,
                                               int* cnt_c, const int* __restrict__ c_dst) {
    int i = blockIdx.x * blockDim.x + threadIdx.x;
    if (i < E_BUILD) atomicAdd(&cnt_b[b_dst[i]], 1);
    else if (i < E_BUILD + E_COMM) atomicAdd(&cnt_c[c_dst[i - E_BUILD]], 1);
}

__global__ __launch_bounds__(256) void scan1m_k(const int* __restrict__ cnt_b, int* __restrict__ ex_b, int* __restrict__ bs_b,
                                                const int* __restrict__ cnt_c, int* __restrict__ ex_c, int* __restrict__ bs_c) {
    __shared__ int sdata[256];
    const int tid = threadIdx.x;
    const int* cnt; int* ex; int* bs; int n, blk;
    if ((int)blockIdx.x < NB_B) { cnt = cnt_b; ex = ex_b; bs = bs_b; n = N_BUILD; blk = blockIdx.x; }
    else                        { cnt = cnt_c; ex = ex_c; bs = bs_c; n = N_COMM;  blk = blockIdx.x - NB_B; }
    const int base = blk * 1024 + tid * 4;
    int v[4]; int s = 0;
#pragma unroll
    for (int j = 0; j < 4; ++j) { v[j] = (base + j < n) ? cnt[base + j] : 0; s += v[j]; }
    sdata[tid] = s; __syncthreads();
    for (int off = 1; off < 256; off <<= 1) {
        int t = (tid >= off) ? sdata[tid - off] : 0;
        __syncthreads();
        sdata[tid] += t;
        __syncthreads();
    }
    if (tid == 255) bs[blk] = sdata[255];
    int run = sdata[tid] - s;
#pragma unroll
    for (int j = 0; j < 4; ++j) { if (base + j < n) ex[base + j] = run; run += v[j]; }
}

__global__ __launch_bounds__(256) void scan2m_k(int* bs_b, int* bs_c) {
    __shared__ int sdata[256];
    int* bs = (blockIdx.x == 0) ? bs_b : bs_c;
    int nb  = (blockIdx.x == 0) ? NB_B : NB_C;
    const int tid = threadIdx.x;
    int v = (tid < nb) ? bs[tid] : 0;
    sdata[tid] = v; __syncthreads();
    for (int off = 1; off < 256; off <<= 1) {
        int t = (tid >= off) ? sdata[tid - off] : 0;
        __syncthreads();
        sdata[tid] += t;
        __syncthreads();
    }
    if (tid < nb) bs[tid] = sdata[tid] - v;
}

__global__ __launch_bounds__(256) void finalizem_k(const int* __restrict__ cnt_b, int* rp_b, const int* __restrict__ bo_b,
                                                   int* cur_b, float* di_b,
                                                   const int* __restrict__ cnt_c, int* rp_c, const int* __restrict__ bo_c,
                                                   int* cur_c, float* di_c) {
    int i = blockIdx.x * blockDim.x + threadIdx.x;
    if (i < N_BUILD) {
        int cc = cnt_b[i];
        int r = rp_b[i] + bo_b[i >> 10];
        rp_b[i] = r; cur_b[i] = r; di_b[i] = 1.0f / (float)(cc + 1);
        if (i == 0) { rp_b[N_BUILD] = E_BUILD; rp_c[N_COMM] = E_COMM; }
    } else if (i < N_BUILD + N_COMM) {
        int ic = i - N_BUILD;
        int cc = cnt_c[ic];
        int r = rp_c[ic] + bo_c[ic >> 10];
        rp_c[ic] = r; cur_c[ic] = r; di_c[ic] = 1.0f / (float)(cc + 1);
    }
}

// XCD-range-partitioned CSR scatter: block (chunk cid, slot x) processes only edges in
// its chunk whose dst/NDIV == x. With blockIdx%8 -> XCD round-robin, all stores to a
// given cse line come from one XCD -> lines assemble fully in that L2 before writeback
// (kills the 9x partial-dirty write amplification). Correct regardless of mapping.
template<int NDIV>
__device__ __forceinline__ void scatter_part(const int* __restrict__ src, const int* __restrict__ dst,
                                             int* cur, const float* __restrict__ di,
                                             int2* __restrict__ cse, int E, int cid, int x) {
    int base = cid * CHUNK + threadIdx.x;
#pragma unroll
    for (int j = 0; j < CHUNK / 256; ++j, base += 256) {
        if (base < E) {
            int d = dst[base];
            if ((unsigned)d / (unsigned)NDIV == (unsigned)x) {
                int s = src[base];
                int pos = atomicAdd(&cur[d], 1);
                cse[pos] = make_int2(s, __float_as_int(sqrtf(di[s] * di[d])));
            }
        }
    }
}

__global__ __launch_bounds__(256) void csr_scatterp_k(const int* __restrict__ b_src, const int* __restrict__ b_dst,
                                                      int* cur_b, const float* __restrict__ di_b, int2* __restrict__ cse_b,
                                                      const int* __restrict__ c_src, const int* __restrict__ c_dst,
                                                      int* cur_c, const float* __restrict__ di_c, int2* __restrict__ cse_c) {
    int bid = blockIdx.x;
    if (bid < 8 * CB_B) {
        scatter_part<N_BUILD / 8>(b_src, b_dst, cur_b, di_b, cse_b, E_BUILD, bid >> 3, bid & 7);
    } else {
        bid -= 8 * CB_B;
        scatter_part<N_COMM / 8>(c_src, c_dst, cur_c, di_c, cse_c, E_COMM, bid >> 3, bid & 7);
    }
}

// ---------------- MFMA GEMM: H[M][N] (bf16) = X[M][K] (bf16) @ Wt[N][K]^T ----------------
template<int K, int N, bool GUARD>
__global__ __launch_bounds__(256) void gemm_mfma_k(const unsigned short* __restrict__ X,
                                                   const unsigned short* __restrict__ Wt,
                                                   unsigned short* __restrict__ H, int M) {
    constexpr int GPR = K / 8;
    __shared__ unsigned short sA[64 * K];
    __shared__ unsigned short sB[N * K];
    const int tid  = threadIdx.x;
    const int row0 = blockIdx.x * 64;

    for (int idx = tid; idx < 64 * GPR; idx += 256) {
        int r = idx / GPR, g = idx % GPR;
        uint4 v = make_uint4(0u, 0u, 0u, 0u);
        if (!GUARD || row0 + r < M)
            v = *(const uint4*)&X[(size_t)(row0 + r) * K + g * 8];
        int gs = g ^ (r & (GPR - 1));
        *(uint4*)&sA[r * K + gs * 8] = v;
    }
    for (int idx = tid; idx < N * GPR; idx += 256) {
        int r = idx / GPR, g = idx % GPR;
        uint4 v = *(const uint4*)&Wt[(size_t)r * K + g * 8];
        int gs = g ^ (r & (GPR - 1));
        *(uint4*)&sB[r * K + gs * 8] = v;
    }
    __syncthreads();

    const int wave = tid >> 6, lane = tid & 63;
    const int rA = wave * 16 + (lane & 15);
    const int kg = lane >> 4;

    f32x4 zero = {0.f, 0.f, 0.f, 0.f};
    f32x4 acc[N / 16];
#pragma unroll
    for (int t = 0; t < N / 16; ++t) acc[t] = zero;

#pragma unroll
    for (int ks = 0; ks < K / 32; ++ks) {
        int gA = (ks * 4 + kg) ^ (rA & (GPR - 1));
        bf16x8 a = *(const bf16x8*)&sA[rA * K + gA * 8];
#pragma unroll
        for (int t = 0; t < N / 16; ++t) {
            int rB = t * 16 + (lane & 15);
            int gB = (ks * 4 + kg) ^ (rB & (GPR - 1));
            bf16x8 b = *(const bf16x8*)&sB[rB * K + gB * 8];
            acc[t] = __builtin_amdgcn_mfma_f32_16x16x32_bf16(a, b, acc[t], 0, 0, 0);
        }
    }

    const int crow = wave * 16 + (lane >> 4) * 4;
    const int ccol = lane & 15;
#pragma unroll
    for (int t = 0; t < N / 16; ++t) {
#pragma unroll
        for (int j = 0; j < 4; ++j) {
            int r = row0 + crow + j;
            if (!GUARD || r < M)
                H[(size_t)r * N + t * 16 + ccol] = f2b(acc[t][j]);
        }
    }
}

// ---------------- fused attention + building GEMM layer 1 (K=N=128) ----------------
__global__ __launch_bounds__(256) void gemm_att_k(const float* __restrict__ bF,
                                                  const unsigned short* __restrict__ cx,
                                                  const int* __restrict__ map,
                                                  const int* __restrict__ l2g,
                                                  const float* __restrict__ Watt,  // [128][2]
                                                  const float* __restrict__ batt,  // [2]
                                                  const unsigned short* __restrict__ Wt,  // [128][128]
                                                  unsigned short* __restrict__ H) {
    constexpr int K = 128, N = 128, GPR = 16;
    __shared__ unsigned short sA[64 * K];
    __shared__ unsigned short sB[N * K];
    __shared__ float sWt[256];
    const int tid = threadIdx.x;
    const int row0 = blockIdx.x * 64;
    sWt[tid] = Watt[tid];
    for (int idx = tid; idx < N * GPR; idx += 256) {
        int r = idx / GPR, g = idx % GPR;
        uint4 v = *(const uint4*)&Wt[(size_t)r * K + g * 8];
        int gs = g ^ (r & (GPR - 1));
        *(uint4*)&sB[r * K + gs * 8] = v;
    }
    __syncthreads();
    {
        const int r = tid >> 2, j = tid & 3;   // N_BUILD % 64 == 0 -> no guard
        const int g = l2g[row0 + r];
        float vals[32];
        if (j < 2) {
            const float* f1 = &bF[(size_t)g * 64 + j * 32];
#pragma unroll
            for (int t = 0; t < 8; ++t) {
                float4 v = *(const float4*)&f1[t * 4];
                vals[t*4+0]=v.x; vals[t*4+1]=v.y; vals[t*4+2]=v.z; vals[t*4+3]=v.w;
            }
        } else {
            const unsigned short* f2 = &cx[(size_t)map[g] * 64 + (j & 1) * 32];
#pragma unroll
            for (int t = 0; t < 4; ++t) {
                uint4 u = *(const uint4*)&f2[t * 8];
                up8(u, &vals[t * 8]);
            }
        }
        float l0 = 0.f, l1 = 0.f;
        const int ch0 = j * 32;
#pragma unroll
        for (int t = 0; t < 32; ++t) {
            l0 = fmaf(vals[t], sWt[(ch0 + t) * 2 + 0], l0);
            l1 = fmaf(vals[t], sWt[(ch0 + t) * 2 + 1], l1);
        }
        l0 += __shfl_xor(l0, 1, 4); l0 += __shfl_xor(l0, 2, 4);
        l1 += __shfl_xor(l1, 1, 4); l1 += __shfl_xor(l1, 2, 4);
        l0 += batt[0]; l1 += batt[1];
        float mm = fmaxf(l0, l1);
        float e0 = __expf(l0 - mm), e1 = __expf(l1 - mm);
        float a = ((j < 2) ? e0 : e1) / (e0 + e1);
#pragma unroll
        for (int t = 0; t < 4; ++t) {
            uint4 o;
            o.x = pk2(vals[t*8+0]*a, vals[t*8+1]*a);
            o.y = pk2(vals[t*8+2]*a, vals[t*8+3]*a);
            o.z = pk2(vals[t*8+4]*a, vals[t*8+5]*a);
            o.w = pk2(vals[t*8+6]*a, vals[t*8+7]*a);
            int gi = j * 4 + t;
            int gs = gi ^ (r & (GPR - 1));
            *(uint4*)&sA[r * K + gs * 8] = o;
        }
    }
    __syncthreads();
    const int wave = tid >> 6, lane = tid & 63;
    const int rA = wave * 16 + (lane & 15);
    const int kg = lane >> 4;
    f32x4 zero = {0.f, 0.f, 0.f, 0.f};
    f32x4 acc[8];
#pragma unroll
    for (int t = 0; t < 8; ++t) acc[t] = zero;
#pragma unroll
    for (int ks = 0; ks < 4; ++ks) {
        int gA = (ks * 4 + kg) ^ (rA & 15);
        bf16x8 a = *(const bf16x8*)&sA[rA * K + gA * 8];
#pragma unroll
        for (int t = 0; t < 8; ++t) {
            int rB = t * 16 + (lane & 15);
            int gB = (ks * 4 + kg) ^ (rB & 15);
            bf16x8 b = *(const bf16x8*)&sB[rB * K + gB * 8];
            acc[t] = __builtin_amdgcn_mfma_f32_16x16x32_bf16(a, b, acc[t], 0, 0, 0);
        }
    }
    const int crow = wave * 16 + (lane >> 4) * 4;
    const int ccol = lane & 15;
#pragma unroll
    for (int t = 0; t < 8; ++t)
#pragma unroll
        for (int jj = 0; jj < 4; ++jj)
            H[(size_t)(row0 + crow + jj) * N + t * 16 + ccol] = f2b(acc[t][jj]);
}

// ---------------- gathers: deep lane-split node packing ----------------
// F=128: 16 lanes/node (4 nodes/wave); F=64: 8 lanes/node (8 nodes/wave).
// Each lane owns 8 channels (uint4 = 16B); a wave's load instruction covers all its
// nodes' rows simultaneously -> per-node latency chains shrink by the packing factor.
template<int F, bool RELU>
__global__ __launch_bounds__(256) void gatherF_k(const int* __restrict__ rowptr,
                                                 const int2* __restrict__ cse,
                                                 const unsigned short* __restrict__ h,
                                                 const float* __restrict__ dinv,
                                                 const float* __restrict__ bias,
                                                 unsigned short* __restrict__ out, int nGrp) {
    constexpr int LPN = F / 8;              // lanes per node
    constexpr int NPW = 64 / LPN;           // nodes per wave
    int wid = (blockIdx.x * blockDim.x + threadIdx.x) >> 6;
    int lane = threadIdx.x & 63;
    if (wid >= nGrp) return;
    int node = wid * NPW + lane / LPN;
    int c = (lane % LPN) * 8;
    int beg = rowptr[node], end = rowptr[node + 1];
    uint4 hv = *(const uint4*)&h[(size_t)node * F + c];
    float iv = dinv[node];
    float4 bb0 = *(const float4*)&bias[c];
    float4 bb1 = *(const float4*)&bias[c + 4];
    float acc[8];
#pragma unroll
    for (int i = 0; i < 8; ++i) acc[i] = 0.f;
    for (int p = beg; p < end; p += 8) {
        int2 q[8]; uint4 v[8];
#pragma unroll
        for (int t = 0; t < 8; ++t) { int e = p + t; q[t] = cse[e < end ? e : 0]; }
#pragma unroll
        for (int t = 0; t < 8; ++t) v[t] = *(const uint4*)&h[(size_t)q[t].x * F + c];
#pragma unroll
        for (int t = 0; t < 8; ++t) {
            float w = (p + t < end) ? __int_as_float(q[t].y) : 0.f;
            float r[8]; up8(v[t], r);
#pragma unroll
            for (int i = 0; i < 8; ++i) acc[i] = fmaf(r[i], w, acc[i]);
        }
    }
    float hr[8]; up8(hv, hr);
    float o[8];
    o[0] = fmaf(hr[0], iv, acc[0]) + bb0.x; o[1] = fmaf(hr[1], iv, acc[1]) + bb0.y;
    o[2] = fmaf(hr[2], iv, acc[2]) + bb0.z; o[3] = fmaf(hr[3], iv, acc[3]) + bb0.w;
    o[4] = fmaf(hr[4], iv, acc[4]) + bb1.x; o[5] = fmaf(hr[5], iv, acc[5]) + bb1.y;
    o[6] = fmaf(hr[6], iv, acc[6]) + bb1.z; o[7] = fmaf(hr[7], iv, acc[7]) + bb1.w;
    if (RELU) {
#pragma unroll
        for (int i = 0; i < 8; ++i) o[i] = fmaxf(o[i], 0.f);
    }
    uint4 ov;
    ov.x = pk2(o[0], o[1]); ov.y = pk2(o[2], o[3]);
    ov.z = pk2(o[4], o[5]); ov.w = pk2(o[6], o[7]);
    *(uint4*)&out[(size_t)node * F + c] = ov;
}

// building layer-2 gather fused with layer-3 XW (64 -> 2): 8 nodes/wave, 8 lanes/node.
__global__ __launch_bounds__(256) void gather64_dot_k(const int* __restrict__ rowptr,
                                                      const int2* __restrict__ cse,
                                                      const unsigned short* __restrict__ h,
                                                      const float* __restrict__ dinv,
                                                      const float* __restrict__ bias,
                                                      const float* __restrict__ W3,  // [64][2]
                                                      float* __restrict__ Dh, int nOct) {
    int wid = (blockIdx.x * blockDim.x + threadIdx.x) >> 6;
    int lane = threadIdx.x & 63;
    if (wid >= nOct) return;
    int node = wid * 8 + (lane >> 3);
    int sl = lane & 7, c = sl * 8;
    int beg = rowptr[node], end = rowptr[node + 1];
    uint4 hv = *(const uint4*)&h[(size_t)node * 64 + c];
    float iv = dinv[node];
    float4 bb0 = *(const float4*)&bias[c];
    float4 bb1 = *(const float4*)&bias[c + 4];
    float4 w4[4];
#pragma unroll
    for (int i = 0; i < 4; ++i) w4[i] = *(const float4*)&W3[c * 2 + i * 4];
    float acc[8];
#pragma unroll
    for (int i = 0; i < 8; ++i) acc[i] = 0.f;
    for (int p = beg; p < end; p += 8) {
        int2 q[8]; uint4 v[8];
#pragma unroll
        for (int t = 0; t < 8; ++t) { int e = p + t; q[t] = cse[e < end ? e : 0]; }
#pragma unroll
        for (int t = 0; t < 8; ++t) v[t] = *(const uint4*)&h[(size_t)q[t].x * 64 + c];
#pragma unroll
        for (int t = 0; t < 8; ++t) {
            float w = (p + t < end) ? __int_as_float(q[t].y) : 0.f;
            float r[8]; up8(v[t], r);
#pragma unroll
            for (int i = 0; i < 8; ++i) acc[i] = fmaf(r[i], w, acc[i]);
        }
    }
    float hr[8]; up8(hv, hr);
    float o[8];
    o[0] = fmaf(hr[0], iv, acc[0]) + bb0.x; o[1] = fmaf(hr[1], iv, acc[1]) + bb0.y;
    o[2] = fmaf(hr[2], iv, acc[2]) + bb0.z; o[3] = fmaf(hr[3], iv, acc[3]) + bb0.w;
    o[4] = fmaf(hr[4], iv, acc[4]) + bb1.x; o[5] = fmaf(hr[5], iv, acc[5]) + bb1.y;
    o[6] = fmaf(hr[6], iv, acc[6]) + bb1.z; o[7] = fmaf(hr[7], iv, acc[7]) + bb1.w;
#pragma unroll
    for (int i = 0; i < 8; ++i) o[i] = fmaxf(o[i], 0.f);
    float d0 = 0.f, d1 = 0.f;
#pragma unroll
    for (int i = 0; i < 4; ++i) {
        d0 = fmaf(o[2*i],   w4[i].x, d0); d0 = fmaf(o[2*i+1], w4[i].z, d0);
        d1 = fmaf(o[2*i],   w4[i].y, d1); d1 = fmaf(o[2*i+1], w4[i].w, d1);
    }
#pragma unroll
    for (int m = 1; m < 8; m <<= 1) {
        d0 += __shfl_xor(d0, m, 8);
        d1 += __shfl_xor(d1, m, 8);
    }
    if (sl == 0) {
        Dh[2 * (size_t)node + 0] = d0;
        Dh[2 * (size_t)node + 1] = d1;
    }
}

// final layer: gather (F=2, f32) + bias + log-softmax + scatter to global order
__global__ __launch_bounds__(256) void gather2_logsm_k(const int* __restrict__ rowptr,
                                                       const int2* __restrict__ cse,
                                                       const float* __restrict__ h2,
                                                       const float* __restrict__ dinv,
                                                       const float* __restrict__ bias,
                                                       const int* __restrict__ l2g,
                                                       float* __restrict__ out, int n) {
    int i = blockIdx.x * blockDim.x + threadIdx.x;
    if (i >= n) return;
    int beg = rowptr[i], end = rowptr[i + 1];
    float2 hv = *(const float2*)&h2[2 * (size_t)i];
    float iv = dinv[i];
    float a = 0.f, b = 0.f;
    for (int p = beg; p < end; p += 8) {
        int2 q[8]; float2 v[8];
#pragma unroll
        for (int t = 0; t < 8; ++t) { int e = p + t; q[t] = cse[e < end ? e : 0]; }
#pragma unroll
        for (int t = 0; t < 8; ++t) v[t] = *(const float2*)&h2[2 * (size_t)q[t].x];
#pragma unroll
        for (int t = 0; t < 8; ++t) {
            float w = (p + t < end) ? __int_as_float(q[t].y) : 0.f;
            a = fmaf(v[t].x, w, a);
            b = fmaf(v[t].y, w, b);
        }
    }
    a = fmaf(hv.x, iv, a) + bias[0];
    b = fmaf(hv.y, iv, b) + bias[1];
    float m = fmaxf(a, b);
    float ls = m + logf(__expf(a - m) + __expf(b - m));
    int g = l2g[i];
    out[2 * (size_t)g + 0] = a - ls;
    out[2 * (size_t)g + 1] = b - ls;
}

// ---------------- launch ----------------

static inline dim3 g1(long long n, int tpb = 256) { return dim3((unsigned)((n + tpb - 1) / tpb)); }

extern "C" void kernel_launch(void* const* d_in, const int* in_sizes, int n_in,
                              void* d_out, int out_size, void* d_ws, size_t ws_size,
                              hipStream_t stream) {
    const float* bF   = (const float*)d_in[0];
    const float* cF   = (const float*)d_in[1];
    const float* W_c1 = (const float*)d_in[2];
    const float* b_c1 = (const float*)d_in[3];
    const float* W_c2 = (const float*)d_in[4];
    const float* b_c2 = (const float*)d_in[5];
    const float* W_at = (const float*)d_in[6];
    const float* b_at = (const float*)d_in[7];
    const float* W_b1 = (const float*)d_in[8];
    const float* b_b1 = (const float*)d_in[9];
    const float* W_b2 = (const float*)d_in[10];
    const float* b_b2 = (const float*)d_in[11];
    const float* W_b3 = (const float*)d_in[12];
    const float* b_b3 = (const float*)d_in[13];
    const int* b_src = (const int*)d_in[14];
    const int* b_dst = (const int*)d_in[15];
    const int* c_src = (const int*)d_in[16];
    const int* c_dst = (const int*)d_in[17];
    const int* map   = (const int*)d_in[18];
    const int* l2g   = (const int*)d_in[19];
    float* out = (float*)d_out;

    char* p = (char*)d_ws;
    auto alloc = [&](size_t bytes) { char* q = p; p += (bytes + 15) & ~(size_t)15; return q; };
    int*   cnt_b    = (int*)  alloc(N_BUILD * 4);
    int*   rowptr_b = (int*)  alloc((N_BUILD + 4) * 4);
    int*   cursor_b = (int*)  alloc(N_BUILD * 4);
    int*   bsum_b   = (int*)  alloc(256 * 4);
    int*   cnt_c    = (int*)  alloc(N_COMM * 4);
    int*   rowptr_c = (int*)  alloc((N_COMM + 4) * 4);
    int*   cursor_c = (int*)  alloc(N_COMM * 4);
    int*   bsum_c   = (int*)  alloc(256 * 4);
    int2*  cse_b    = (int2*) alloc((size_t)E_BUILD * 8);
    int2*  cse_c    = (int2*) alloc((size_t)E_COMM * 8);
    float* dinv_b   = (float*)alloc(N_BUILD * 4);
    float* dinv_c   = (float*)alloc(N_COMM * 4);
    unsigned short* cFb    = (unsigned short*)alloc((size_t)N_COMM * 32 * 2);
    unsigned short* Wt_c1  = (unsigned short*)alloc(64 * 32 * 2);
    unsigned short* Wt_c2  = (unsigned short*)alloc(64 * 64 * 2);
    unsigned short* Wt_b1  = (unsigned short*)alloc(128 * 128 * 2);
    unsigned short* Wt_b2  = (unsigned short*)alloc(64 * 128 * 2);
    unsigned short* ch_bf  = (unsigned short*)alloc((size_t)N_COMM * 64 * 2);
    unsigned short* cx1_bf = (unsigned short*)alloc((size_t)N_COMM * 64 * 2);
    unsigned short* cx2_bf = (unsigned short*)alloc((size_t)N_COMM * 64 * 2);
    unsigned short* A_bf   = (unsigned short*)alloc((size_t)N_BUILD * 128 * 2); // o1
    unsigned short* B_bf   = (unsigned short*)alloc((size_t)N_BUILD * 128 * 2); // h1 / h2
    float* Dh = (float*)alloc((size_t)N_BUILD * 2 * 4);

    // ---- init (counts zero + out prefill + weight prep), then CSR build both graphs ----
    init_k<<<g1(INIT_TOT), 256, 0, stream>>>(cnt_b, cnt_c, out,
                                             cF, cFb, W_c1, Wt_c1, W_c2, Wt_c2, W_b1, Wt_b1, W_b2, Wt_b2);
    hist2_k<<<g1(E_BUILD + E_COMM), 256, 0, stream>>>(cnt_b, b_dst, cnt_c, c_dst);
    scan1m_k<<<NB_B + NB_C, 256, 0, stream>>>(cnt_b, rowptr_b, bsum_b, cnt_c, rowptr_c, bsum_c);
    scan2m_k<<<2, 256, 0, stream>>>(bsum_b, bsum_c);
    finalizem_k<<<g1(N_BUILD + N_COMM), 256, 0, stream>>>(cnt_b, rowptr_b, bsum_b, cursor_b, dinv_b,
                                                          cnt_c, rowptr_c, bsum_c, cursor_c, dinv_c);
    csr_scatterp_k<<<8 * (CB_B + CB_C), 256, 0, stream>>>(b_src, b_dst, cursor_b, dinv_b, cse_b,
                                                          c_src, c_dst, cursor_c, dinv_c, cse_c);

    // ---- community GCN layer 1 (32 -> 64) + relu ----
    gemm_mfma_k<32, 64, true><<<dim3((N_COMM + 63) / 64), 256, 0, stream>>>(cFb, Wt_c1, ch_bf, N_COMM);
    gatherF_k<64, true><<<g1((long long)(N_COMM / 8) * 64), 256, 0, stream>>>(rowptr_c, cse_c, ch_bf, dinv_c, b_c1, cx1_bf, N_COMM / 8);

    // ---- community GCN layer 2 (64 -> 64) + relu ----
    gemm_mfma_k<64, 64, true><<<dim3((N_COMM + 63) / 64), 256, 0, stream>>>(cx1_bf, Wt_c2, ch_bf, N_COMM);
    gatherF_k<64, true><<<g1((long long)(N_COMM / 8) * 64), 256, 0, stream>>>(rowptr_c, cse_c, ch_bf, dinv_c, b_c2, cx2_bf, N_COMM / 8);

    // ---- building layer 1: fused attention + GEMM (128 -> 128), then gather + relu ----
    gemm_att_k<<<dim3(N_BUILD / 64), 256, 0, stream>>>(bF, cx2_bf, map, l2g, W_at, b_at, Wt_b1, B_bf);
    gatherF_k<128, true><<<g1((long long)(N_BUILD / 4) * 64), 256, 0, stream>>>(rowptr_b, cse_b, B_bf, dinv_b, b_b1, A_bf, N_BUILD / 4);

    // ---- building layer 2 (128 -> 64) + relu, fused with layer-3 XW ----
    gemm_mfma_k<128, 64, false><<<dim3(N_BUILD / 64), 256, 0, stream>>>(A_bf, Wt_b2, B_bf, N_BUILD);
    gather64_dot_k<<<g1((long long)(N_BUILD / 8) * 64), 256, 0, stream>>>(rowptr_b, cse_b, B_bf, dinv_b, b_b2, W_b3, Dh, N_BUILD / 8);

    // ---- building layer 3 aggregation + log-softmax + scatter ----
    gather2_logsm_k<<<g1(N_BUILD), 256, 0, stream>>>(rowptr_b, cse_b, Dh, dinv_b, b_b3, l2g, out, N_BUILD);
}

// Round 8
// 321.632 us; speedup vs baseline: 12.0318x; 1.0536x over previous
//
#include <hip/hip_runtime.h>
#include <hip/hip_bf16.h>
#include <math.h>

#define N_BUILD 200000
#define N_COMM  10000
#define E_BUILD 1200000
#define E_COMM  160000
#define NB_B 196   // scan blocks for building (200000/1024 rounded up)
#define NB_C 10
#define CHUNK 2048
#define CB_B ((E_BUILD + CHUNK - 1) / CHUNK)   // 586
#define CB_C ((E_COMM  + CHUNK - 1) / CHUNK)   // 79

typedef __bf16 bf16x8 __attribute__((ext_vector_type(8)));
typedef float  f32x4  __attribute__((ext_vector_type(4)));

// ---------------- bf16 helpers (RNE) ----------------
__device__ __forceinline__ unsigned short f2b(float f) {
    unsigned int u = __builtin_bit_cast(unsigned int, f);
    u += 0x7fffu + ((u >> 16) & 1u);
    return (unsigned short)(u >> 16);
}
__device__ __forceinline__ float b2f(unsigned short h) {
    unsigned int u = ((unsigned int)h) << 16;
    return __builtin_bit_cast(float, u);
}
__device__ __forceinline__ unsigned int pk2(float a, float b) {
    return (unsigned int)f2b(a) | ((unsigned int)f2b(b) << 16);
}
__device__ __forceinline__ void up8(uint4 v, float* r) {
    r[0] = b2f((unsigned short)v.x); r[1] = b2f((unsigned short)(v.x >> 16));
    r[2] = b2f((unsigned short)v.y); r[3] = b2f((unsigned short)(v.y >> 16));
    r[4] = b2f((unsigned short)v.z); r[5] = b2f((unsigned short)(v.z >> 16));
    r[6] = b2f((unsigned short)v.w); r[7] = b2f((unsigned short)(v.w >> 16));
}

// ---------------- merged init: zero counts + out prefill + all weight prep ----------------
#define INIT_TOT (N_BUILD + N_COMM + 2 * N_BUILD + N_COMM * 32 + 2048 + 4096 + 16384 + 8192)
__global__ __launch_bounds__(256) void init_k(int* cnt_b, int* cnt_c, float* out,
                                              const float* __restrict__ cF, unsigned short* __restrict__ cFb,
                                              const float* __restrict__ W_c1, unsigned short* __restrict__ Wt_c1,
                                              const float* __restrict__ W_c2, unsigned short* __restrict__ Wt_c2,
                                              const float* __restrict__ W_b1, unsigned short* __restrict__ Wt_b1,
                                              const float* __restrict__ W_b2, unsigned short* __restrict__ Wt_b2) {
    int i = blockIdx.x * blockDim.x + threadIdx.x;
    if (i < N_BUILD) { cnt_b[i] = 0; return; }
    i -= N_BUILD;
    if (i < N_COMM) { cnt_c[i] = 0; return; }
    i -= N_COMM;
    if (i < 2 * N_BUILD) { out[i] = -0.69314718056f; return; }
    i -= 2 * N_BUILD;
    if (i < N_COMM * 32) { cFb[i] = f2b(cF[i]); return; }
    i -= N_COMM * 32;
    if (i < 2048) { Wt_c1[(i % 64) * 32 + i / 64] = f2b(W_c1[i]); return; }
    i -= 2048;
    if (i < 4096) { Wt_c2[(i % 64) * 64 + i / 64] = f2b(W_c2[i]); return; }
    i -= 4096;
    if (i < 16384) { Wt_b1[(i % 128) * 128 + i / 128] = f2b(W_b1[i]); return; }
    i -= 16384;
    if (i < 8192) { Wt_b2[(i % 64) * 128 + i / 64] = f2b(W_b2[i]); }
}

// ---------------- merged CSR build kernels ----------------

__global__ __launch_bounds__(256) void hist2_k(int* cnt_b, const int* __restrict__ b_dst,
                                               int* cnt_c, const int* __restrict__ c_dst) {
    int i = blockIdx.x * blockDim.x + threadIdx.x;
    if (i < E_BUILD) atomicAdd(&cnt_b[b_dst[i]], 1);
    else if (i < E_BUILD + E_COMM) atomicAdd(&cnt_c[c_dst[i - E_BUILD]], 1);
}

__global__ __launch_bounds__(256) void scan1m_k(const int* __restrict__ cnt_b, int* __restrict__ ex_b, int* __restrict__ bs_b,
                                                const int* __restrict__ cnt_c, int* __restrict__ ex_c, int* __restrict__ bs_c) {
    __shared__ int sdata[256];
    const int tid = threadIdx.x;
    const int* cnt; int* ex; int* bs; int n, blk;
    if ((int)blockIdx.x < NB_B) { cnt = cnt_b; ex = ex_b; bs = bs_b; n = N_BUILD; blk = blockIdx.x; }
    else                        { cnt = cnt_c; ex = ex_c; bs = bs_c; n = N_COMM;  blk = blockIdx.x - NB_B; }
    const int base = blk * 1024 + tid * 4;
    int v[4]; int s = 0;
#pragma unroll
    for (int j = 0; j < 4; ++j) { v[j] = (base + j < n) ? cnt[base + j] : 0; s += v[j]; }
    sdata[tid] = s; __syncthreads();
    for (int off = 1; off < 256; off <<= 1) {
        int t = (tid >= off) ? sdata[tid - off] : 0;
        __syncthreads();
        sdata[tid] += t;
        __syncthreads();
    }
    if (tid == 255) bs[blk] = sdata[255];
    int run = sdata[tid] - s;
#pragma unroll
    for (int j = 0; j < 4; ++j) { if (base + j < n) ex[base + j] = run; run += v[j]; }
}

__global__ __launch_bounds__(256) void scan2m_k(int* bs_b, int* bs_c) {
    __shared__ int sdata[256];
    int* bs = (blockIdx.x == 0) ? bs_b : bs_c;
    int nb  = (blockIdx.x == 0) ? NB_B : NB_C;
    const int tid = threadIdx.x;
    int v = (tid < nb) ? bs[tid] : 0;
    sdata[tid] = v; __syncthreads();
    for (int off = 1; off < 256; off <<= 1) {
        int t = (tid >= off) ? sdata[tid - off] : 0;
        __syncthreads();
        sdata[tid] += t;
        __syncthreads();
    }
    if (tid < nb) bs[tid] = sdata[tid] - v;
}

__global__ __launch_bounds__(256) void finalizem_k(const int* __restrict__ cnt_b, int* rp_b, const int* __restrict__ bo_b,
                                                   int* cur_b, float* di_b,
                                                   const int* __restrict__ cnt_c, int* rp_c, const int* __restrict__ bo_c,
                                                   int* cur_c, float* di_c) {
    int i = blockIdx.x * blockDim.x + threadIdx.x;
    if (i < N_BUILD) {
        int cc = cnt_b[i];
        int r = rp_b[i] + bo_b[i >> 10];
        rp_b[i] = r; cur_b[i] = r; di_b[i] = 1.0f / (float)(cc + 1);
        if (i == 0) { rp_b[N_BUILD] = E_BUILD; rp_c[N_COMM] = E_COMM; }
    } else if (i < N_BUILD + N_COMM) {
        int ic = i - N_BUILD;
        int cc = cnt_c[ic];
        int r = rp_c[ic] + bo_c[ic >> 10];
        rp_c[ic] = r; cur_c[ic] = r; di_c[ic] = 1.0f / (float)(cc + 1);
    }
}

// XCD-range-partitioned CSR scatter (kills partial-dirty-line write amplification).
template<int NDIV>
__device__ __forceinline__ void scatter_part(const int* __restrict__ src, const int* __restrict__ dst,
                                             int* cur, const float* __restrict__ di,
                                             int2* __restrict__ cse, int E, int cid, int x) {
    int base = cid * CHUNK + threadIdx.x;
#pragma unroll
    for (int j = 0; j < CHUNK / 256; ++j, base += 256) {
        if (base < E) {
            int d = dst[base];
            if ((unsigned)d / (unsigned)NDIV == (unsigned)x) {
                int s = src[base];
                int pos = atomicAdd(&cur[d], 1);
                cse[pos] = make_int2(s, __float_as_int(sqrtf(di[s] * di[d])));
            }
        }
    }
}

__global__ __launch_bounds__(256) void csr_scatterp_k(const int* __restrict__ b_src, const int* __restrict__ b_dst,
                                                      int* cur_b, const float* __restrict__ di_b, int2* __restrict__ cse_b,
                                                      const int* __restrict__ c_src, const int* __restrict__ c_dst,
                                                      int* cur_c, const float* __restrict__ di_c, int2* __restrict__ cse_c) {
    int bid = blockIdx.x;
    if (bid < 8 * CB_B) {
        scatter_part<N_BUILD / 8>(b_src, b_dst, cur_b, di_b, cse_b, E_BUILD, bid >> 3, bid & 7);
    } else {
        bid -= 8 * CB_B;
        scatter_part<N_COMM / 8>(c_src, c_dst, cur_c, di_c, cse_c, E_COMM, bid >> 3, bid & 7);
    }
}

// ---------------- MFMA GEMM: H[M][N] (bf16) = X[M][K] (bf16) @ Wt[N][K]^T ----------------
template<int K, int N, bool GUARD>
__global__ __launch_bounds__(256) void gemm_mfma_k(const unsigned short* __restrict__ X,
                                                   const unsigned short* __restrict__ Wt,
                                                   unsigned short* __restrict__ H, int M) {
    constexpr int GPR = K / 8;
    __shared__ unsigned short sA[64 * K];
    __shared__ unsigned short sB[N * K];
    const int tid  = threadIdx.x;
    const int row0 = blockIdx.x * 64;

    for (int idx = tid; idx < 64 * GPR; idx += 256) {
        int r = idx / GPR, g = idx % GPR;
        uint4 v = make_uint4(0u, 0u, 0u, 0u);
        if (!GUARD || row0 + r < M)
            v = *(const uint4*)&X[(size_t)(row0 + r) * K + g * 8];
        int gs = g ^ (r & (GPR - 1));
        *(uint4*)&sA[r * K + gs * 8] = v;
    }
    for (int idx = tid; idx < N * GPR; idx += 256) {
        int r = idx / GPR, g = idx % GPR;
        uint4 v = *(const uint4*)&Wt[(size_t)r * K + g * 8];
        int gs = g ^ (r & (GPR - 1));
        *(uint4*)&sB[r * K + gs * 8] = v;
    }
    __syncthreads();

    const int wave = tid >> 6, lane = tid & 63;
    const int rA = wave * 16 + (lane & 15);
    const int kg = lane >> 4;

    f32x4 zero = {0.f, 0.f, 0.f, 0.f};
    f32x4 acc[N / 16];
#pragma unroll
    for (int t = 0; t < N / 16; ++t) acc[t] = zero;

#pragma unroll
    for (int ks = 0; ks < K / 32; ++ks) {
        int gA = (ks * 4 + kg) ^ (rA & (GPR - 1));
        bf16x8 a = *(const bf16x8*)&sA[rA * K + gA * 8];
#pragma unroll
        for (int t = 0; t < N / 16; ++t) {
            int rB = t * 16 + (lane & 15);
            int gB = (ks * 4 + kg) ^ (rB & (GPR - 1));
            bf16x8 b = *(const bf16x8*)&sB[rB * K + gB * 8];
            acc[t] = __builtin_amdgcn_mfma_f32_16x16x32_bf16(a, b, acc[t], 0, 0, 0);
        }
    }

    const int crow = wave * 16 + (lane >> 4) * 4;
    const int ccol = lane & 15;
#pragma unroll
    for (int t = 0; t < N / 16; ++t) {
#pragma unroll
        for (int j = 0; j < 4; ++j) {
            int r = row0 + crow + j;
            if (!GUARD || r < M)
                H[(size_t)r * N + t * 16 + ccol] = f2b(acc[t][j]);
        }
    }
}

// ---------------- fused attention + building GEMM layer 1 (K=N=128) ----------------
__global__ __launch_bounds__(256) void gemm_att_k(const float* __restrict__ bF,
                                                  const unsigned short* __restrict__ cx,
                                                  const int* __restrict__ map,
                                                  const int* __restrict__ l2g,
                                                  const float* __restrict__ Watt,  // [128][2]
                                                  const float* __restrict__ batt,  // [2]
                                                  const unsigned short* __restrict__ Wt,  // [128][128]
                                                  unsigned short* __restrict__ H) {
    constexpr int K = 128, N = 128, GPR = 16;
    __shared__ unsigned short sA[64 * K];
    __shared__ unsigned short sB[N * K];
    __shared__ float sWt[256];
    const int tid = threadIdx.x;
    const int row0 = blockIdx.x * 64;
    sWt[tid] = Watt[tid];
    for (int idx = tid; idx < N * GPR; idx += 256) {
        int r = idx / GPR, g = idx % GPR;
        uint4 v = *(const uint4*)&Wt[(size_t)r * K + g * 8];
        int gs = g ^ (r & (GPR - 1));
        *(uint4*)&sB[r * K + gs * 8] = v;
    }
    __syncthreads();
    {
        const int r = tid >> 2, j = tid & 3;   // N_BUILD % 64 == 0 -> no guard
        const int g = l2g[row0 + r];
        float vals[32];
        if (j < 2) {
            const float* f1 = &bF[(size_t)g * 64 + j * 32];
#pragma unroll
            for (int t = 0; t < 8; ++t) {
                float4 v = *(const float4*)&f1[t * 4];
                vals[t*4+0]=v.x; vals[t*4+1]=v.y; vals[t*4+2]=v.z; vals[t*4+3]=v.w;
            }
        } else {
            const unsigned short* f2 = &cx[(size_t)map[g] * 64 + (j & 1) * 32];
#pragma unroll
            for (int t = 0; t < 4; ++t) {
                uint4 u = *(const uint4*)&f2[t * 8];
                up8(u, &vals[t * 8]);
            }
        }
        float l0 = 0.f, l1 = 0.f;
        const int ch0 = j * 32;
#pragma unroll
        for (int t = 0; t < 32; ++t) {
            l0 = fmaf(vals[t], sWt[(ch0 + t) * 2 + 0], l0);
            l1 = fmaf(vals[t], sWt[(ch0 + t) * 2 + 1], l1);
        }
        l0 += __shfl_xor(l0, 1, 4); l0 += __shfl_xor(l0, 2, 4);
        l1 += __shfl_xor(l1, 1, 4); l1 += __shfl_xor(l1, 2, 4);
        l0 += batt[0]; l1 += batt[1];
        float mm = fmaxf(l0, l1);
        float e0 = __expf(l0 - mm), e1 = __expf(l1 - mm);
        float a = ((j < 2) ? e0 : e1) / (e0 + e1);
#pragma unroll
        for (int t = 0; t < 4; ++t) {
            uint4 o;
            o.x = pk2(vals[t*8+0]*a, vals[t*8+1]*a);
            o.y = pk2(vals[t*8+2]*a, vals[t*8+3]*a);
            o.z = pk2(vals[t*8+4]*a, vals[t*8+5]*a);
            o.w = pk2(vals[t*8+6]*a, vals[t*8+7]*a);
            int gi = j * 4 + t;
            int gs = gi ^ (r & (GPR - 1));
            *(uint4*)&sA[r * K + gs * 8] = o;
        }
    }
    __syncthreads();
    const int wave = tid >> 6, lane = tid & 63;
    const int rA = wave * 16 + (lane & 15);
    const int kg = lane >> 4;
    f32x4 zero = {0.f, 0.f, 0.f, 0.f};
    f32x4 acc[8];
#pragma unroll
    for (int t = 0; t < 8; ++t) acc[t] = zero;
#pragma unroll
    for (int ks = 0; ks < 4; ++ks) {
        int gA = (ks * 4 + kg) ^ (rA & 15);
        bf16x8 a = *(const bf16x8*)&sA[rA * K + gA * 8];
#pragma unroll
        for (int t = 0; t < 8; ++t) {
            int rB = t * 16 + (lane & 15);
            int gB = (ks * 4 + kg) ^ (rB & 15);
            bf16x8 b = *(const bf16x8*)&sB[rB * K + gB * 8];
            acc[t] = __builtin_amdgcn_mfma_f32_16x16x32_bf16(a, b, acc[t], 0, 0, 0);
        }
    }
    const int crow = wave * 16 + (lane >> 4) * 4;
    const int ccol = lane & 15;
#pragma unroll
    for (int t = 0; t < 8; ++t)
#pragma unroll
        for (int jj = 0; jj < 4; ++jj)
            H[(size_t)(row0 + crow + jj) * N + t * 16 + ccol] = f2b(acc[t][jj]);
}

// ---------------- fused building layer-1 aggregation + layer-2 GEMM ----------------
// Block handles 64 nodes: (1) gather-aggregate o1 = relu(agg(h1)+h1/deg+b1) straight
// into LDS (never touches global), (2) MFMA o1 @ Wt_b2 -> h2[64][64].
// Eliminates the 51MB o1 write + 51MB o1 read of the unfused pipeline.
__global__ __launch_bounds__(256) void gather_gemm_k(const int* __restrict__ rowptr,
                                                     const int2* __restrict__ cse,
                                                     const unsigned short* __restrict__ h,     // h1 [N][128]
                                                     const float* __restrict__ dinv,
                                                     const float* __restrict__ bias,           // b_b1 [128]
                                                     const unsigned short* __restrict__ Wt,    // Wt_b2 [64][128]
                                                     unsigned short* __restrict__ H) {         // h2 [N][64]
    constexpr int K = 128, N = 64, GPR = 16;
    __shared__ unsigned short sA[64 * K];
    __shared__ unsigned short sB[N * K];
    const int tid = threadIdx.x;
    const int row0 = blockIdx.x * 64;
    // stage Wt_b2 (swizzled)
    for (int idx = tid; idx < N * GPR; idx += 256) {
        int r = idx / GPR, g = idx % GPR;
        uint4 v = *(const uint4*)&Wt[(size_t)r * K + g * 8];
        int gs = g ^ (r & (GPR - 1));
        *(uint4*)&sB[r * K + gs * 8] = v;
    }
    // gather phase: each wave aggregates 16 nodes (4 sub-batches of 4 nodes, 16 lanes/node)
    const int lane = tid & 63;
    const int wave = tid >> 6;
    const int slot = lane >> 4;          // node slot within sub-batch
    const int c = (lane & 15) * 8;       // channel base (8 ch = 16B per lane)
#pragma unroll
    for (int sb = 0; sb < 4; ++sb) {
        const int r = wave * 16 + sb * 4 + slot;   // LDS row 0..63
        const int node = row0 + r;
        int beg = rowptr[node], end = rowptr[node + 1];
        uint4 hv = *(const uint4*)&h[(size_t)node * K + c];
        float iv = dinv[node];
        float4 bb0 = *(const float4*)&bias[c];
        float4 bb1 = *(const float4*)&bias[c + 4];
        float acc[8];
#pragma unroll
        for (int i = 0; i < 8; ++i) acc[i] = 0.f;
        for (int p = beg; p < end; p += 8) {
            int2 q[8]; uint4 v[8];
#pragma unroll
            for (int t = 0; t < 8; ++t) { int e = p + t; q[t] = cse[e < end ? e : 0]; }
#pragma unroll
            for (int t = 0; t < 8; ++t) v[t] = *(const uint4*)&h[(size_t)q[t].x * K + c];
#pragma unroll
            for (int t = 0; t < 8; ++t) {
                float w = (p + t < end) ? __int_as_float(q[t].y) : 0.f;
                float rr[8]; up8(v[t], rr);
#pragma unroll
                for (int i = 0; i < 8; ++i) acc[i] = fmaf(rr[i], w, acc[i]);
            }
        }
        float hr[8]; up8(hv, hr);
        float o[8];
        o[0] = fmaf(hr[0], iv, acc[0]) + bb0.x; o[1] = fmaf(hr[1], iv, acc[1]) + bb0.y;
        o[2] = fmaf(hr[2], iv, acc[2]) + bb0.z; o[3] = fmaf(hr[3], iv, acc[3]) + bb0.w;
        o[4] = fmaf(hr[4], iv, acc[4]) + bb1.x; o[5] = fmaf(hr[5], iv, acc[5]) + bb1.y;
        o[6] = fmaf(hr[6], iv, acc[6]) + bb1.z; o[7] = fmaf(hr[7], iv, acc[7]) + bb1.w;
#pragma unroll
        for (int i = 0; i < 8; ++i) o[i] = fmaxf(o[i], 0.f);
        uint4 ov;
        ov.x = pk2(o[0], o[1]); ov.y = pk2(o[2], o[3]);
        ov.z = pk2(o[4], o[5]); ov.w = pk2(o[6], o[7]);
        const int g = lane & 15;
        const int gs = g ^ (r & (GPR - 1));
        *(uint4*)&sA[r * K + gs * 8] = ov;
    }
    __syncthreads();
    // MFMA phase: h2[64][64] = sA @ sB^T
    const int rA = wave * 16 + (lane & 15);
    const int kg = lane >> 4;
    f32x4 zero = {0.f, 0.f, 0.f, 0.f};
    f32x4 acc[4];
#pragma unroll
    for (int t = 0; t < 4; ++t) acc[t] = zero;
#pragma unroll
    for (int ks = 0; ks < 4; ++ks) {
        int gA = (ks * 4 + kg) ^ (rA & (GPR - 1));
        bf16x8 a = *(const bf16x8*)&sA[rA * K + gA * 8];
#pragma unroll
        for (int t = 0; t < 4; ++t) {
            int rB = t * 16 + (lane & 15);
            int gB = (ks * 4 + kg) ^ (rB & (GPR - 1));
            bf16x8 b = *(const bf16x8*)&sB[rB * K + gB * 8];
            acc[t] = __builtin_amdgcn_mfma_f32_16x16x32_bf16(a, b, acc[t], 0, 0, 0);
        }
    }
    const int crow = wave * 16 + (lane >> 4) * 4;
    const int ccol = lane & 15;
#pragma unroll
    for (int t = 0; t < 4; ++t)
#pragma unroll
        for (int jj = 0; jj < 4; ++jj)
            H[(size_t)(row0 + crow + jj) * N + t * 16 + ccol] = f2b(acc[t][jj]);
}

// ---------------- gathers: deep lane-split node packing ----------------
template<int F, bool RELU>
__global__ __launch_bounds__(256) void gatherF_k(const int* __restrict__ rowptr,
                                                 const int2* __restrict__ cse,
                                                 const unsigned short* __restrict__ h,
                                                 const float* __restrict__ dinv,
                                                 const float* __restrict__ bias,
                                                 unsigned short* __restrict__ out, int nGrp) {
    constexpr int LPN = F / 8;              // lanes per node
    constexpr int NPW = 64 / LPN;           // nodes per wave
    int wid = (blockIdx.x * blockDim.x + threadIdx.x) >> 6;
    int lane = threadIdx.x & 63;
    if (wid >= nGrp) return;
    int node = wid * NPW + lane / LPN;
    int c = (lane % LPN) * 8;
    int beg = rowptr[node], end = rowptr[node + 1];
    uint4 hv = *(const uint4*)&h[(size_t)node * F + c];
    float iv = dinv[node];
    float4 bb0 = *(const float4*)&bias[c];
    float4 bb1 = *(const float4*)&bias[c + 4];
    float acc[8];
#pragma unroll
    for (int i = 0; i < 8; ++i) acc[i] = 0.f;
    for (int p = beg; p < end; p += 8) {
        int2 q[8]; uint4 v[8];
#pragma unroll
        for (int t = 0; t < 8; ++t) { int e = p + t; q[t] = cse[e < end ? e : 0]; }
#pragma unroll
        for (int t = 0; t < 8; ++t) v[t] = *(const uint4*)&h[(size_t)q[t].x * F + c];
#pragma unroll
        for (int t = 0; t < 8; ++t) {
            float w = (p + t < end) ? __int_as_float(q[t].y) : 0.f;
            float r[8]; up8(v[t], r);
#pragma unroll
            for (int i = 0; i < 8; ++i) acc[i] = fmaf(r[i], w, acc[i]);
        }
    }
    float hr[8]; up8(hv, hr);
    float o[8];
    o[0] = fmaf(hr[0], iv, acc[0]) + bb0.x; o[1] = fmaf(hr[1], iv, acc[1]) + bb0.y;
    o[2] = fmaf(hr[2], iv, acc[2]) + bb0.z; o[3] = fmaf(hr[3], iv, acc[3]) + bb0.w;
    o[4] = fmaf(hr[4], iv, acc[4]) + bb1.x; o[5] = fmaf(hr[5], iv, acc[5]) + bb1.y;
    o[6] = fmaf(hr[6], iv, acc[6]) + bb1.z; o[7] = fmaf(hr[7], iv, acc[7]) + bb1.w;
    if (RELU) {
#pragma unroll
        for (int i = 0; i < 8; ++i) o[i] = fmaxf(o[i], 0.f);
    }
    uint4 ov;
    ov.x = pk2(o[0], o[1]); ov.y = pk2(o[2], o[3]);
    ov.z = pk2(o[4], o[5]); ov.w = pk2(o[6], o[7]);
    *(uint4*)&out[(size_t)node * F + c] = ov;
}

// building layer-2 gather fused with layer-3 XW (64 -> 2): 8 nodes/wave, 8 lanes/node.
__global__ __launch_bounds__(256) void gather64_dot_k(const int* __restrict__ rowptr,
                                                      const int2* __restrict__ cse,
                                                      const unsigned short* __restrict__ h,
                                                      const float* __restrict__ dinv,
                                                      const float* __restrict__ bias,
                                                      const float* __restrict__ W3,  // [64][2]
                                                      float* __restrict__ Dh, int nOct) {
    int wid = (blockIdx.x * blockDim.x + threadIdx.x) >> 6;
    int lane = threadIdx.x & 63;
    if (wid >= nOct) return;
    int node = wid * 8 + (lane >> 3);
    int sl = lane & 7, c = sl * 8;
    int beg = rowptr[node], end = rowptr[node + 1];
    uint4 hv = *(const uint4*)&h[(size_t)node * 64 + c];
    float iv = dinv[node];
    float4 bb0 = *(const float4*)&bias[c];
    float4 bb1 = *(const float4*)&bias[c + 4];
    float4 w4[4];
#pragma unroll
    for (int i = 0; i < 4; ++i) w4[i] = *(const float4*)&W3[c * 2 + i * 4];
    float acc[8];
#pragma unroll
    for (int i = 0; i < 8; ++i) acc[i] = 0.f;
    for (int p = beg; p < end; p += 8) {
        int2 q[8]; uint4 v[8];
#pragma unroll
        for (int t = 0; t < 8; ++t) { int e = p + t; q[t] = cse[e < end ? e : 0]; }
#pragma unroll
        for (int t = 0; t < 8; ++t) v[t] = *(const uint4*)&h[(size_t)q[t].x * 64 + c];
#pragma unroll
        for (int t = 0; t < 8; ++t) {
            float w = (p + t < end) ? __int_as_float(q[t].y) : 0.f;
            float r[8]; up8(v[t], r);
#pragma unroll
            for (int i = 0; i < 8; ++i) acc[i] = fmaf(r[i], w, acc[i]);
        }
    }
    float hr[8]; up8(hv, hr);
    float o[8];
    o[0] = fmaf(hr[0], iv, acc[0]) + bb0.x; o[1] = fmaf(hr[1], iv, acc[1]) + bb0.y;
    o[2] = fmaf(hr[2], iv, acc[2]) + bb0.z; o[3] = fmaf(hr[3], iv, acc[3]) + bb0.w;
    o[4] = fmaf(hr[4], iv, acc[4]) + bb1.x; o[5] = fmaf(hr[5], iv, acc[5]) + bb1.y;
    o[6] = fmaf(hr[6], iv, acc[6]) + bb1.z; o[7] = fmaf(hr[7], iv, acc[7]) + bb1.w;
#pragma unroll
    for (int i = 0; i < 8; ++i) o[i] = fmaxf(o[i], 0.f);
    float d0 = 0.f, d1 = 0.f;
#pragma unroll
    for (int i = 0; i < 4; ++i) {
        d0 = fmaf(o[2*i],   w4[i].x, d0); d0 = fmaf(o[2*i+1], w4[i].z, d0);
        d1 = fmaf(o[2*i],   w4[i].y, d1); d1 = fmaf(o[2*i+1], w4[i].w, d1);
    }
#pragma unroll
    for (int m = 1; m < 8; m <<= 1) {
        d0 += __shfl_xor(d0, m, 8);
        d1 += __shfl_xor(d1, m, 8);
    }
    if (sl == 0) {
        Dh[2 * (size_t)node + 0] = d0;
        Dh[2 * (size_t)node + 1] = d1;
    }
}

// final layer: gather (F=2, f32) + bias + log-softmax + scatter to global order
__global__ __launch_bounds__(256) void gather2_logsm_k(const int* __restrict__ rowptr,
                                                       const int2* __restrict__ cse,
                                                       const float* __restrict__ h2,
                                                       const float* __restrict__ dinv,
                                                       const float* __restrict__ bias,
                                                       const int* __restrict__ l2g,
                                                       float* __restrict__ out, int n) {
    int i = blockIdx.x * blockDim.x + threadIdx.x;
    if (i >= n) return;
    int beg = rowptr[i], end = rowptr[i + 1];
    float2 hv = *(const float2*)&h2[2 * (size_t)i];
    float iv = dinv[i];
    float a = 0.f, b = 0.f;
    for (int p = beg; p < end; p += 8) {
        int2 q[8]; float2 v[8];
#pragma unroll
        for (int t = 0; t < 8; ++t) { int e = p + t; q[t] = cse[e < end ? e : 0]; }
#pragma unroll
        for (int t = 0; t < 8; ++t) v[t] = *(const float2*)&h2[2 * (size_t)q[t].x];
#pragma unroll
        for (int t = 0; t < 8; ++t) {
            float w = (p + t < end) ? __int_as_float(q[t].y) : 0.f;
            a = fmaf(v[t].x, w, a);
            b = fmaf(v[t].y, w, b);
        }
    }
    a = fmaf(hv.x, iv, a) + bias[0];
    b = fmaf(hv.y, iv, b) + bias[1];
    float m = fmaxf(a, b);
    float ls = m + logf(__expf(a - m) + __expf(b - m));
    int g = l2g[i];
    out[2 * (size_t)g + 0] = a - ls;
    out[2 * (size_t)g + 1] = b - ls;
}

// ---------------- launch ----------------

static inline dim3 g1(long long n, int tpb = 256) { return dim3((unsigned)((n + tpb - 1) / tpb)); }

extern "C" void kernel_launch(void* const* d_in, const int* in_sizes, int n_in,
                              void* d_out, int out_size, void* d_ws, size_t ws_size,
                              hipStream_t stream) {
    const float* bF   = (const float*)d_in[0];
    const float* cF   = (const float*)d_in[1];
    const float* W_c1 = (const float*)d_in[2];
    const float* b_c1 = (const float*)d_in[3];
    const float* W_c2 = (const float*)d_in[4];
    const float* b_c2 = (const float*)d_in[5];
    const float* W_at = (const float*)d_in[6];
    const float* b_at = (const float*)d_in[7];
    const float* W_b1 = (const float*)d_in[8];
    const float* b_b1 = (const float*)d_in[9];
    const float* W_b2 = (const float*)d_in[10];
    const float* b_b2 = (const float*)d_in[11];
    const float* W_b3 = (const float*)d_in[12];
    const float* b_b3 = (const float*)d_in[13];
    const int* b_src = (const int*)d_in[14];
    const int* b_dst = (const int*)d_in[15];
    const int* c_src = (const int*)d_in[16];
    const int* c_dst = (const int*)d_in[17];
    const int* map   = (const int*)d_in[18];
    const int* l2g   = (const int*)d_in[19];
    float* out = (float*)d_out;

    char* p = (char*)d_ws;
    auto alloc = [&](size_t bytes) { char* q = p; p += (bytes + 15) & ~(size_t)15; return q; };
    int*   cnt_b    = (int*)  alloc(N_BUILD * 4);
    int*   rowptr_b = (int*)  alloc((N_BUILD + 4) * 4);
    int*   cursor_b = (int*)  alloc(N_BUILD * 4);
    int*   bsum_b   = (int*)  alloc(256 * 4);
    int*   cnt_c    = (int*)  alloc(N_COMM * 4);
    int*   rowptr_c = (int*)  alloc((N_COMM + 4) * 4);
    int*   cursor_c = (int*)  alloc(N_COMM * 4);
    int*   bsum_c   = (int*)  alloc(256 * 4);
    int2*  cse_b    = (int2*) alloc((size_t)E_BUILD * 8);
    int2*  cse_c    = (int2*) alloc((size_t)E_COMM * 8);
    float* dinv_b   = (float*)alloc(N_BUILD * 4);
    float* dinv_c   = (float*)alloc(N_COMM * 4);
    unsigned short* cFb    = (unsigned short*)alloc((size_t)N_COMM * 32 * 2);
    unsigned short* Wt_c1  = (unsigned short*)alloc(64 * 32 * 2);
    unsigned short* Wt_c2  = (unsigned short*)alloc(64 * 64 * 2);
    unsigned short* Wt_b1  = (unsigned short*)alloc(128 * 128 * 2);
    unsigned short* Wt_b2  = (unsigned short*)alloc(64 * 128 * 2);
    unsigned short* ch_bf  = (unsigned short*)alloc((size_t)N_COMM * 64 * 2);
    unsigned short* cx1_bf = (unsigned short*)alloc((size_t)N_COMM * 64 * 2);
    unsigned short* cx2_bf = (unsigned short*)alloc((size_t)N_COMM * 64 * 2);
    unsigned short* A_bf   = (unsigned short*)alloc((size_t)N_BUILD * 128 * 2); // h2
    unsigned short* B_bf   = (unsigned short*)alloc((size_t)N_BUILD * 128 * 2); // h1
    float* Dh = (float*)alloc((size_t)N_BUILD * 2 * 4);

    // ---- init (counts zero + out prefill + weight prep), then CSR build both graphs ----
    init_k<<<g1(INIT_TOT), 256, 0, stream>>>(cnt_b, cnt_c, out,
                                             cF, cFb, W_c1, Wt_c1, W_c2, Wt_c2, W_b1, Wt_b1, W_b2, Wt_b2);
    hist2_k<<<g1(E_BUILD + E_COMM), 256, 0, stream>>>(cnt_b, b_dst, cnt_c, c_dst);
    scan1m_k<<<NB_B + NB_C, 256, 0, stream>>>(cnt_b, rowptr_b, bsum_b, cnt_c, rowptr_c, bsum_c);
    scan2m_k<<<2, 256, 0, stream>>>(bsum_b, bsum_c);
    finalizem_k<<<g1(N_BUILD + N_COMM), 256, 0, stream>>>(cnt_b, rowptr_b, bsum_b, cursor_b, dinv_b,
                                                          cnt_c, rowptr_c, bsum_c, cursor_c, dinv_c);
    csr_scatterp_k<<<8 * (CB_B + CB_C), 256, 0, stream>>>(b_src, b_dst, cursor_b, dinv_b, cse_b,
                                                          c_src, c_dst, cursor_c, dinv_c, cse_c);

    // ---- community GCN layer 1 (32 -> 64) + relu ----
    gemm_mfma_k<32, 64, true><<<dim3((N_COMM + 63) / 64), 256, 0, stream>>>(cFb, Wt_c1, ch_bf, N_COMM);
    gatherF_k<64, true><<<g1((long long)(N_COMM / 8) * 64), 256, 0, stream>>>(rowptr_c, cse_c, ch_bf, dinv_c, b_c1, cx1_bf, N_COMM / 8);

    // ---- community GCN layer 2 (64 -> 64) + relu ----
    gemm_mfma_k<64, 64, true><<<dim3((N_COMM + 63) / 64), 256, 0, stream>>>(cx1_bf, Wt_c2, ch_bf, N_COMM);
    gatherF_k<64, true><<<g1((long long)(N_COMM / 8) * 64), 256, 0, stream>>>(rowptr_c, cse_c, ch_bf, dinv_c, b_c2, cx2_bf, N_COMM / 8);

    // ---- building layer 1 GEMM (fused attention), writes h1 ----
    gemm_att_k<<<dim3(N_BUILD / 64), 256, 0, stream>>>(bF, cx2_bf, map, l2g, W_at, b_at, Wt_b1, B_bf);

    // ---- fused: layer-1 aggregation + relu + layer-2 GEMM -> h2 (A_bf) ----
    gather_gemm_k<<<dim3(N_BUILD / 64), 256, 0, stream>>>(rowptr_b, cse_b, B_bf, dinv_b, b_b1, Wt_b2, A_bf);

    // ---- building layer 2 aggregation + relu, fused with layer-3 XW -> Dh ----
    gather64_dot_k<<<g1((long long)(N_BUILD / 8) * 64), 256, 0, stream>>>(rowptr_b, cse_b, A_bf, dinv_b, b_b2, W_b3, Dh, N_BUILD / 8);

    // ---- building layer 3 aggregation + log-softmax + scatter ----
    gather2_logsm_k<<<g1(N_BUILD), 256, 0, stream>>>(rowptr_b, cse_b, Dh, dinv_b, b_b3, l2g, out, N_BUILD);
}